// Round 2
// baseline (4450.847 us; speedup 1.0000x reference)
//
#include <hip/hip_runtime.h>

#define INVBN 0.9999950000374997f   // 1/sqrt(1 + 1e-5)
#define ATT_SCALE 0.17677669529663687f  // 32^-0.5

// ---------------------------------------------------------------------------
// Repack conv3x3 weights (M,K,3,3) -> Wt[tap][m][k], folding BN scales and the
// 1x1 local conv into the center tap.  bsum[m] = b1[m] + b2[m].
// ---------------------------------------------------------------------------
__global__ __launch_bounds__(256)
void repack_kernel(const float* __restrict__ W2, const float* __restrict__ W1,
                   const float* __restrict__ g1, const float* __restrict__ g2,
                   const float* __restrict__ b1, const float* __restrict__ b2,
                   float* __restrict__ Wt, float* __restrict__ bsum)
{
    int i = blockIdx.x * 256 + threadIdx.x;
    if (i < 512) bsum[i] = b1[i] + b2[i];
    if (i >= 512 * 512 * 9) return;
    int tap = i / 262144;
    int rem = i - tap * 262144;          // m*512 + k
    int m   = rem >> 9;
    float v = g2[m] * INVBN * W2[(size_t)rem * 9 + tap];
    if (tap == 4) v = fmaf(g1[m] * INVBN, W1[rem], v);
    Wt[i] = v;
}

// ---------------------------------------------------------------------------
// 1x1 conv as GEMM: Out[b][m][p] = sum_k W[m][k] * X[b][k][p],  p in [0,4096)
// 128x128 tile, 256 threads, 8x8 per thread, BK=16
// ---------------------------------------------------------------------------
__global__ __launch_bounds__(256)
void gemm1x1_kernel(const float* __restrict__ X, const float* __restrict__ W,
                    float* __restrict__ Out, int M, int K)
{
    const int N = 4096;
    int b  = blockIdx.z;
    int n0 = blockIdx.x * 128;
    int m0 = blockIdx.y * 128;
    const float* Xb = X + (size_t)b * K * N;
    float* Ob = Out + (size_t)b * M * N;

    __shared__ float As[16][132];
    __shared__ float Bs[16][128];

    int t  = threadIdx.x;
    int tx = t & 15, ty = t >> 4;
    int rm = ty * 8, rn = tx * 8;

    float acc[8][8];
#pragma unroll
    for (int i = 0; i < 8; ++i)
#pragma unroll
        for (int j = 0; j < 8; ++j) acc[i][j] = 0.f;

    for (int k0 = 0; k0 < K; k0 += 16) {
#pragma unroll
        for (int i = 0; i < 8; ++i) {
            int f = i * 256 + t;
            int m = f >> 4, k = f & 15;
            As[k][m] = W[(size_t)(m0 + m) * K + (k0 + k)];
        }
#pragma unroll
        for (int i = 0; i < 2; ++i) {
            int f  = i * 256 + t;
            int k  = f >> 5, n4 = (f & 31) << 2;
            *reinterpret_cast<float4*>(&Bs[k][n4]) =
                *reinterpret_cast<const float4*>(&Xb[(size_t)(k0 + k) * N + (n0 + n4)]);
        }
        __syncthreads();
#pragma unroll
        for (int kk = 0; kk < 16; ++kk) {
            float a[8], bb[8];
#pragma unroll
            for (int i = 0; i < 8; ++i) a[i] = As[kk][rm + i];
#pragma unroll
            for (int j = 0; j < 8; ++j) bb[j] = Bs[kk][rn + j];
#pragma unroll
            for (int i = 0; i < 8; ++i)
#pragma unroll
                for (int j = 0; j < 8; ++j)
                    acc[i][j] = fmaf(a[i], bb[j], acc[i][j]);
        }
        __syncthreads();
    }
#pragma unroll
    for (int i = 0; i < 8; ++i) {
        size_t rb = (size_t)(m0 + rm + i) * N + n0 + rn;
        float4 o0 = make_float4(acc[i][0], acc[i][1], acc[i][2], acc[i][3]);
        float4 o1 = make_float4(acc[i][4], acc[i][5], acc[i][6], acc[i][7]);
        *reinterpret_cast<float4*>(&Ob[rb])     = o0;
        *reinterpret_cast<float4*>(&Ob[rb + 4]) = o1;
    }
}

// ---------------------------------------------------------------------------
// conv3x3 (zero pad 1) as 9-tap shifted GEMM with pre-folded weights.
// Out = acc + bsum[oc]   (local branch fully fused)
// ---------------------------------------------------------------------------
__global__ __launch_bounds__(256)
void conv3x3_kernel(const float* __restrict__ X, const float* __restrict__ Wt,
                    const float* __restrict__ bsum, float* __restrict__ Out)
{
    const int N = 4096, K = 512;
    int b  = blockIdx.z;
    int n0 = blockIdx.x * 128;
    int m0 = blockIdx.y * 128;
    const float* Xb = X + (size_t)b * K * N;

    __shared__ float As[16][132];
    __shared__ float Bs[16][128];

    int t  = threadIdx.x;
    int tx = t & 15, ty = t >> 4;
    int rm = ty * 8, rn = tx * 8;

    float acc[8][8];
#pragma unroll
    for (int i = 0; i < 8; ++i)
#pragma unroll
        for (int j = 0; j < 8; ++j) acc[i][j] = 0.f;

    for (int tap = 0; tap < 9; ++tap) {
        int dr = tap / 3 - 1, ds = tap % 3 - 1;
        const float* Wtap = Wt + (size_t)tap * 262144;
        for (int k0 = 0; k0 < K; k0 += 16) {
#pragma unroll
            for (int i = 0; i < 8; ++i) {
                int f = i * 256 + t;
                int m = f >> 4, k = f & 15;
                As[k][m] = Wtap[(size_t)(m0 + m) * K + (k0 + k)];
            }
#pragma unroll
            for (int i = 0; i < 8; ++i) {
                int f = i * 256 + t;
                int k = f >> 7, n = f & 127;
                int p = n0 + n;
                int h = p >> 6, w = p & 63;
                int hs = h + dr, wsx = w + ds;
                float v = 0.f;
                if ((unsigned)hs < 64u && (unsigned)wsx < 64u)
                    v = Xb[(size_t)(k0 + k) * N + hs * 64 + wsx];
                Bs[k][n] = v;
            }
            __syncthreads();
#pragma unroll
            for (int kk = 0; kk < 16; ++kk) {
                float a[8], bb[8];
#pragma unroll
                for (int i = 0; i < 8; ++i) a[i] = As[kk][rm + i];
#pragma unroll
                for (int j = 0; j < 8; ++j) bb[j] = Bs[kk][rn + j];
#pragma unroll
                for (int i = 0; i < 8; ++i)
#pragma unroll
                    for (int j = 0; j < 8; ++j)
                        acc[i][j] = fmaf(a[i], bb[j], acc[i][j]);
            }
            __syncthreads();
        }
    }
#pragma unroll
    for (int i = 0; i < 8; ++i) {
        int oc = m0 + rm + i;
        float bv = bsum[oc];
        size_t rb = ((size_t)b * 512 + oc) * 4096 + n0 + rn;
#pragma unroll
        for (int jv = 0; jv < 2; ++jv) {
            float4 o;
            o.x = acc[i][jv * 4 + 0] + bv;
            o.y = acc[i][jv * 4 + 1] + bv;
            o.z = acc[i][jv * 4 + 2] + bv;
            o.w = acc[i][jv * 4 + 3] + bv;
            *reinterpret_cast<float4*>(&Out[rb + jv * 4]) = o;
        }
    }
}

// ---------------------------------------------------------------------------
// Window attention for ONE batch: one block per (window, head). L=64, HD=32.
// ---------------------------------------------------------------------------
__global__ __launch_bounds__(256)
void attn_kernel(const float* __restrict__ QKV, const float* __restrict__ RT,
                 float* __restrict__ Out)
{
    int blk  = blockIdx.x;           // win*16 + head, win in [0,64)
    int head = blk & 15;
    int win  = blk >> 4;
    int wwi  = win & 7, hhi = win >> 3;

    __shared__ float Qs[64][33];
    __shared__ float Ks[64][33];
    __shared__ float Vs[64][33];
    __shared__ float Ss[64][65];

    int t = threadIdx.x;
    int ch0 = head * 32;
    int sp0 = (hhi * 8) * 64 + wwi * 8;

#pragma unroll
    for (int i = 0; i < 8; ++i) {
        int e  = i * 256 + t;
        int d  = e >> 6, tk = e & 63;
        int sp = sp0 + (tk >> 3) * 64 + (tk & 7);
        Qs[tk][d] = QKV[(size_t)(ch0 + d) * 4096 + sp];
        Ks[tk][d] = QKV[(size_t)(512 + ch0 + d) * 4096 + sp];
        Vs[tk][d] = QKV[(size_t)(1024 + ch0 + d) * 4096 + sp];
    }
    __syncthreads();

    int ti = t >> 2, qq = t & 3;
    float qreg[32];
#pragma unroll
    for (int d = 0; d < 32; ++d) qreg[d] = Qs[ti][d];

    float ev[16];
    float mx = -1e30f;
    int yi = ti >> 3, xi = ti & 7;
#pragma unroll
    for (int jj = 0; jj < 16; ++jj) {
        int j = qq * 16 + jj;
        float s = 0.f;
#pragma unroll
        for (int d = 0; d < 32; ++d) s = fmaf(qreg[d], Ks[j][d], s);
        int yj = j >> 3, xj = j & 7;
        int ridx = ((yi - yj + 7) * 15 + (xi - xj + 7)) * 16 + head;
        s = s * ATT_SCALE + RT[ridx];
        ev[jj] = s;
        mx = fmaxf(mx, s);
    }
    mx = fmaxf(mx, __shfl_xor(mx, 1));
    mx = fmaxf(mx, __shfl_xor(mx, 2));
    float sum = 0.f;
#pragma unroll
    for (int jj = 0; jj < 16; ++jj) {
        ev[jj] = __expf(ev[jj] - mx);
        sum += ev[jj];
    }
    sum += __shfl_xor(sum, 1);
    sum += __shfl_xor(sum, 2);
    float rs = 1.f / sum;
#pragma unroll
    for (int jj = 0; jj < 16; ++jj)
        Ss[ti][qq * 16 + jj] = ev[jj] * rs;
    __syncthreads();

    int r = t & 63, d0 = t >> 6;
    float o[8];
#pragma unroll
    for (int i = 0; i < 8; ++i) o[i] = 0.f;
    for (int j = 0; j < 64; ++j) {
        float sv = Ss[r][j];
#pragma unroll
        for (int i = 0; i < 8; ++i)
            o[i] = fmaf(sv, Vs[j][d0 + 4 * i], o[i]);
    }
    int sp = sp0 + (r >> 3) * 64 + (r & 7);
#pragma unroll
    for (int i = 0; i < 8; ++i) {
        int d = d0 + 4 * i;
        Out[(size_t)(head * 32 + d) * 4096 + sp] = o[i];
    }
}

// ---------------------------------------------------------------------------
// Fused: t = avgpool_x(attn) + avgpool_y(attn) + local   (reflect@64->62,
// zero outside [0,64], /8 count_include_pad), then depthwise 8x8 (reflect
// row/col 64->62, zero pad 3) + BN3.  Writes U in-place over the local plane
// (plane fully staged in LDS before any write).
// ---------------------------------------------------------------------------
__global__ __launch_bounds__(256)
void pooldw_kernel(const float* __restrict__ A, const float* __restrict__ L,
                   const float* __restrict__ Wd,
                   const float* __restrict__ g3, const float* __restrict__ b3,
                   float* __restrict__ U)
{
    int bc = blockIdx.x;               // b*512 + c
    int c  = bc & 511;
    __shared__ float ap[64][64];
    __shared__ float tp[64][64];
    __shared__ float wd[64];
    int t = threadIdx.x;
    const float* aplane = A + (size_t)bc * 4096;
    const float* lplane = L + (size_t)bc * 4096;
#pragma unroll
    for (int i = 0; i < 4; ++i) {
        reinterpret_cast<float4*>(&ap[0][0])[i * 256 + t] =
            reinterpret_cast<const float4*>(aplane)[i * 256 + t];
        reinterpret_cast<float4*>(&tp[0][0])[i * 256 + t] =
            reinterpret_cast<const float4*>(lplane)[i * 256 + t];
    }
    if (t < 64) wd[t] = Wd[c * 64 + t];
    __syncthreads();

    // pool: tp[h][w] += 0.125*(sx+sy)
#pragma unroll
    for (int k = 0; k < 16; ++k) {
        int p = k * 256 + t;
        int h = p >> 6, w = p & 63;
        float sx = 0.f, sy = 0.f;
#pragma unroll
        for (int j = -3; j <= 4; ++j) {
            int y = h + j;
            if (y >= 0 && y <= 64) sx += ap[(y == 64) ? 62 : y][w];
            int x = w + j;
            if (x >= 0 && x <= 64) sy += ap[h][(x == 64) ? 62 : x];
        }
        tp[h][w] += 0.125f * (sx + sy);
    }
    __syncthreads();

    float gc  = g3[c] * INVBN;
    float bcv = b3[c];
#pragma unroll
    for (int k = 0; k < 16; ++k) {
        int p = k * 256 + t;
        int h = p >> 6, w = p & 63;
        float acc = 0.f;
#pragma unroll
        for (int i = 0; i < 8; ++i) {
            int y = h - 3 + i;
            if (y < 0 || y > 64) continue;
            int yy = (y == 64) ? 62 : y;
#pragma unroll
            for (int j = 0; j < 8; ++j) {
                int x = w - 3 + j;
                if (x < 0 || x > 64) continue;
                int xx = (x == 64) ? 62 : x;
                acc = fmaf(wd[i * 8 + j], tp[yy][xx], acc);
            }
        }
        U[(size_t)bc * 4096 + p] = gc * acc + bcv;
    }
}

// ---------------------------------------------------------------------------
extern "C" void kernel_launch(void* const* d_in, const int* in_sizes, int n_in,
                              void* d_out, int out_size, void* d_ws, size_t ws_size,
                              hipStream_t stream)
{
    (void)in_sizes; (void)n_in; (void)out_size; (void)ws_size;
    const float* x     = (const float*)d_in[0];
    const float* w_lc1 = (const float*)d_in[1];
    const float* g1    = (const float*)d_in[2];
    const float* b1    = (const float*)d_in[3];
    const float* w_lc2 = (const float*)d_in[4];
    const float* g2    = (const float*)d_in[5];
    const float* b2    = (const float*)d_in[6];
    const float* w_qkv = (const float*)d_in[7];
    const float* rt    = (const float*)d_in[8];
    const float* w_dw  = (const float*)d_in[9];
    const float* g3    = (const float*)d_in[10];
    const float* b3    = (const float*)d_in[11];
    const float* w_pw  = (const float*)d_in[12];
    float* out = (float*)d_out;

    // workspace layout (floats), total 25,428,480 fl = 97 MB
    float* ws        = (float*)d_ws;
    float* buf_local = ws;                    // 16,777,216 (B,512,64,64); becomes U in-place
    float* buf_qkv   = ws + 16777216;         // 6,291,456  (one batch: 1536*4096)
    float* wt2       = ws + 23068672;         // 2,359,296  (9 taps folded)
    float* bsum      = ws + 25427968;         // 512
    float* attnbuf   = out;                   // d_out as scratch for attention output

    dim3 blk(256);

    repack_kernel<<<dim3(9216), blk, 0, stream>>>(w_lc2, w_lc1, g1, g2, b1, b2, wt2, bsum);
    conv3x3_kernel<<<dim3(32, 4, 8), blk, 0, stream>>>(x, wt2, bsum, buf_local);
    for (int b = 0; b < 8; ++b) {
        gemm1x1_kernel<<<dim3(32, 12, 1), blk, 0, stream>>>(
            x + (size_t)b * 2097152, w_qkv, buf_qkv, 1536, 512);
        attn_kernel<<<dim3(1024), blk, 0, stream>>>(
            buf_qkv, rt, attnbuf + (size_t)b * 2097152);
    }
    pooldw_kernel<<<dim3(4096), blk, 0, stream>>>(attnbuf, buf_local, w_dw, g3, b3, buf_local);
    gemm1x1_kernel<<<dim3(32, 4, 8), blk, 0, stream>>>(buf_local, w_pw, out, 512, 512);
}

// Round 3
// 1101.454 us; speedup vs baseline: 4.0409x; 4.0409x over previous
//
#include <hip/hip_runtime.h>

#define INVBN 0.9999950000374997f       // 1/sqrt(1 + 1e-5)
#define ATT_SCALE 0.17677669529663687f  // 32^-0.5

typedef short bf16x8 __attribute__((ext_vector_type(8)));
typedef float f32x4  __attribute__((ext_vector_type(4)));
typedef unsigned short us8v __attribute__((ext_vector_type(8)));

#define AS1C(p) ((const __attribute__((address_space(1))) void*)(p))
#define AS3(p)  ((__attribute__((address_space(3))) void*)(p))

__device__ __forceinline__ float bf2f(unsigned short u) {
    return __uint_as_float(((unsigned)u) << 16);
}
__device__ __forceinline__ unsigned short f2bf(float f) {
    unsigned u = __float_as_uint(f);
    u += 0x7FFFu + ((u >> 16) & 1u);        // RNE
    return (unsigned short)(u >> 16);
}

// ---------------------------------------------------------------------------
// Repack: Wt3[tap][m][k] bf16 (BN-folded conv3x3 + lc1 into center tap),
// Wq[m][k] bf16, bsum[m] = b1+b2.
// ---------------------------------------------------------------------------
__global__ __launch_bounds__(256)
void repack_kernel(const float* __restrict__ W2, const float* __restrict__ W1,
                   const float* __restrict__ Wq,
                   const float* __restrict__ g1, const float* __restrict__ g2,
                   const float* __restrict__ b1, const float* __restrict__ b2,
                   unsigned short* __restrict__ Wt, unsigned short* __restrict__ WqO,
                   float* __restrict__ bsum)
{
    int i = blockIdx.x * 256 + threadIdx.x;
    if (i < 512) bsum[i] = b1[i] + b2[i];
    if (i < 786432) WqO[i] = f2bf(Wq[i]);
    if (i >= 2359296) return;
    int tap = i / 262144;
    int rem = i - tap * 262144;          // m*512 + k
    int m   = rem >> 9;
    float v = g2[m] * INVBN * W2[(size_t)rem * 9 + tap];
    if (tap == 4) v = fmaf(g1[m] * INVBN, W1[rem], v);
    Wt[i] = f2bf(v);
}

// ---------------------------------------------------------------------------
// x (B,512,64,64) f32 NCHW  ->  X_tp (B, 66*66, 512) bf16, zero borders.
// Block = (padded row ph, batch b).
// ---------------------------------------------------------------------------
__global__ __launch_bounds__(256)
void pad_transpose_kernel(const float* __restrict__ X, unsigned short* __restrict__ XT)
{
    int ph = blockIdx.x;      // 0..65
    int b  = blockIdx.y;
    int t  = threadIdx.x;
    unsigned short* rowbase = XT + ((size_t)b * 4356 + (size_t)ph * 66) * 512;
    uint4 z = make_uint4(0, 0, 0, 0);
    if (ph == 0 || ph == 65) {
        uint4* p4 = (uint4*)rowbase;                 // 66*512 elems = 4224 uint4
        for (int i = t; i < 4224; i += 256) p4[i] = z;
        return;
    }
    if (t < 64)       ((uint4*)rowbase)[t] = z;                  // pw = 0
    else if (t < 128) ((uint4*)(rowbase + 65 * 512))[t - 64] = z; // pw = 65

    int h = ph - 1;
    __shared__ float tile[64][65];
    const float* xb = X + (size_t)b * 512 * 4096 + h * 64;
    for (int cc = 0; cc < 8; ++cc) {
        int c0 = cc * 64;
        __syncthreads();
#pragma unroll
        for (int i = 0; i < 4; ++i) {
            int cl = i * 16 + (t >> 4);
            int w0 = (t & 15) * 4;
            *(float4*)&tile[cl][w0] =
                *(const float4*)&xb[(size_t)(c0 + cl) * 4096 + w0];
        }
        __syncthreads();
#pragma unroll
        for (int it = 0; it < 2; ++it) {
            int wl = it * 32 + (t >> 3);     // w = 0..63  -> pw = wl+1
            int cs = (t & 7) * 8;
            us8v v;
#pragma unroll
            for (int e = 0; e < 8; ++e) v[e] = f2bf(tile[cs + e][wl]);
            *(us8v*)&rowbase[(size_t)(1 + wl) * 512 + c0 + cs] = v;
        }
    }
}

// ---------------------------------------------------------------------------
// MFMA GEMM: Out[b][m][p] = sum_taps sum_k A[b][pp(p,tap)][k] * Bw[tap][m][k]
// A = X_tp bf16 (padded-transposed acts), Bw bf16 [NTAPS][M][512], out bf16.
// 128x128 tile, 4 waves, BK=64, global_load_lds(16B) staging with XOR swizzle.
// ---------------------------------------------------------------------------
template<int NTAPS>
__global__ __launch_bounds__(256)
void mfma_gemm(const unsigned short* __restrict__ A,
               const unsigned short* __restrict__ Bw,
               const float* __restrict__ bias,
               unsigned short* __restrict__ Out, int M)
{
    __shared__ short As[128 * 64];
    __shared__ short Bs[128 * 64];

    const int t  = threadIdx.x;
    const int n0 = blockIdx.x * 128;
    const int m0 = blockIdx.y * 128;
    const int b  = blockIdx.z;
    const unsigned short* Ab = A + (size_t)b * (4356 * 512);
    unsigned short* Ob = Out + (size_t)b * ((size_t)M * 4096);

    // --- staging addressing (thread -> 4 slots per matrix per K-step) ---
    const int trow = t >> 3;                    // 0..31 (row = i*32 + trow)
    const int csrc = (t & 7) ^ (trow & 7);      // inverse XOR swizzle on source
    const unsigned short* aSrc[4];
    const unsigned short* bSrc[4];
#pragma unroll
    for (int i = 0; i < 4; ++i) {
        int r = i * 32 + trow;
        int p = n0 + r, h = p >> 6, w = p & 63;
        aSrc[i] = Ab + ((size_t)((h + 1) * 66 + (w + 1)) * 512 + csrc * 8);
        bSrc[i] = Bw + ((size_t)(m0 + r) * 512 + csrc * 8);
    }
    short* aDst = As + (t & 192) * 8;           // wave-uniform LDS base
    short* bDst = Bs + (t & 192) * 8;

    // --- fragment read offsets (swizzled) ---
    const int lane = t & 63;
    const int wv = t >> 6, wr = wv >> 1, wc = wv & 1;
    const int lrow = lane & 15, lk = lane >> 4;
    int aOff[4][2], bOff[4][2];
#pragma unroll
    for (int f = 0; f < 4; ++f)
#pragma unroll
        for (int kk = 0; kk < 2; ++kk) {
            int ra = wr * 64 + f * 16 + lrow;
            aOff[f][kk] = ra * 64 + ((kk * 4 + lk) ^ (ra & 7)) * 8;
            int rb = wc * 64 + f * 16 + lrow;
            bOff[f][kk] = rb * 64 + ((kk * 4 + lk) ^ (rb & 7)) * 8;
        }

    f32x4 acc[4][4] = {};

#pragma unroll 1
    for (int tap = 0; tap < NTAPS; ++tap) {
        const int dr  = (NTAPS == 9) ? (tap / 3 - 1) : 0;
        const int dsh = (NTAPS == 9) ? (tap % 3 - 1) : 0;
        const int aTapOff = (dr * 66 + dsh) * 512;
        const size_t bTapOff = (size_t)tap * (size_t)M * 512;
#pragma unroll 1
        for (int ks = 0; ks < 8; ++ks) {
            const int k0 = ks * 64;
            __syncthreads();
#pragma unroll
            for (int i = 0; i < 4; ++i) {
                __builtin_amdgcn_global_load_lds(
                    AS1C(aSrc[i] + aTapOff + k0), AS3(aDst + i * 2048), 16, 0, 0);
                __builtin_amdgcn_global_load_lds(
                    AS1C(bSrc[i] + bTapOff + k0), AS3(bDst + i * 2048), 16, 0, 0);
            }
            __syncthreads();
            bf16x8 av[4][2], bv[4][2];
#pragma unroll
            for (int f = 0; f < 4; ++f) {
                av[f][0] = *(const bf16x8*)&As[aOff[f][0]];
                av[f][1] = *(const bf16x8*)&As[aOff[f][1]];
                bv[f][0] = *(const bf16x8*)&Bs[bOff[f][0]];
                bv[f][1] = *(const bf16x8*)&Bs[bOff[f][1]];
            }
#pragma unroll
            for (int kk = 0; kk < 2; ++kk)
#pragma unroll
                for (int fn = 0; fn < 4; ++fn)
#pragma unroll
                    for (int fm = 0; fm < 4; ++fm)
                        acc[fn][fm] = __builtin_amdgcn_mfma_f32_16x16x32_bf16(
                            av[fn][kk], bv[fm][kk], acc[fn][fm], 0, 0, 0);
        }
    }

    // --- epilogue: bias + bf16 store (D: col m = lane&15, rows n = lk*4+reg)
#pragma unroll
    for (int fm = 0; fm < 4; ++fm) {
        int m = m0 + wc * 64 + fm * 16 + lrow;
        float bv = bias ? bias[m] : 0.f;
        size_t mrow = (size_t)m * 4096;
#pragma unroll
        for (int fn = 0; fn < 4; ++fn) {
            int nb = n0 + wr * 64 + fn * 16 + lk * 4;
            f32x4 a4 = acc[fn][fm];
            ushort4 o;
            o.x = f2bf(a4[0] + bv);
            o.y = f2bf(a4[1] + bv);
            o.z = f2bf(a4[2] + bv);
            o.w = f2bf(a4[3] + bv);
            *(ushort4*)&Ob[mrow + nb] = o;
        }
    }
}

// ---------------------------------------------------------------------------
// Window attention for ONE batch (bf16 qkv in, f32 out).
// ---------------------------------------------------------------------------
__global__ __launch_bounds__(256)
void attn_kernel(const unsigned short* __restrict__ QKV, const float* __restrict__ RT,
                 float* __restrict__ Out)
{
    int blk  = blockIdx.x;           // win*16 + head
    int head = blk & 15;
    int win  = blk >> 4;
    int wwi  = win & 7, hhi = win >> 3;

    __shared__ float Qs[64][33];
    __shared__ float Ks[64][33];
    __shared__ float Vs[64][33];
    __shared__ float Ss[64][65];

    int t = threadIdx.x;
    int ch0 = head * 32;
    int sp0 = (hhi * 8) * 64 + wwi * 8;

#pragma unroll
    for (int i = 0; i < 2; ++i) {
        int cidx = i * 256 + t;            // 0..511
        int d    = cidx >> 4;              // 0..31
        int tk0  = (cidx & 15) * 4;        // 0..60
        int sp   = sp0 + ((tk0 >> 3) << 6) + (tk0 & 7);
        ushort4 q4 = *(const ushort4*)&QKV[(size_t)(ch0 + d) * 4096 + sp];
        ushort4 k4 = *(const ushort4*)&QKV[(size_t)(512 + ch0 + d) * 4096 + sp];
        ushort4 v4 = *(const ushort4*)&QKV[(size_t)(1024 + ch0 + d) * 4096 + sp];
        Qs[tk0+0][d] = bf2f(q4.x); Qs[tk0+1][d] = bf2f(q4.y);
        Qs[tk0+2][d] = bf2f(q4.z); Qs[tk0+3][d] = bf2f(q4.w);
        Ks[tk0+0][d] = bf2f(k4.x); Ks[tk0+1][d] = bf2f(k4.y);
        Ks[tk0+2][d] = bf2f(k4.z); Ks[tk0+3][d] = bf2f(k4.w);
        Vs[tk0+0][d] = bf2f(v4.x); Vs[tk0+1][d] = bf2f(v4.y);
        Vs[tk0+2][d] = bf2f(v4.z); Vs[tk0+3][d] = bf2f(v4.w);
    }
    __syncthreads();

    int ti = t >> 2, qq = t & 3;
    float qreg[32];
#pragma unroll
    for (int d = 0; d < 32; ++d) qreg[d] = Qs[ti][d];

    float ev[16];
    float mx = -1e30f;
    int yi = ti >> 3, xi = ti & 7;
#pragma unroll
    for (int jj = 0; jj < 16; ++jj) {
        int j = qq * 16 + jj;
        float s = 0.f;
#pragma unroll
        for (int d = 0; d < 32; ++d) s = fmaf(qreg[d], Ks[j][d], s);
        int yj = j >> 3, xj = j & 7;
        int ridx = ((yi - yj + 7) * 15 + (xi - xj + 7)) * 16 + head;
        s = s * ATT_SCALE + RT[ridx];
        ev[jj] = s;
        mx = fmaxf(mx, s);
    }
    mx = fmaxf(mx, __shfl_xor(mx, 1));
    mx = fmaxf(mx, __shfl_xor(mx, 2));
    float sum = 0.f;
#pragma unroll
    for (int jj = 0; jj < 16; ++jj) {
        ev[jj] = __expf(ev[jj] - mx);
        sum += ev[jj];
    }
    sum += __shfl_xor(sum, 1);
    sum += __shfl_xor(sum, 2);
    float rs = 1.f / sum;
#pragma unroll
    for (int jj = 0; jj < 16; ++jj)
        Ss[ti][qq * 16 + jj] = ev[jj] * rs;
    __syncthreads();

    int r = t & 63, d0 = t >> 6;
    float o[8];
#pragma unroll
    for (int i = 0; i < 8; ++i) o[i] = 0.f;
    for (int j = 0; j < 64; ++j) {
        float sv = Ss[r][j];
#pragma unroll
        for (int i = 0; i < 8; ++i)
            o[i] = fmaf(sv, Vs[j][d0 + 4 * i], o[i]);
    }
    int sp = sp0 + (r >> 3) * 64 + (r & 7);
#pragma unroll
    for (int i = 0; i < 8; ++i) {
        int d = d0 + 4 * i;
        Out[(size_t)(head * 32 + d) * 4096 + sp] = o[i];
    }
}

// ---------------------------------------------------------------------------
// Fused pool(+local) + depthwise 8x8 + BN3.  attn f32 in, local bf16 in,
// U bf16 out.
// ---------------------------------------------------------------------------
__global__ __launch_bounds__(256)
void pooldw_kernel(const float* __restrict__ A, const unsigned short* __restrict__ L,
                   const float* __restrict__ Wd,
                   const float* __restrict__ g3, const float* __restrict__ b3,
                   unsigned short* __restrict__ U)
{
    int bc = blockIdx.x;               // b*512 + c
    int c  = bc & 511;
    __shared__ float ap[64][64];
    __shared__ float tp[64][64];
    __shared__ float wd[64];
    int t = threadIdx.x;
    const float* aplane = A + (size_t)bc * 4096;
    const unsigned short* lplane = L + (size_t)bc * 4096;
    float* apf = &ap[0][0];
    float* tpf = &tp[0][0];
#pragma unroll
    for (int i = 0; i < 4; ++i) {
        ((float4*)apf)[i * 256 + t] = ((const float4*)aplane)[i * 256 + t];
        ushort4 u4 = ((const ushort4*)lplane)[i * 256 + t];
        int e = (i * 256 + t) * 4;
        tpf[e+0] = bf2f(u4.x); tpf[e+1] = bf2f(u4.y);
        tpf[e+2] = bf2f(u4.z); tpf[e+3] = bf2f(u4.w);
    }
    if (t < 64) wd[t] = Wd[c * 64 + t];
    __syncthreads();

#pragma unroll
    for (int k = 0; k < 16; ++k) {
        int p = k * 256 + t;
        int h = p >> 6, w = p & 63;
        float sx = 0.f, sy = 0.f;
#pragma unroll
        for (int j = -3; j <= 4; ++j) {
            int y = h + j;
            if (y >= 0 && y <= 64) sx += ap[(y == 64) ? 62 : y][w];
            int x = w + j;
            if (x >= 0 && x <= 64) sy += ap[h][(x == 64) ? 62 : x];
        }
        tp[h][w] += 0.125f * (sx + sy);
    }
    __syncthreads();

    float gc  = g3[c] * INVBN;
    float bcv = b3[c];
#pragma unroll
    for (int k = 0; k < 16; ++k) {
        int p = k * 256 + t;
        int h = p >> 6, w = p & 63;
        float acc = 0.f;
#pragma unroll
        for (int i = 0; i < 8; ++i) {
            int y = h - 3 + i;
            if (y < 0 || y > 64) continue;
            int yy = (y == 64) ? 62 : y;
#pragma unroll
            for (int j = 0; j < 8; ++j) {
                int x = w - 3 + j;
                if (x < 0 || x > 64) continue;
                int xx = (x == 64) ? 62 : x;
                acc = fmaf(wd[i * 8 + j], tp[yy][xx], acc);
            }
        }
        U[(size_t)bc * 4096 + p] = f2bf(gc * acc + bcv);
    }
}

// ---------------------------------------------------------------------------
// Final 1x1 conv: X bf16 (U), W f32, out f32.  fp32-vector GEMM.
// ---------------------------------------------------------------------------
__global__ __launch_bounds__(256)
void gemm1x1_bf16_kernel(const unsigned short* __restrict__ X, const float* __restrict__ W,
                         float* __restrict__ Out)
{
    const int N = 4096, K = 512;
    int b  = blockIdx.z;
    int n0 = blockIdx.x * 128;
    int m0 = blockIdx.y * 128;
    const unsigned short* Xb = X + (size_t)b * K * N;
    float* Ob = Out + (size_t)b * 512 * N;

    __shared__ float As2[16][132];
    __shared__ float Bs2[16][128];

    int t  = threadIdx.x;
    int tx = t & 15, ty = t >> 4;
    int rm = ty * 8, rn = tx * 8;

    float acc[8][8];
#pragma unroll
    for (int i = 0; i < 8; ++i)
#pragma unroll
        for (int j = 0; j < 8; ++j) acc[i][j] = 0.f;

    for (int k0 = 0; k0 < K; k0 += 16) {
#pragma unroll
        for (int i = 0; i < 8; ++i) {
            int f = i * 256 + t;
            int m = f >> 4, k = f & 15;
            As2[k][m] = W[(size_t)(m0 + m) * K + (k0 + k)];
        }
        {
            int kq = t >> 4, n8 = (t & 15) * 8;
            uint4 raw = *(const uint4*)&Xb[(size_t)(k0 + kq) * N + n0 + n8];
            float* brow = &Bs2[kq][n8];
            brow[0] = __uint_as_float(raw.x << 16);
            brow[1] = __uint_as_float(raw.x & 0xffff0000u);
            brow[2] = __uint_as_float(raw.y << 16);
            brow[3] = __uint_as_float(raw.y & 0xffff0000u);
            brow[4] = __uint_as_float(raw.z << 16);
            brow[5] = __uint_as_float(raw.z & 0xffff0000u);
            brow[6] = __uint_as_float(raw.w << 16);
            brow[7] = __uint_as_float(raw.w & 0xffff0000u);
        }
        __syncthreads();
#pragma unroll
        for (int kk = 0; kk < 16; ++kk) {
            float a[8], bb[8];
#pragma unroll
            for (int i = 0; i < 8; ++i) a[i] = As2[kk][rm + i];
#pragma unroll
            for (int j = 0; j < 8; ++j) bb[j] = Bs2[kk][rn + j];
#pragma unroll
            for (int i = 0; i < 8; ++i)
#pragma unroll
                for (int j = 0; j < 8; ++j)
                    acc[i][j] = fmaf(a[i], bb[j], acc[i][j]);
        }
        __syncthreads();
    }
#pragma unroll
    for (int i = 0; i < 8; ++i) {
        size_t rb = (size_t)(m0 + rm + i) * N + n0 + rn;
        *reinterpret_cast<float4*>(&Ob[rb])     = make_float4(acc[i][0], acc[i][1], acc[i][2], acc[i][3]);
        *reinterpret_cast<float4*>(&Ob[rb + 4]) = make_float4(acc[i][4], acc[i][5], acc[i][6], acc[i][7]);
    }
}

// ---------------------------------------------------------------------------
extern "C" void kernel_launch(void* const* d_in, const int* in_sizes, int n_in,
                              void* d_out, int out_size, void* d_ws, size_t ws_size,
                              hipStream_t stream)
{
    (void)in_sizes; (void)n_in; (void)out_size; (void)ws_size;
    const float* x     = (const float*)d_in[0];
    const float* w_lc1 = (const float*)d_in[1];
    const float* g1    = (const float*)d_in[2];
    const float* b1    = (const float*)d_in[3];
    const float* w_lc2 = (const float*)d_in[4];
    const float* g2    = (const float*)d_in[5];
    const float* b2    = (const float*)d_in[6];
    const float* w_qkv = (const float*)d_in[7];
    const float* rt    = (const float*)d_in[8];
    const float* w_dw  = (const float*)d_in[9];
    const float* g3    = (const float*)d_in[10];
    const float* b3    = (const float*)d_in[11];
    const float* w_pw  = (const float*)d_in[12];
    float* out = (float*)d_out;

    // workspace (float offsets), total 22,028,800 floats = 88.1 MB
    float* ws = (float*)d_ws;
    unsigned short* local_us = (unsigned short*)ws;                // (B,512,4096) bf16
    unsigned short* qkv_us   = (unsigned short*)(ws + 8388608);    // (1536,4096) bf16, 1 batch
    unsigned short* xt_us    = (unsigned short*)(ws + 11534336);   // (B,4356,512) bf16
    unsigned short* u_us     = xt_us;                              // alias: U after X_tp dead
    unsigned short* wt3_us   = (unsigned short*)(ws + 20455424);   // (9,512,512) bf16
    unsigned short* wq_us    = (unsigned short*)(ws + 21635072);   // (1536,512) bf16
    float*          bsum     = ws + 22028288;                      // 512 f32

    repack_kernel<<<dim3(9216), 256, 0, stream>>>(w_lc2, w_lc1, w_qkv,
                                                  g1, g2, b1, b2, wt3_us, wq_us, bsum);
    pad_transpose_kernel<<<dim3(66, 8), 256, 0, stream>>>(x, xt_us);
    mfma_gemm<9><<<dim3(32, 4, 8), 256, 0, stream>>>(xt_us, wt3_us, bsum, local_us, 512);
    for (int b = 0; b < 8; ++b) {
        mfma_gemm<1><<<dim3(32, 12, 1), 256, 0, stream>>>(
            xt_us + (size_t)b * 4356 * 512, wq_us, nullptr, qkv_us, 1536);
        attn_kernel<<<dim3(1024), 256, 0, stream>>>(
            qkv_us, rt, out + (size_t)b * 2097152);
    }
    pooldw_kernel<<<dim3(4096), 256, 0, stream>>>(out, local_us, w_dw, g3, b3, u_us);
    gemm1x1_bf16_kernel<<<dim3(32, 4, 8), 256, 0, stream>>>(u_us, w_pw, out);
}

// Round 5
// 744.425 us; speedup vs baseline: 5.9789x; 1.4796x over previous
//
#include <hip/hip_runtime.h>

#define INVBN 0.9999950000374997f       // 1/sqrt(1 + 1e-5)
#define ATT_SCALE 0.17677669529663687f  // 32^-0.5

typedef short bf16x8 __attribute__((ext_vector_type(8)));
typedef float f32x4  __attribute__((ext_vector_type(4)));
typedef unsigned short us8v __attribute__((ext_vector_type(8)));

#define AS1C(p) ((const __attribute__((address_space(1))) void*)(p))
#define AS3(p)  ((__attribute__((address_space(3))) void*)(p))

__device__ __forceinline__ float bf2f(unsigned short u) {
    return __uint_as_float(((unsigned)u) << 16);
}
__device__ __forceinline__ unsigned short f2bf(float f) {
    unsigned u = __float_as_uint(f);
    u += 0x7FFFu + ((u >> 16) & 1u);        // RNE
    return (unsigned short)(u >> 16);
}

// ---------------------------------------------------------------------------
// Repack: Wt3[tap][m][k] bf16 (BN-folded conv3x3 + lc1 into center tap),
// Wq, Wpw bf16, bsum[m] = b1+b2.
// ---------------------------------------------------------------------------
__global__ __launch_bounds__(256)
void repack_kernel(const float* __restrict__ W2, const float* __restrict__ W1,
                   const float* __restrict__ Wq, const float* __restrict__ Wp,
                   const float* __restrict__ g1, const float* __restrict__ g2,
                   const float* __restrict__ b1, const float* __restrict__ b2,
                   unsigned short* __restrict__ Wt, unsigned short* __restrict__ WqO,
                   unsigned short* __restrict__ WpO, float* __restrict__ bsum)
{
    int i = blockIdx.x * 256 + threadIdx.x;
    if (i < 512) bsum[i] = b1[i] + b2[i];
    if (i < 786432) WqO[i] = f2bf(Wq[i]);
    if (i < 262144) WpO[i] = f2bf(Wp[i]);
    if (i >= 2359296) return;
    int tap = i / 262144;
    int rem = i - tap * 262144;          // m*512 + k
    int m   = rem >> 9;
    float v = g2[m] * INVBN * W2[(size_t)rem * 9 + tap];
    if (tap == 4) v = fmaf(g1[m] * INVBN, W1[rem], v);
    Wt[i] = f2bf(v);
}

// ---------------------------------------------------------------------------
// x (B,512,64,64) f32 NCHW  ->  X_tp (B, 66*66, 512) bf16, zero borders.
// ---------------------------------------------------------------------------
__global__ __launch_bounds__(256)
void pad_transpose_kernel(const float* __restrict__ X, unsigned short* __restrict__ XT)
{
    int ph = blockIdx.x;      // 0..65
    int b  = blockIdx.y;
    int t  = threadIdx.x;
    unsigned short* rowbase = XT + ((size_t)b * 4356 + (size_t)ph * 66) * 512;
    uint4 z = make_uint4(0, 0, 0, 0);
    if (ph == 0 || ph == 65) {
        uint4* p4 = (uint4*)rowbase;                 // 66*512 elems = 4224 uint4
        for (int i = t; i < 4224; i += 256) p4[i] = z;
        return;
    }
    if (t < 64)       ((uint4*)rowbase)[t] = z;                  // pw = 0
    else if (t < 128) ((uint4*)(rowbase + 65 * 512))[t - 64] = z; // pw = 65

    int h = ph - 1;
    __shared__ float tile[64][65];
    const float* xb = X + (size_t)b * 512 * 4096 + h * 64;
    for (int cc = 0; cc < 8; ++cc) {
        int c0 = cc * 64;
        __syncthreads();
#pragma unroll
        for (int i = 0; i < 4; ++i) {
            int cl = i * 16 + (t >> 4);
            int w0 = (t & 15) * 4;
            *(float4*)&tile[cl][w0] =
                *(const float4*)&xb[(size_t)(c0 + cl) * 4096 + w0];
        }
        __syncthreads();
#pragma unroll
        for (int it = 0; it < 2; ++it) {
            int wl = it * 32 + (t >> 3);     // w = 0..63  -> pw = wl+1
            int cs = (t & 7) * 8;
            us8v v;
#pragma unroll
            for (int e = 0; e < 8; ++e) v[e] = f2bf(tile[cs + e][wl]);
            *(us8v*)&rowbase[(size_t)(1 + wl) * 512 + c0 + cs] = v;
        }
    }
}

// ---------------------------------------------------------------------------
// MFMA GEMM.  A bf16: PAD ? (B,66*66,512) padded-transposed : (B,4096,512).
// Bw bf16 [NTAPS][M][512].  Out: bf16 or f32 per OT.  128x128 tile, 4 waves.
// ---------------------------------------------------------------------------
template<int NTAPS, bool PAD, typename OT>
__global__ __launch_bounds__(256)
void mfma_gemm(const unsigned short* __restrict__ A,
               const unsigned short* __restrict__ Bw,
               const float* __restrict__ bias,
               OT* __restrict__ Out, int M)
{
    __shared__ short As[128 * 64];
    __shared__ short Bs[128 * 64];

    const int t  = threadIdx.x;
    const int n0 = blockIdx.x * 128;
    const int m0 = blockIdx.y * 128;
    const int b  = blockIdx.z;
    const unsigned short* Ab = A + (size_t)b * (PAD ? 4356 * 512 : 4096 * 512);
    OT* Ob = Out + (size_t)b * ((size_t)M * 4096);

    // --- staging addressing ---
    const int trow = t >> 3;                    // 0..31 (row = i*32 + trow)
    const int csrc = (t & 7) ^ (trow & 7);      // inverse XOR swizzle on source
    const unsigned short* aSrc[4];
    const unsigned short* bSrc[4];
#pragma unroll
    for (int i = 0; i < 4; ++i) {
        int r = i * 32 + trow;
        int p = n0 + r;
        if (PAD) {
            int h = p >> 6, w = p & 63;
            aSrc[i] = Ab + ((size_t)((h + 1) * 66 + (w + 1)) * 512 + csrc * 8);
        } else {
            aSrc[i] = Ab + ((size_t)p * 512 + csrc * 8);
        }
        bSrc[i] = Bw + ((size_t)(m0 + r) * 512 + csrc * 8);
    }
    short* aDst = As + (t & 192) * 8;           // wave-uniform LDS base
    short* bDst = Bs + (t & 192) * 8;

    // --- fragment read offsets (swizzled) ---
    const int lane = t & 63;
    const int wv = t >> 6, wr = wv >> 1, wc = wv & 1;
    const int lrow = lane & 15, lk = lane >> 4;
    int aOff[4][2], bOff[4][2];
#pragma unroll
    for (int f = 0; f < 4; ++f)
#pragma unroll
        for (int kk = 0; kk < 2; ++kk) {
            int ra = wr * 64 + f * 16 + lrow;
            aOff[f][kk] = ra * 64 + ((kk * 4 + lk) ^ (ra & 7)) * 8;
            int rb = wc * 64 + f * 16 + lrow;
            bOff[f][kk] = rb * 64 + ((kk * 4 + lk) ^ (rb & 7)) * 8;
        }

    f32x4 acc[4][4] = {};

#pragma unroll 1
    for (int tap = 0; tap < NTAPS; ++tap) {
        const int dr  = (NTAPS == 9) ? (tap / 3 - 1) : 0;
        const int dsh = (NTAPS == 9) ? (tap % 3 - 1) : 0;
        const int aTapOff = (dr * 66 + dsh) * 512;
        const size_t bTapOff = (size_t)tap * (size_t)M * 512;
#pragma unroll 1
        for (int ks = 0; ks < 8; ++ks) {
            const int k0 = ks * 64;
            __syncthreads();
#pragma unroll
            for (int i = 0; i < 4; ++i) {
                __builtin_amdgcn_global_load_lds(
                    AS1C(aSrc[i] + aTapOff + k0), AS3(aDst + i * 2048), 16, 0, 0);
                __builtin_amdgcn_global_load_lds(
                    AS1C(bSrc[i] + bTapOff + k0), AS3(bDst + i * 2048), 16, 0, 0);
            }
            __syncthreads();
            bf16x8 av[4][2], bv[4][2];
#pragma unroll
            for (int f = 0; f < 4; ++f) {
                av[f][0] = *(const bf16x8*)&As[aOff[f][0]];
                av[f][1] = *(const bf16x8*)&As[aOff[f][1]];
                bv[f][0] = *(const bf16x8*)&Bs[bOff[f][0]];
                bv[f][1] = *(const bf16x8*)&Bs[bOff[f][1]];
            }
#pragma unroll
            for (int kk = 0; kk < 2; ++kk)
#pragma unroll
                for (int fn = 0; fn < 4; ++fn)
#pragma unroll
                    for (int fm = 0; fm < 4; ++fm)
                        acc[fn][fm] = __builtin_amdgcn_mfma_f32_16x16x32_bf16(
                            av[fn][kk], bv[fm][kk], acc[fn][fm], 0, 0, 0);
        }
    }

    // --- epilogue: bias + store (D: col m = lane&15, rows n = lk*4+reg) ---
#pragma unroll
    for (int fm = 0; fm < 4; ++fm) {
        int m = m0 + wc * 64 + fm * 16 + lrow;
        float bv = bias ? bias[m] : 0.f;
        size_t mrow = (size_t)m * 4096;
#pragma unroll
        for (int fn = 0; fn < 4; ++fn) {
            int nb = n0 + wr * 64 + fn * 16 + lk * 4;
            f32x4 a4 = acc[fn][fm];
            if constexpr (sizeof(OT) == 2) {
                ushort4 o;
                o.x = f2bf(a4[0] + bv);
                o.y = f2bf(a4[1] + bv);
                o.z = f2bf(a4[2] + bv);
                o.w = f2bf(a4[3] + bv);
                *(ushort4*)&Ob[mrow + nb] = o;
            } else {
                *(float4*)&Ob[mrow + nb] =
                    make_float4(a4[0] + bv, a4[1] + bv, a4[2] + bv, a4[3] + bv);
            }
        }
    }
}

// ---------------------------------------------------------------------------
// Window attention (bf16 qkv in, f32 out).  grid (1024, nbatch).
// ---------------------------------------------------------------------------
__global__ __launch_bounds__(256)
void attn_kernel(const unsigned short* __restrict__ QKV, const float* __restrict__ RT,
                 float* __restrict__ OutB)
{
    int blk  = blockIdx.x;           // win*16 + head
    int head = blk & 15;
    int win  = blk >> 4;
    int wwi  = win & 7, hhi = win >> 3;
    int b    = blockIdx.y;
    const unsigned short* Q = QKV + (size_t)b * 1536 * 4096;
    float* Out = OutB + (size_t)b * 512 * 4096;

    __shared__ float Qs[64][33];
    __shared__ float Ks[64][33];
    __shared__ float Vs[64][33];
    __shared__ float Ss[64][65];

    int t = threadIdx.x;
    int ch0 = head * 32;
    int sp0 = (hhi * 8) * 64 + wwi * 8;

#pragma unroll
    for (int i = 0; i < 2; ++i) {
        int cidx = i * 256 + t;            // 0..511
        int d    = cidx >> 4;              // 0..31
        int tk0  = (cidx & 15) * 4;        // 0..60
        int sp   = sp0 + ((tk0 >> 3) << 6) + (tk0 & 7);
        ushort4 q4 = *(const ushort4*)&Q[(size_t)(ch0 + d) * 4096 + sp];
        ushort4 k4 = *(const ushort4*)&Q[(size_t)(512 + ch0 + d) * 4096 + sp];
        ushort4 v4 = *(const ushort4*)&Q[(size_t)(1024 + ch0 + d) * 4096 + sp];
        Qs[tk0+0][d] = bf2f(q4.x); Qs[tk0+1][d] = bf2f(q4.y);
        Qs[tk0+2][d] = bf2f(q4.z); Qs[tk0+3][d] = bf2f(q4.w);
        Ks[tk0+0][d] = bf2f(k4.x); Ks[tk0+1][d] = bf2f(k4.y);
        Ks[tk0+2][d] = bf2f(k4.z); Ks[tk0+3][d] = bf2f(k4.w);
        Vs[tk0+0][d] = bf2f(v4.x); Vs[tk0+1][d] = bf2f(v4.y);
        Vs[tk0+2][d] = bf2f(v4.z); Vs[tk0+3][d] = bf2f(v4.w);
    }
    __syncthreads();

    int ti = t >> 2, qq = t & 3;
    float qreg[32];
#pragma unroll
    for (int d = 0; d < 32; ++d) qreg[d] = Qs[ti][d];

    float ev[16];
    float mx = -1e30f;
    int yi = ti >> 3, xi = ti & 7;
#pragma unroll
    for (int jj = 0; jj < 16; ++jj) {
        int j = qq * 16 + jj;
        float s = 0.f;
#pragma unroll
        for (int d = 0; d < 32; ++d) s = fmaf(qreg[d], Ks[j][d], s);
        int yj = j >> 3, xj = j & 7;
        int ridx = ((yi - yj + 7) * 15 + (xi - xj + 7)) * 16 + head;
        s = s * ATT_SCALE + RT[ridx];
        ev[jj] = s;
        mx = fmaxf(mx, s);
    }
    mx = fmaxf(mx, __shfl_xor(mx, 1));
    mx = fmaxf(mx, __shfl_xor(mx, 2));
    float sum = 0.f;
#pragma unroll
    for (int jj = 0; jj < 16; ++jj) {
        ev[jj] = __expf(ev[jj] - mx);
        sum += ev[jj];
    }
    sum += __shfl_xor(sum, 1);
    sum += __shfl_xor(sum, 2);
    float rs = 1.f / sum;
#pragma unroll
    for (int jj = 0; jj < 16; ++jj)
        Ss[ti][qq * 16 + jj] = ev[jj] * rs;
    __syncthreads();

    int r = t & 63, d0 = t >> 6;
    float o[8];
#pragma unroll
    for (int i = 0; i < 8; ++i) o[i] = 0.f;
    for (int j = 0; j < 64; ++j) {
        float sv = Ss[r][j];
#pragma unroll
        for (int i = 0; i < 8; ++i)
            o[i] = fmaf(sv, Vs[j][d0 + 4 * i], o[i]);
    }
    int sp = sp0 + (r >> 3) * 64 + (r & 7);
#pragma unroll
    for (int i = 0; i < 8; ++i) {
        int d = d0 + 4 * i;
        Out[(size_t)(head * 32 + d) * 4096 + sp] = o[i];
    }
}

// ---------------------------------------------------------------------------
// Branch-free fused pool(+local) + depthwise 8x8 + BN3.
// Borders (zero + reflect 64->62) materialized in padded LDS tiles once.
// Interior of apad/tpad at [3+y][4+x] (col offset 4 keeps float4 alignment).
// ---------------------------------------------------------------------------
__global__ __launch_bounds__(256)
void pooldw_kernel(const float* __restrict__ A, const unsigned short* __restrict__ L,
                   const float* __restrict__ Wd,
                   const float* __restrict__ g3, const float* __restrict__ b3,
                   unsigned short* __restrict__ U)
{
    int bc = blockIdx.x;               // b*512 + c
    int c  = bc & 511;
    __shared__ float apad[72][72];
    __shared__ float tpad[72][72];
    __shared__ float wd[64];
    int t = threadIdx.x;
    float* apf = &apad[0][0];
    float* tpf = &tpad[0][0];
#pragma unroll
    for (int i = 0; i < 21; ++i) {
        int e = i * 256 + t;
        if (e < 5184) { apf[e] = 0.f; tpf[e] = 0.f; }
    }
    if (t < 64) wd[t] = Wd[c * 64 + t];
    __syncthreads();

    const float* ap = A + (size_t)bc * 4096;
    const unsigned short* lp = L + (size_t)bc * 4096;
#pragma unroll
    for (int i = 0; i < 4; ++i) {
        int idx = i * 256 + t;             // 1024 float4
        int y = idx >> 4, x4 = (idx & 15) * 4;
        *(float4*)&apad[3 + y][4 + x4] = ((const float4*)ap)[idx];
    }
    if (t < 64)       apad[67][4 + t] = ap[62 * 64 + t];          // row 64 -> 62
    else if (t < 128) { int y = t - 64; apad[3 + y][68] = ap[y * 64 + 62]; }
    else if (t == 128) apad[67][68] = ap[62 * 64 + 62];
    __syncthreads();

    // pool + local -> tpad interior  (all reads lane-consecutive, branch-free)
#pragma unroll
    for (int k = 0; k < 16; ++k) {
        int p = k * 256 + t;
        int h = p >> 6, w = p & 63;
        float sx = 0.f, sy = 0.f;
#pragma unroll
        for (int i = 0; i < 8; ++i) {
            sx += apad[h + i][4 + w];
            sy += apad[3 + h][w + 1 + i];
        }
        tpad[3 + h][4 + w] = fmaf(0.125f, sx + sy, bf2f(lp[p]));
    }
    __syncthreads();
    if (t < 64)       tpad[67][4 + t] = tpad[65][4 + t];
    else if (t < 128) { int y = t - 64; tpad[3 + y][68] = tpad[3 + y][66]; }
    else if (t == 128) tpad[67][68] = tpad[65][66];
    __syncthreads();

    float gc  = g3[c] * INVBN;
    float bcv = b3[c];
#pragma unroll
    for (int k = 0; k < 16; ++k) {
        int p = k * 256 + t;
        int h = p >> 6, w = p & 63;
        float acc = 0.f;
#pragma unroll
        for (int i = 0; i < 8; ++i)
#pragma unroll
            for (int j = 0; j < 8; ++j)
                acc = fmaf(wd[i * 8 + j], tpad[h + i][w + 1 + j], acc);
        U[(size_t)bc * 4096 + p] = f2bf(gc * acc + bcv);
    }
}

// ---------------------------------------------------------------------------
// U (B,512,4096) bf16 -> Ut (B,4096,512) bf16.  64p x 64c LDS tiles.
// ---------------------------------------------------------------------------
__global__ __launch_bounds__(256)
void transpose_cp_kernel(const unsigned short* __restrict__ U, unsigned short* __restrict__ Ut)
{
    int pt = blockIdx.x;               // p-tile 0..63
    int b  = blockIdx.y;
    const unsigned short* Ub = U + (size_t)b * 512 * 4096;
    unsigned short* Utb = Ut + (size_t)b * 4096 * 512;
    __shared__ unsigned short tile[64][72];
    int t = threadIdx.x;
    int p0 = pt * 64;

    for (int cc = 0; cc < 8; ++cc) {
        int c0 = cc * 64;
        __syncthreads();
        {
            int cl = t >> 2, px = (t & 3) * 16;
            const unsigned short* src = &Ub[(size_t)(c0 + cl) * 4096 + p0 + px];
            *(us8v*)&tile[cl][px]     = *(const us8v*)src;
            *(us8v*)&tile[cl][px + 8] = *(const us8v*)(src + 8);
        }
        __syncthreads();
        {
            int pl = t >> 2, cx = (t & 3) * 16;
            us8v o0, o1;
#pragma unroll
            for (int e = 0; e < 8; ++e) {
                o0[e] = tile[cx + e][pl];
                o1[e] = tile[cx + 8 + e][pl];
            }
            unsigned short* dst = &Utb[(size_t)(p0 + pl) * 512 + c0 + cx];
            *(us8v*)dst       = o0;
            *(us8v*)(dst + 8) = o1;
        }
    }
}

// ---------------------------------------------------------------------------
extern "C" void kernel_launch(void* const* d_in, const int* in_sizes, int n_in,
                              void* d_out, int out_size, void* d_ws, size_t ws_size,
                              hipStream_t stream)
{
    (void)in_sizes; (void)n_in; (void)out_size;
    const float* x     = (const float*)d_in[0];
    const float* w_lc1 = (const float*)d_in[1];
    const float* g1    = (const float*)d_in[2];
    const float* b1    = (const float*)d_in[3];
    const float* w_lc2 = (const float*)d_in[4];
    const float* g2    = (const float*)d_in[5];
    const float* b2    = (const float*)d_in[6];
    const float* w_qkv = (const float*)d_in[7];
    const float* rt    = (const float*)d_in[8];
    const float* w_dw  = (const float*)d_in[9];
    const float* g3    = (const float*)d_in[10];
    const float* b3    = (const float*)d_in[11];
    const float* w_pw  = (const float*)d_in[12];
    float* out = (float*)d_out;

    // workspace layout (bf16 short offsets) — sizes audited this round:
    //   local : 16,777,216            [0 .. 16,777,216)
    //   xt    : 8*4356*512 = 17,842,176  [16,777,216 .. 34,619,392)   (aliased by U)
    //   wt3   : 2,359,296             [34,619,392 .. 36,978,688)
    //   wq    :   786,432             [36,978,688 .. 37,765,120)
    //   wpw   :   262,144             [37,765,120 .. 38,027,264)
    //   bsum  : 512 f32 = 1,024       [38,027,264 .. 38,028,288)
    //   qkv   : 6,291,456 (per-batch) or 50,331,648 (full)  [38,028,288 ..)
    unsigned short* S        = (unsigned short*)d_ws;
    unsigned short* local_us = S;
    unsigned short* xt_us    = S + 16777216;
    unsigned short* u_us     = xt_us;                   // alias: U after X_tp dead
    unsigned short* wt3_us   = S + 34619392;
    unsigned short* wq_us    = S + 36978688;
    unsigned short* wpw_us   = S + 37765120;
    float*          bsum     = (float*)(S + 38027264);
    unsigned short* qkv_us   = S + 38028288;
    unsigned short* ut_us    = local_us;                // alias: Ut after local dead

    const bool full = ws_size >= (size_t)(38028288 + 50331648) * 2;  // 176.72 MB

    repack_kernel<<<dim3(9216), 256, 0, stream>>>(w_lc2, w_lc1, w_qkv, w_pw,
                                                  g1, g2, b1, b2,
                                                  wt3_us, wq_us, wpw_us, bsum);
    pad_transpose_kernel<<<dim3(66, 8), 256, 0, stream>>>(x, xt_us);
    mfma_gemm<9, true, unsigned short><<<dim3(32, 4, 8), 256, 0, stream>>>(
        xt_us, wt3_us, bsum, local_us, 512);

    if (full) {
        mfma_gemm<1, true, unsigned short><<<dim3(32, 12, 8), 256, 0, stream>>>(
            xt_us, wq_us, nullptr, qkv_us, 1536);
        attn_kernel<<<dim3(1024, 8), 256, 0, stream>>>(qkv_us, rt, out);
    } else {
        for (int b = 0; b < 8; ++b) {
            mfma_gemm<1, true, unsigned short><<<dim3(32, 12, 1), 256, 0, stream>>>(
                xt_us + (size_t)b * 4356 * 512, wq_us, nullptr, qkv_us, 1536);
            attn_kernel<<<dim3(1024, 1), 256, 0, stream>>>(
                qkv_us, rt, out + (size_t)b * 2097152);
        }
    }

    pooldw_kernel<<<dim3(4096), 256, 0, stream>>>(out, local_us, w_dw, g3, b3, u_us);
    transpose_cp_kernel<<<dim3(64, 8), 256, 0, stream>>>(u_us, ut_us);
    mfma_gemm<1, false, float><<<dim3(32, 4, 8), 256, 0, stream>>>(
        ut_us, wpw_us, nullptr, out, 512);
}

// Round 6
// 648.175 us; speedup vs baseline: 6.8667x; 1.1485x over previous
//
#include <hip/hip_runtime.h>

#define INVBN 0.9999950000374997f       // 1/sqrt(1 + 1e-5)
#define ATT_SCALE 0.17677669529663687f  // 32^-0.5

typedef short bf16x8 __attribute__((ext_vector_type(8)));
typedef float f32x4  __attribute__((ext_vector_type(4)));
typedef unsigned short us8v __attribute__((ext_vector_type(8)));

#define AS1C(p) ((const __attribute__((address_space(1))) void*)(p))
#define AS3(p)  ((__attribute__((address_space(3))) void*)(p))

__device__ __forceinline__ float bf2f(unsigned short u) {
    return __uint_as_float(((unsigned)u) << 16);
}
__device__ __forceinline__ unsigned short f2bf(float f) {
    unsigned u = __float_as_uint(f);
    u += 0x7FFFu + ((u >> 16) & 1u);        // RNE
    return (unsigned short)(u >> 16);
}

// ---------------------------------------------------------------------------
// Repack: Wt3[tap][m][k] bf16 (BN-folded conv3x3 + lc1 into center tap),
// Wq, Wpw bf16, bsum[m] = b1+b2.
// ---------------------------------------------------------------------------
__global__ __launch_bounds__(256)
void repack_kernel(const float* __restrict__ W2, const float* __restrict__ W1,
                   const float* __restrict__ Wq, const float* __restrict__ Wp,
                   const float* __restrict__ g1, const float* __restrict__ g2,
                   const float* __restrict__ b1, const float* __restrict__ b2,
                   unsigned short* __restrict__ Wt, unsigned short* __restrict__ WqO,
                   unsigned short* __restrict__ WpO, float* __restrict__ bsum)
{
    int i = blockIdx.x * 256 + threadIdx.x;
    if (i < 512) bsum[i] = b1[i] + b2[i];
    if (i < 786432) WqO[i] = f2bf(Wq[i]);
    if (i < 262144) WpO[i] = f2bf(Wp[i]);
    if (i >= 2359296) return;
    int tap = i / 262144;
    int rem = i - tap * 262144;          // m*512 + k
    int m   = rem >> 9;
    float v = g2[m] * INVBN * W2[(size_t)rem * 9 + tap];
    if (tap == 4) v = fmaf(g1[m] * INVBN, W1[rem], v);
    Wt[i] = f2bf(v);
}

// ---------------------------------------------------------------------------
// x (B,512,64,64) f32 NCHW  ->  X_tp (B, 66*66, 512) bf16, zero borders.
// ---------------------------------------------------------------------------
__global__ __launch_bounds__(256)
void pad_transpose_kernel(const float* __restrict__ X, unsigned short* __restrict__ XT)
{
    int ph = blockIdx.x;      // 0..65
    int b  = blockIdx.y;
    int t  = threadIdx.x;
    unsigned short* rowbase = XT + ((size_t)b * 4356 + (size_t)ph * 66) * 512;
    uint4 z = make_uint4(0, 0, 0, 0);
    if (ph == 0 || ph == 65) {
        uint4* p4 = (uint4*)rowbase;                 // 66*512 elems = 4224 uint4
        for (int i = t; i < 4224; i += 256) p4[i] = z;
        return;
    }
    if (t < 64)       ((uint4*)rowbase)[t] = z;                  // pw = 0
    else if (t < 128) ((uint4*)(rowbase + 65 * 512))[t - 64] = z; // pw = 65

    int h = ph - 1;
    __shared__ float tile[64][65];
    const float* xb = X + (size_t)b * 512 * 4096 + h * 64;
    for (int cc = 0; cc < 8; ++cc) {
        int c0 = cc * 64;
        __syncthreads();
#pragma unroll
        for (int i = 0; i < 4; ++i) {
            int cl = i * 16 + (t >> 4);
            int w0 = (t & 15) * 4;
            *(float4*)&tile[cl][w0] =
                *(const float4*)&xb[(size_t)(c0 + cl) * 4096 + w0];
        }
        __syncthreads();
#pragma unroll
        for (int it = 0; it < 2; ++it) {
            int wl = it * 32 + (t >> 3);     // w = 0..63  -> pw = wl+1
            int cs = (t & 7) * 8;
            us8v v;
#pragma unroll
            for (int e = 0; e < 8; ++e) v[e] = f2bf(tile[cs + e][wl]);
            *(us8v*)&rowbase[(size_t)(1 + wl) * 512 + c0 + cs] = v;
        }
    }
}

// ---------------------------------------------------------------------------
// MFMA GEMM.  A bf16: PAD ? (B,66*66,512) padded-transposed : (B,4096,512).
// Bw bf16 [NTAPS][M][512].  Out: bf16 or f32 per OT.  128x128 tile, 4 waves.
// ---------------------------------------------------------------------------
template<int NTAPS, bool PAD, typename OT>
__global__ __launch_bounds__(256)
void mfma_gemm(const unsigned short* __restrict__ A,
               const unsigned short* __restrict__ Bw,
               const float* __restrict__ bias,
               OT* __restrict__ Out, int M)
{
    __shared__ short As[128 * 64];
    __shared__ short Bs[128 * 64];

    const int t  = threadIdx.x;
    const int n0 = blockIdx.x * 128;
    const int m0 = blockIdx.y * 128;
    const int b  = blockIdx.z;
    const unsigned short* Ab = A + (size_t)b * (PAD ? 4356 * 512 : 4096 * 512);
    OT* Ob = Out + (size_t)b * ((size_t)M * 4096);

    // --- staging addressing ---
    const int trow = t >> 3;                    // 0..31 (row = i*32 + trow)
    const int csrc = (t & 7) ^ (trow & 7);      // inverse XOR swizzle on source
    const unsigned short* aSrc[4];
    const unsigned short* bSrc[4];
#pragma unroll
    for (int i = 0; i < 4; ++i) {
        int r = i * 32 + trow;
        int p = n0 + r;
        if (PAD) {
            int h = p >> 6, w = p & 63;
            aSrc[i] = Ab + ((size_t)((h + 1) * 66 + (w + 1)) * 512 + csrc * 8);
        } else {
            aSrc[i] = Ab + ((size_t)p * 512 + csrc * 8);
        }
        bSrc[i] = Bw + ((size_t)(m0 + r) * 512 + csrc * 8);
    }
    short* aDst = As + (t & 192) * 8;           // wave-uniform LDS base
    short* bDst = Bs + (t & 192) * 8;

    // --- fragment read offsets (swizzled) ---
    const int lane = t & 63;
    const int wv = t >> 6, wr = wv >> 1, wc = wv & 1;
    const int lrow = lane & 15, lk = lane >> 4;
    int aOff[4][2], bOff[4][2];
#pragma unroll
    for (int f = 0; f < 4; ++f)
#pragma unroll
        for (int kk = 0; kk < 2; ++kk) {
            int ra = wr * 64 + f * 16 + lrow;
            aOff[f][kk] = ra * 64 + ((kk * 4 + lk) ^ (ra & 7)) * 8;
            int rb = wc * 64 + f * 16 + lrow;
            bOff[f][kk] = rb * 64 + ((kk * 4 + lk) ^ (rb & 7)) * 8;
        }

    f32x4 acc[4][4] = {};

#pragma unroll 1
    for (int tap = 0; tap < NTAPS; ++tap) {
        const int dr  = (NTAPS == 9) ? (tap / 3 - 1) : 0;
        const int dsh = (NTAPS == 9) ? (tap % 3 - 1) : 0;
        const int aTapOff = (dr * 66 + dsh) * 512;
        const size_t bTapOff = (size_t)tap * (size_t)M * 512;
#pragma unroll 1
        for (int ks = 0; ks < 8; ++ks) {
            const int k0 = ks * 64;
            __syncthreads();
#pragma unroll
            for (int i = 0; i < 4; ++i) {
                __builtin_amdgcn_global_load_lds(
                    AS1C(aSrc[i] + aTapOff + k0), AS3(aDst + i * 2048), 16, 0, 0);
                __builtin_amdgcn_global_load_lds(
                    AS1C(bSrc[i] + bTapOff + k0), AS3(bDst + i * 2048), 16, 0, 0);
            }
            __syncthreads();
            bf16x8 av[4][2], bv[4][2];
#pragma unroll
            for (int f = 0; f < 4; ++f) {
                av[f][0] = *(const bf16x8*)&As[aOff[f][0]];
                av[f][1] = *(const bf16x8*)&As[aOff[f][1]];
                bv[f][0] = *(const bf16x8*)&Bs[bOff[f][0]];
                bv[f][1] = *(const bf16x8*)&Bs[bOff[f][1]];
            }
#pragma unroll
            for (int kk = 0; kk < 2; ++kk)
#pragma unroll
                for (int fn = 0; fn < 4; ++fn)
#pragma unroll
                    for (int fm = 0; fm < 4; ++fm)
                        acc[fn][fm] = __builtin_amdgcn_mfma_f32_16x16x32_bf16(
                            av[fn][kk], bv[fm][kk], acc[fn][fm], 0, 0, 0);
        }
    }

    // --- epilogue: bias + store (D: col m = lane&15, rows n = lk*4+reg) ---
#pragma unroll
    for (int fm = 0; fm < 4; ++fm) {
        int m = m0 + wc * 64 + fm * 16 + lrow;
        float bv = bias ? bias[m] : 0.f;
        size_t mrow = (size_t)m * 4096;
#pragma unroll
        for (int fn = 0; fn < 4; ++fn) {
            int nb = n0 + wr * 64 + fn * 16 + lk * 4;
            f32x4 a4 = acc[fn][fm];
            if constexpr (sizeof(OT) == 2) {
                ushort4 o;
                o.x = f2bf(a4[0] + bv);
                o.y = f2bf(a4[1] + bv);
                o.z = f2bf(a4[2] + bv);
                o.w = f2bf(a4[3] + bv);
                *(ushort4*)&Ob[mrow + nb] = o;
            } else {
                *(float4*)&Ob[mrow + nb] =
                    make_float4(a4[0] + bv, a4[1] + bv, a4[2] + bv, a4[3] + bv);
            }
        }
    }
}

// ---------------------------------------------------------------------------
// Window attention (bf16 qkv in, f32 out).  grid (1024, nbatch).
// ---------------------------------------------------------------------------
__global__ __launch_bounds__(256)
void attn_kernel(const unsigned short* __restrict__ QKV, const float* __restrict__ RT,
                 float* __restrict__ OutB)
{
    int blk  = blockIdx.x;           // win*16 + head
    int head = blk & 15;
    int win  = blk >> 4;
    int wwi  = win & 7, hhi = win >> 3;
    int b    = blockIdx.y;
    const unsigned short* Q = QKV + (size_t)b * 1536 * 4096;
    float* Out = OutB + (size_t)b * 512 * 4096;

    __shared__ float Qs[64][33];
    __shared__ float Ks[64][33];
    __shared__ float Vs[64][33];
    __shared__ float Ss[64][65];

    int t = threadIdx.x;
    int ch0 = head * 32;
    int sp0 = (hhi * 8) * 64 + wwi * 8;

#pragma unroll
    for (int i = 0; i < 2; ++i) {
        int cidx = i * 256 + t;            // 0..511
        int d    = cidx >> 4;              // 0..31
        int tk0  = (cidx & 15) * 4;        // 0..60
        int sp   = sp0 + ((tk0 >> 3) << 6) + (tk0 & 7);
        ushort4 q4 = *(const ushort4*)&Q[(size_t)(ch0 + d) * 4096 + sp];
        ushort4 k4 = *(const ushort4*)&Q[(size_t)(512 + ch0 + d) * 4096 + sp];
        ushort4 v4 = *(const ushort4*)&Q[(size_t)(1024 + ch0 + d) * 4096 + sp];
        Qs[tk0+0][d] = bf2f(q4.x); Qs[tk0+1][d] = bf2f(q4.y);
        Qs[tk0+2][d] = bf2f(q4.z); Qs[tk0+3][d] = bf2f(q4.w);
        Ks[tk0+0][d] = bf2f(k4.x); Ks[tk0+1][d] = bf2f(k4.y);
        Ks[tk0+2][d] = bf2f(k4.z); Ks[tk0+3][d] = bf2f(k4.w);
        Vs[tk0+0][d] = bf2f(v4.x); Vs[tk0+1][d] = bf2f(v4.y);
        Vs[tk0+2][d] = bf2f(v4.z); Vs[tk0+3][d] = bf2f(v4.w);
    }
    __syncthreads();

    int ti = t >> 2, qq = t & 3;
    float qreg[32];
#pragma unroll
    for (int d = 0; d < 32; ++d) qreg[d] = Qs[ti][d];

    float ev[16];
    float mx = -1e30f;
    int yi = ti >> 3, xi = ti & 7;
#pragma unroll
    for (int jj = 0; jj < 16; ++jj) {
        int j = qq * 16 + jj;
        float s = 0.f;
#pragma unroll
        for (int d = 0; d < 32; ++d) s = fmaf(qreg[d], Ks[j][d], s);
        int yj = j >> 3, xj = j & 7;
        int ridx = ((yi - yj + 7) * 15 + (xi - xj + 7)) * 16 + head;
        s = s * ATT_SCALE + RT[ridx];
        ev[jj] = s;
        mx = fmaxf(mx, s);
    }
    mx = fmaxf(mx, __shfl_xor(mx, 1));
    mx = fmaxf(mx, __shfl_xor(mx, 2));
    float sum = 0.f;
#pragma unroll
    for (int jj = 0; jj < 16; ++jj) {
        ev[jj] = __expf(ev[jj] - mx);
        sum += ev[jj];
    }
    sum += __shfl_xor(sum, 1);
    sum += __shfl_xor(sum, 2);
    float rs = 1.f / sum;
#pragma unroll
    for (int jj = 0; jj < 16; ++jj)
        Ss[ti][qq * 16 + jj] = ev[jj] * rs;
    __syncthreads();

    int r = t & 63, d0 = t >> 6;
    float o[8];
#pragma unroll
    for (int i = 0; i < 8; ++i) o[i] = 0.f;
    for (int j = 0; j < 64; ++j) {
        float sv = Ss[r][j];
#pragma unroll
        for (int i = 0; i < 8; ++i)
            o[i] = fmaf(sv, Vs[j][d0 + 4 * i], o[i]);
    }
    int sp = sp0 + (r >> 3) * 64 + (r & 7);
#pragma unroll
    for (int i = 0; i < 8; ++i) {
        int d = d0 + 4 * i;
        Out[(size_t)(head * 32 + d) * 4096 + sp] = o[i];
    }
}

// ---------------------------------------------------------------------------
// Fused pool(+local) + depthwise 8x8 + BN3, v3: single 72x72 LDS tile,
// 4-wide pixel groups, all LDS traffic as ds_read_b128/ds_write_b128,
// dw weights via wave-uniform global reads (scalar pipe, not LDS).
// Thread t: w-group u = t&15 (w0 = 4u), row-phase rr = t>>4; pixels
// (h = g*16+rr, w = w0..w0+3) for g = 0..3.
// ---------------------------------------------------------------------------
__global__ __launch_bounds__(256)
void pooldw_kernel(const float* __restrict__ A, const unsigned short* __restrict__ L,
                   const float* __restrict__ Wd,
                   const float* __restrict__ g3, const float* __restrict__ b3,
                   unsigned short* __restrict__ U)
{
    int bc = blockIdx.x;               // b*512 + c
    int c  = bc & 511;
    __shared__ float pad[72][72];      // 20.25 KB
    int t = threadIdx.x;
    float* pf = &pad[0][0];
#pragma unroll
    for (int i = 0; i < 21; ++i) {
        int e = i * 256 + t;
        if (e < 5184) pf[e] = 0.f;
    }
    __syncthreads();

    // stage A plane: interior at [3+y][4+x], reflect row 64->62, col 64->62
    const float* ap = A + (size_t)bc * 4096;
#pragma unroll
    for (int i = 0; i < 4; ++i) {
        int idx = i * 256 + t;             // 1024 float4
        int y = idx >> 4, x4 = (idx & 15) * 4;
        *(float4*)&pad[3 + y][4 + x4] = ((const float4*)ap)[idx];
    }
    if (t < 64)       pad[67][4 + t] = ap[62 * 64 + t];
    else if (t < 128) { int y = t - 64; pad[3 + y][68] = ap[y * 64 + 62]; }
    else if (t == 128) pad[67][68] = ap[62 * 64 + 62];
    __syncthreads();

    // pool + local into registers (res[g] = 4 px)
    const unsigned short* lp = L + (size_t)bc * 4096;
    int u  = t & 15, rr = t >> 4;
    int w0 = u * 4;
    float4 res[4];
#pragma unroll
    for (int g = 0; g < 4; ++g) {
        int h = g * 16 + rr;
        float4 sx = make_float4(0.f, 0.f, 0.f, 0.f);
#pragma unroll
        for (int i = 0; i < 8; ++i) {
            float4 v = *(const float4*)&pad[h + i][4 + w0];
            sx.x += v.x; sx.y += v.y; sx.z += v.z; sx.w += v.w;
        }
        float win[12];
        *(float4*)&win[0] = *(const float4*)&pad[3 + h][w0];
        *(float4*)&win[4] = *(const float4*)&pad[3 + h][w0 + 4];
        *(float4*)&win[8] = *(const float4*)&pad[3 + h][w0 + 8];
        float4 sy = make_float4(0.f, 0.f, 0.f, 0.f);
#pragma unroll
        for (int i = 0; i < 8; ++i) {
            sy.x += win[1 + i];
            sy.y += win[2 + i];
            sy.z += win[3 + i];
            sy.w += win[4 + i];
        }
        ushort4 l4 = *(const ushort4*)&lp[h * 64 + w0];
        res[g].x = fmaf(0.125f, sx.x + sy.x, bf2f(l4.x));
        res[g].y = fmaf(0.125f, sx.y + sy.y, bf2f(l4.y));
        res[g].z = fmaf(0.125f, sx.z + sy.z, bf2f(l4.z));
        res[g].w = fmaf(0.125f, sx.w + sy.w, bf2f(l4.w));
    }
    __syncthreads();

    // write pooled values over the same tile interior
#pragma unroll
    for (int g = 0; g < 4; ++g) {
        int h = g * 16 + rr;
        *(float4*)&pad[3 + h][4 + w0] = res[g];
    }
    __syncthreads();
    // refresh reflect borders from pooled values (zero borders still intact)
    if (t < 64)       pad[67][4 + t] = pad[65][4 + t];
    else if (t < 128) { int y = t - 64; pad[3 + y][68] = pad[3 + y][66]; }
    else if (t == 128) pad[67][68] = pad[65][66];
    __syncthreads();

    // depthwise 8x8 + BN3; weights via uniform (scalar) global loads
    const float* wdp = Wd + c * 64;
    float gc  = g3[c] * INVBN;
    float bcv = b3[c];
#pragma unroll
    for (int g = 0; g < 4; ++g) {
        int h = g * 16 + rr;
        float a0 = 0.f, a1 = 0.f, a2 = 0.f, a3 = 0.f;
#pragma unroll
        for (int i = 0; i < 8; ++i) {
            float win[12];
            *(float4*)&win[0] = *(const float4*)&pad[h + i][w0];
            *(float4*)&win[4] = *(const float4*)&pad[h + i][w0 + 4];
            *(float4*)&win[8] = *(const float4*)&pad[h + i][w0 + 8];
#pragma unroll
            for (int j = 0; j < 8; ++j) {
                float wv = wdp[i * 8 + j];
                a0 = fmaf(wv, win[1 + j], a0);
                a1 = fmaf(wv, win[2 + j], a1);
                a2 = fmaf(wv, win[3 + j], a2);
                a3 = fmaf(wv, win[4 + j], a3);
            }
        }
        ushort4 o;
        o.x = f2bf(gc * a0 + bcv);
        o.y = f2bf(gc * a1 + bcv);
        o.z = f2bf(gc * a2 + bcv);
        o.w = f2bf(gc * a3 + bcv);
        *(ushort4*)&U[(size_t)bc * 4096 + h * 64 + w0] = o;
    }
}

// ---------------------------------------------------------------------------
// U (B,512,4096) bf16 -> Ut (B,4096,512) bf16.  64p x 64c LDS tiles.
// ---------------------------------------------------------------------------
__global__ __launch_bounds__(256)
void transpose_cp_kernel(const unsigned short* __restrict__ U, unsigned short* __restrict__ Ut)
{
    int pt = blockIdx.x;               // p-tile 0..63
    int b  = blockIdx.y;
    const unsigned short* Ub = U + (size_t)b * 512 * 4096;
    unsigned short* Utb = Ut + (size_t)b * 4096 * 512;
    __shared__ unsigned short tile[64][72];
    int t = threadIdx.x;
    int p0 = pt * 64;

    for (int cc = 0; cc < 8; ++cc) {
        int c0 = cc * 64;
        __syncthreads();
        {
            int cl = t >> 2, px = (t & 3) * 16;
            const unsigned short* src = &Ub[(size_t)(c0 + cl) * 4096 + p0 + px];
            *(us8v*)&tile[cl][px]     = *(const us8v*)src;
            *(us8v*)&tile[cl][px + 8] = *(const us8v*)(src + 8);
        }
        __syncthreads();
        {
            int pl = t >> 2, cx = (t & 3) * 16;
            us8v o0, o1;
#pragma unroll
            for (int e = 0; e < 8; ++e) {
                o0[e] = tile[cx + e][pl];
                o1[e] = tile[cx + 8 + e][pl];
            }
            unsigned short* dst = &Utb[(size_t)(p0 + pl) * 512 + c0 + cx];
            *(us8v*)dst       = o0;
            *(us8v*)(dst + 8) = o1;
        }
    }
}

// ---------------------------------------------------------------------------
extern "C" void kernel_launch(void* const* d_in, const int* in_sizes, int n_in,
                              void* d_out, int out_size, void* d_ws, size_t ws_size,
                              hipStream_t stream)
{
    (void)in_sizes; (void)n_in; (void)out_size;
    const float* x     = (const float*)d_in[0];
    const float* w_lc1 = (const float*)d_in[1];
    const float* g1    = (const float*)d_in[2];
    const float* b1    = (const float*)d_in[3];
    const float* w_lc2 = (const float*)d_in[4];
    const float* g2    = (const float*)d_in[5];
    const float* b2    = (const float*)d_in[6];
    const float* w_qkv = (const float*)d_in[7];
    const float* rt    = (const float*)d_in[8];
    const float* w_dw  = (const float*)d_in[9];
    const float* g3    = (const float*)d_in[10];
    const float* b3    = (const float*)d_in[11];
    const float* w_pw  = (const float*)d_in[12];
    float* out = (float*)d_out;

    // workspace layout (bf16 short offsets):
    //   local : 16,777,216            [0 .. 16,777,216)
    //   xt    : 8*4356*512 = 17,842,176  [16,777,216 .. 34,619,392)   (aliased by U)
    //   wt3   : 2,359,296             [34,619,392 .. 36,978,688)
    //   wq    :   786,432             [36,978,688 .. 37,765,120)
    //   wpw   :   262,144             [37,765,120 .. 38,027,264)
    //   bsum  : 512 f32 = 1,024       [38,027,264 .. 38,028,288)
    //   qkv   : 6,291,456 (per-batch) or 50,331,648 (full)  [38,028,288 ..)
    unsigned short* S        = (unsigned short*)d_ws;
    unsigned short* local_us = S;
    unsigned short* xt_us    = S + 16777216;
    unsigned short* u_us     = xt_us;                   // alias: U after X_tp dead
    unsigned short* wt3_us   = S + 34619392;
    unsigned short* wq_us    = S + 36978688;
    unsigned short* wpw_us   = S + 37765120;
    float*          bsum     = (float*)(S + 38027264);
    unsigned short* qkv_us   = S + 38028288;
    unsigned short* ut_us    = local_us;                // alias: Ut after local dead

    const bool full = ws_size >= (size_t)(38028288 + 50331648) * 2;  // 176.72 MB

    repack_kernel<<<dim3(9216), 256, 0, stream>>>(w_lc2, w_lc1, w_qkv, w_pw,
                                                  g1, g2, b1, b2,
                                                  wt3_us, wq_us, wpw_us, bsum);
    pad_transpose_kernel<<<dim3(66, 8), 256, 0, stream>>>(x, xt_us);
    mfma_gemm<9, true, unsigned short><<<dim3(32, 4, 8), 256, 0, stream>>>(
        xt_us, wt3_us, bsum, local_us, 512);

    if (full) {
        mfma_gemm<1, true, unsigned short><<<dim3(32, 12, 8), 256, 0, stream>>>(
            xt_us, wq_us, nullptr, qkv_us, 1536);
        attn_kernel<<<dim3(1024, 8), 256, 0, stream>>>(qkv_us, rt, out);
    } else {
        for (int b = 0; b < 8; ++b) {
            mfma_gemm<1, true, unsigned short><<<dim3(32, 12, 1), 256, 0, stream>>>(
                xt_us + (size_t)b * 4356 * 512, wq_us, nullptr, qkv_us, 1536);
            attn_kernel<<<dim3(1024, 1), 256, 0, stream>>>(
                qkv_us, rt, out + (size_t)b * 2097152);
        }
    }

    pooldw_kernel<<<dim3(4096), 256, 0, stream>>>(out, local_us, w_dw, g3, b3, u_us);
    transpose_cp_kernel<<<dim3(64, 8), 256, 0, stream>>>(u_us, ut_us);
    mfma_gemm<1, false, float><<<dim3(32, 4, 8), 256, 0, stream>>>(
        ut_us, wpw_us, nullptr, out, 512);
}

// Round 7
// 513.811 us; speedup vs baseline: 8.6624x; 1.2615x over previous
//
#include <hip/hip_runtime.h>

#define INVBN 0.9999950000374997f       // 1/sqrt(1 + 1e-5)
#define ATT_SCALE 0.17677669529663687f  // 32^-0.5

typedef short bf16x8 __attribute__((ext_vector_type(8)));
typedef float f32x4  __attribute__((ext_vector_type(4)));
typedef unsigned short us8v __attribute__((ext_vector_type(8)));

#define AS1C(p) ((const __attribute__((address_space(1))) void*)(p))
#define AS3(p)  ((__attribute__((address_space(3))) void*)(p))

__device__ __forceinline__ float bf2f(unsigned short u) {
    return __uint_as_float(((unsigned)u) << 16);
}
__device__ __forceinline__ unsigned short f2bf(float f) {
    unsigned u = __float_as_uint(f);
    u += 0x7FFFu + ((u >> 16) & 1u);        // RNE
    return (unsigned short)(u >> 16);
}

// ---------------------------------------------------------------------------
// Repack: Wt3[tap][m][k] bf16 (BN-folded conv3x3 + lc1 into center tap),
// Wq, Wpw bf16, bsum[m] = b1+b2.
// ---------------------------------------------------------------------------
__global__ __launch_bounds__(256)
void repack_kernel(const float* __restrict__ W2, const float* __restrict__ W1,
                   const float* __restrict__ Wq, const float* __restrict__ Wp,
                   const float* __restrict__ g1, const float* __restrict__ g2,
                   const float* __restrict__ b1, const float* __restrict__ b2,
                   unsigned short* __restrict__ Wt, unsigned short* __restrict__ WqO,
                   unsigned short* __restrict__ WpO, float* __restrict__ bsum)
{
    int i = blockIdx.x * 256 + threadIdx.x;
    if (i < 512) bsum[i] = b1[i] + b2[i];
    if (i < 786432) WqO[i] = f2bf(Wq[i]);
    if (i < 262144) WpO[i] = f2bf(Wp[i]);
    if (i >= 2359296) return;
    int tap = i / 262144;
    int rem = i - tap * 262144;          // m*512 + k
    int m   = rem >> 9;
    float v = g2[m] * INVBN * W2[(size_t)rem * 9 + tap];
    if (tap == 4) v = fmaf(g1[m] * INVBN, W1[rem], v);
    Wt[i] = f2bf(v);
}

// ---------------------------------------------------------------------------
// Precompute Swin relative-position bias in the MFMA C-layout:
// biasM[head][fi*4+fj][lane][reg] ; element = bias at
// (k-row = 16*fi + (lane>>4)*4 + reg, q-col = 16*fj + (lane&15)).
// ---------------------------------------------------------------------------
__global__ __launch_bounds__(256)
void bias_precompute_kernel(const float* __restrict__ RT, float* __restrict__ biasM)
{
    int idx = blockIdx.x * 256 + threadIdx.x;      // 0..16383
    int h = idx >> 10, rem = idx & 1023;
    int frag = rem >> 6, lane = rem & 63;
    int fi = frag >> 2, fj = frag & 3;
    int q  = 16 * fj + (lane & 15);
    int kb = 16 * fi + ((lane >> 4) << 2);
    int yi = q >> 3, xi = q & 7;
    float4 o;
    float* op = (float*)&o;
#pragma unroll
    for (int r = 0; r < 4; ++r) {
        int j = kb + r;
        int ridx = (yi - (j >> 3) + 7) * 15 + (xi - (j & 7) + 7);
        op[r] = RT[ridx * 16 + h];
    }
    *(float4*)&biasM[(size_t)idx * 4] = o;
}

// ---------------------------------------------------------------------------
// x (B,512,64,64) f32 NCHW  ->  X_tp (B, 66*66, 512) bf16, zero borders.
// ---------------------------------------------------------------------------
__global__ __launch_bounds__(256)
void pad_transpose_kernel(const float* __restrict__ X, unsigned short* __restrict__ XT)
{
    int ph = blockIdx.x;      // 0..65
    int b  = blockIdx.y;
    int t  = threadIdx.x;
    unsigned short* rowbase = XT + ((size_t)b * 4356 + (size_t)ph * 66) * 512;
    uint4 z = make_uint4(0, 0, 0, 0);
    if (ph == 0 || ph == 65) {
        uint4* p4 = (uint4*)rowbase;                 // 66*512 elems = 4224 uint4
        for (int i = t; i < 4224; i += 256) p4[i] = z;
        return;
    }
    if (t < 64)       ((uint4*)rowbase)[t] = z;                  // pw = 0
    else if (t < 128) ((uint4*)(rowbase + 65 * 512))[t - 64] = z; // pw = 65

    int h = ph - 1;
    __shared__ float tile[64][65];
    const float* xb = X + (size_t)b * 512 * 4096 + h * 64;
    for (int cc = 0; cc < 8; ++cc) {
        int c0 = cc * 64;
        __syncthreads();
#pragma unroll
        for (int i = 0; i < 4; ++i) {
            int cl = i * 16 + (t >> 4);
            int w0 = (t & 15) * 4;
            *(float4*)&tile[cl][w0] =
                *(const float4*)&xb[(size_t)(c0 + cl) * 4096 + w0];
        }
        __syncthreads();
#pragma unroll
        for (int it = 0; it < 2; ++it) {
            int wl = it * 32 + (t >> 3);     // w = 0..63  -> pw = wl+1
            int cs = (t & 7) * 8;
            us8v v;
#pragma unroll
            for (int e = 0; e < 8; ++e) v[e] = f2bf(tile[cs + e][wl]);
            *(us8v*)&rowbase[(size_t)(1 + wl) * 512 + c0 + cs] = v;
        }
    }
}

// ---------------------------------------------------------------------------
// MFMA GEMM.  A bf16: PAD ? (B,66*66,512) padded-transposed : (B,4096,512).
// Bw bf16 [NTAPS][M][512].  Out: bf16 or f32 per OT.  128x128 tile, 4 waves.
// ---------------------------------------------------------------------------
template<int NTAPS, bool PAD, typename OT>
__global__ __launch_bounds__(256)
void mfma_gemm(const unsigned short* __restrict__ A,
               const unsigned short* __restrict__ Bw,
               const float* __restrict__ bias,
               OT* __restrict__ Out, int M)
{
    __shared__ short As[128 * 64];
    __shared__ short Bs[128 * 64];

    const int t  = threadIdx.x;
    const int n0 = blockIdx.x * 128;
    const int m0 = blockIdx.y * 128;
    const int b  = blockIdx.z;
    const unsigned short* Ab = A + (size_t)b * (PAD ? 4356 * 512 : 4096 * 512);
    OT* Ob = Out + (size_t)b * ((size_t)M * 4096);

    // --- staging addressing ---
    const int trow = t >> 3;                    // 0..31 (row = i*32 + trow)
    const int csrc = (t & 7) ^ (trow & 7);      // inverse XOR swizzle on source
    const unsigned short* aSrc[4];
    const unsigned short* bSrc[4];
#pragma unroll
    for (int i = 0; i < 4; ++i) {
        int r = i * 32 + trow;
        int p = n0 + r;
        if (PAD) {
            int h = p >> 6, w = p & 63;
            aSrc[i] = Ab + ((size_t)((h + 1) * 66 + (w + 1)) * 512 + csrc * 8);
        } else {
            aSrc[i] = Ab + ((size_t)p * 512 + csrc * 8);
        }
        bSrc[i] = Bw + ((size_t)(m0 + r) * 512 + csrc * 8);
    }
    short* aDst = As + (t & 192) * 8;           // wave-uniform LDS base
    short* bDst = Bs + (t & 192) * 8;

    // --- fragment read offsets (swizzled) ---
    const int lane = t & 63;
    const int wv = t >> 6, wr = wv >> 1, wc = wv & 1;
    const int lrow = lane & 15, lk = lane >> 4;
    int aOff[4][2], bOff[4][2];
#pragma unroll
    for (int f = 0; f < 4; ++f)
#pragma unroll
        for (int kk = 0; kk < 2; ++kk) {
            int ra = wr * 64 + f * 16 + lrow;
            aOff[f][kk] = ra * 64 + ((kk * 4 + lk) ^ (ra & 7)) * 8;
            int rb = wc * 64 + f * 16 + lrow;
            bOff[f][kk] = rb * 64 + ((kk * 4 + lk) ^ (rb & 7)) * 8;
        }

    f32x4 acc[4][4] = {};

#pragma unroll 1
    for (int tap = 0; tap < NTAPS; ++tap) {
        const int dr  = (NTAPS == 9) ? (tap / 3 - 1) : 0;
        const int dsh = (NTAPS == 9) ? (tap % 3 - 1) : 0;
        const int aTapOff = (dr * 66 + dsh) * 512;
        const size_t bTapOff = (size_t)tap * (size_t)M * 512;
#pragma unroll 1
        for (int ks = 0; ks < 8; ++ks) {
            const int k0 = ks * 64;
            __syncthreads();
#pragma unroll
            for (int i = 0; i < 4; ++i) {
                __builtin_amdgcn_global_load_lds(
                    AS1C(aSrc[i] + aTapOff + k0), AS3(aDst + i * 2048), 16, 0, 0);
                __builtin_amdgcn_global_load_lds(
                    AS1C(bSrc[i] + bTapOff + k0), AS3(bDst + i * 2048), 16, 0, 0);
            }
            __syncthreads();
            bf16x8 av[4][2], bv[4][2];
#pragma unroll
            for (int f = 0; f < 4; ++f) {
                av[f][0] = *(const bf16x8*)&As[aOff[f][0]];
                av[f][1] = *(const bf16x8*)&As[aOff[f][1]];
                bv[f][0] = *(const bf16x8*)&Bs[bOff[f][0]];
                bv[f][1] = *(const bf16x8*)&Bs[bOff[f][1]];
            }
#pragma unroll
            for (int kk = 0; kk < 2; ++kk)
#pragma unroll
                for (int fn = 0; fn < 4; ++fn)
#pragma unroll
                    for (int fm = 0; fm < 4; ++fm)
                        acc[fn][fm] = __builtin_amdgcn_mfma_f32_16x16x32_bf16(
                            av[fn][kk], bv[fm][kk], acc[fn][fm], 0, 0, 0);
        }
    }

    // --- epilogue: bias + store (D: col m = lane&15, rows n = lk*4+reg) ---
#pragma unroll
    for (int fm = 0; fm < 4; ++fm) {
        int m = m0 + wc * 64 + fm * 16 + lrow;
        float bv = bias ? bias[m] : 0.f;
        size_t mrow = (size_t)m * 4096;
#pragma unroll
        for (int fn = 0; fn < 4; ++fn) {
            int nb = n0 + wr * 64 + fn * 16 + lk * 4;
            f32x4 a4 = acc[fn][fm];
            if constexpr (sizeof(OT) == 2) {
                ushort4 o;
                o.x = f2bf(a4[0] + bv);
                o.y = f2bf(a4[1] + bv);
                o.z = f2bf(a4[2] + bv);
                o.w = f2bf(a4[3] + bv);
                *(ushort4*)&Ob[mrow + nb] = o;
            } else {
                *(float4*)&Ob[mrow + nb] =
                    make_float4(a4[0] + bv, a4[1] + bv, a4[2] + bv, a4[3] + bv);
            }
        }
    }
}

// ---------------------------------------------------------------------------
// MFMA window attention: 1 wave per (window, head), 4 waves/block, no barriers.
// S^T = mfma(K, Q) (swapped operands -> softmax axis is lane-local+xor16/32);
// P packed bf16 -> LDS; O^T = mfma(V^T-from-global, P^T-from-LDS).
// grid (256, nbatch): blockIdx.x = wing(6b)<<2 | headgrp(2b).
// ---------------------------------------------------------------------------
__global__ __launch_bounds__(256)
void attn_mfma_kernel(const unsigned short* __restrict__ QKV,
                      const float* __restrict__ biasM,
                      float* __restrict__ OutB)
{
    __shared__ short smem[4 * 9216];
    int t = threadIdx.x;
    int wv = t >> 6, lane = t & 63;
    int wing = blockIdx.x >> 2;
    int head = (blockIdx.x & 3) * 4 + wv;
    int b    = blockIdx.y;
    int hhi = wing >> 3, wwi = wing & 7;
    int sp0 = hhi * 512 + wwi * 8;
    int ch0 = head * 32;
    const unsigned short* Qg = QKV + (size_t)b * 1536 * 4096;

    short* Qtm = smem + wv * 9216;     // [64][36] token-major Q
    short* Ktm = Qtm + 2304;           // [64][36] token-major K
    short* Pq  = Qtm + 4608;           // [64][72] P (q-major)

    // ---- stage Q, K token-major ----
    {
        int d  = lane & 31;
        int rb = lane >> 5;
#pragma unroll
        for (int i = 0; i < 4; ++i) {
            int r = rb + 2 * i;        // window row 0..7
            us8v q8 = *(const us8v*)&Qg[(size_t)(ch0 + d) * 4096 + sp0 + r * 64];
            us8v k8 = *(const us8v*)&Qg[(size_t)(512 + ch0 + d) * 4096 + sp0 + r * 64];
#pragma unroll
            for (int e = 0; e < 8; ++e) {
                Qtm[(r * 8 + e) * 36 + d] = (short)q8[e];
                Ktm[(r * 8 + e) * 36 + d] = (short)k8[e];
            }
        }
    }

    int lrow = lane & 15, lk = lane >> 4;

    // ---- S^T = K . Q^T  (k-dim = 32 channels, single mfma each) ----
    bf16x8 kf[4], qf[4];
#pragma unroll
    for (int f = 0; f < 4; ++f) {
        kf[f] = *(const bf16x8*)&Ktm[(lrow + 16 * f) * 36 + lk * 8];
        qf[f] = *(const bf16x8*)&Qtm[(lrow + 16 * f) * 36 + lk * 8];
    }
    f32x4 s[4][4] = {};
#pragma unroll
    for (int fi = 0; fi < 4; ++fi)
#pragma unroll
        for (int fj = 0; fj < 4; ++fj)
            s[fi][fj] = __builtin_amdgcn_mfma_f32_16x16x32_bf16(
                kf[fi], qf[fj], s[fi][fj], 0, 0, 0);

    // ---- softmax over k (rows of S^T) per q-column fragment fj ----
    const float* bM = biasM + (size_t)head * 4096;
    float rs[4];
#pragma unroll
    for (int fj = 0; fj < 4; ++fj) {
        float v[4][4];
#pragma unroll
        for (int fi = 0; fi < 4; ++fi) {
            float4 bv = *(const float4*)&bM[((fi * 4 + fj) * 64 + lane) * 4];
            const float* bvp = (const float*)&bv;
#pragma unroll
            for (int r = 0; r < 4; ++r)
                v[fi][r] = fmaf(s[fi][fj][r], ATT_SCALE, bvp[r]);
        }
        float m = -1e30f;
#pragma unroll
        for (int fi = 0; fi < 4; ++fi)
#pragma unroll
            for (int r = 0; r < 4; ++r) m = fmaxf(m, v[fi][r]);
        m = fmaxf(m, __shfl_xor(m, 16));
        m = fmaxf(m, __shfl_xor(m, 32));
        float ev[4][4];
        float sum = 0.f;
#pragma unroll
        for (int fi = 0; fi < 4; ++fi)
#pragma unroll
            for (int r = 0; r < 4; ++r) {
                ev[fi][r] = __expf(v[fi][r] - m);
                sum += ev[fi][r];
            }
        sum += __shfl_xor(sum, 16);
        sum += __shfl_xor(sum, 32);
        rs[fj] = 1.f / sum;
        // pack to bf16, write P[q][k] (k = 16*fi + lk*4 + r)
#pragma unroll
        for (int fi = 0; fi < 4; ++fi) {
            unsigned p0 = (unsigned)f2bf(ev[fi][0]) | ((unsigned)f2bf(ev[fi][1]) << 16);
            unsigned p1 = (unsigned)f2bf(ev[fi][2]) | ((unsigned)f2bf(ev[fi][3]) << 16);
            *(uint2*)&Pq[(lrow + 16 * fj) * 72 + 16 * fi + lk * 4] = make_uint2(p0, p1);
        }
    }

    // ---- O^T = V^T . P^T ----
    f32x4 o[2][4] = {};
#pragma unroll
    for (int ks = 0; ks < 2; ++ks) {
        bf16x8 vf[2], pf[4];
#pragma unroll
        for (int fid = 0; fid < 2; ++fid)
            vf[fid] = *(const bf16x8*)&Qg[(size_t)(1024 + ch0 + 16 * fid + lrow) * 4096
                                          + sp0 + (lk + 4 * ks) * 64];
#pragma unroll
        for (int fjq = 0; fjq < 4; ++fjq)
            pf[fjq] = *(const bf16x8*)&Pq[(lrow + 16 * fjq) * 72 + ks * 32 + lk * 8];
#pragma unroll
        for (int fid = 0; fid < 2; ++fid)
#pragma unroll
            for (int fjq = 0; fjq < 4; ++fjq)
                o[fid][fjq] = __builtin_amdgcn_mfma_f32_16x16x32_bf16(
                    vf[fid], pf[fjq], o[fid][fjq], 0, 0, 0);
    }

    // ---- epilogue: deferred softmax normalization + scatter store ----
    float* Out = OutB + (size_t)b * 512 * 4096;
#pragma unroll
    for (int fjq = 0; fjq < 4; ++fjq) {
        int q  = lrow + 16 * fjq;
        int sp = sp0 + ((q >> 3) << 6) + (q & 7);
        float rr = rs[fjq];
#pragma unroll
        for (int fid = 0; fid < 2; ++fid)
#pragma unroll
            for (int r = 0; r < 4; ++r) {
                int dch = 16 * fid + lk * 4 + r;
                Out[(size_t)(ch0 + dch) * 4096 + sp] = o[fid][fjq][r] * rr;
            }
    }
}

// ---------------------------------------------------------------------------
// Fused pool(+local) + depthwise 8x8 + BN3: single 72x72 LDS tile,
// 4-wide pixel groups, b128 LDS traffic, dw weights via scalar loads.
// ---------------------------------------------------------------------------
__global__ __launch_bounds__(256)
void pooldw_kernel(const float* __restrict__ A, const unsigned short* __restrict__ L,
                   const float* __restrict__ Wd,
                   const float* __restrict__ g3, const float* __restrict__ b3,
                   unsigned short* __restrict__ U)
{
    int bc = blockIdx.x;               // b*512 + c
    int c  = bc & 511;
    __shared__ float pad[72][72];      // 20.25 KB
    int t = threadIdx.x;
    float* pf = &pad[0][0];
#pragma unroll
    for (int i = 0; i < 21; ++i) {
        int e = i * 256 + t;
        if (e < 5184) pf[e] = 0.f;
    }
    __syncthreads();

    const float* ap = A + (size_t)bc * 4096;
#pragma unroll
    for (int i = 0; i < 4; ++i) {
        int idx = i * 256 + t;             // 1024 float4
        int y = idx >> 4, x4 = (idx & 15) * 4;
        *(float4*)&pad[3 + y][4 + x4] = ((const float4*)ap)[idx];
    }
    if (t < 64)       pad[67][4 + t] = ap[62 * 64 + t];
    else if (t < 128) { int y = t - 64; pad[3 + y][68] = ap[y * 64 + 62]; }
    else if (t == 128) pad[67][68] = ap[62 * 64 + 62];
    __syncthreads();

    const unsigned short* lp = L + (size_t)bc * 4096;
    int u  = t & 15, rr = t >> 4;
    int w0 = u * 4;
    float4 res[4];
#pragma unroll
    for (int g = 0; g < 4; ++g) {
        int h = g * 16 + rr;
        float4 sx = make_float4(0.f, 0.f, 0.f, 0.f);
#pragma unroll
        for (int i = 0; i < 8; ++i) {
            float4 v = *(const float4*)&pad[h + i][4 + w0];
            sx.x += v.x; sx.y += v.y; sx.z += v.z; sx.w += v.w;
        }
        float win[12];
        *(float4*)&win[0] = *(const float4*)&pad[3 + h][w0];
        *(float4*)&win[4] = *(const float4*)&pad[3 + h][w0 + 4];
        *(float4*)&win[8] = *(const float4*)&pad[3 + h][w0 + 8];
        float4 sy = make_float4(0.f, 0.f, 0.f, 0.f);
#pragma unroll
        for (int i = 0; i < 8; ++i) {
            sy.x += win[1 + i];
            sy.y += win[2 + i];
            sy.z += win[3 + i];
            sy.w += win[4 + i];
        }
        ushort4 l4 = *(const ushort4*)&lp[h * 64 + w0];
        res[g].x = fmaf(0.125f, sx.x + sy.x, bf2f(l4.x));
        res[g].y = fmaf(0.125f, sx.y + sy.y, bf2f(l4.y));
        res[g].z = fmaf(0.125f, sx.z + sy.z, bf2f(l4.z));
        res[g].w = fmaf(0.125f, sx.w + sy.w, bf2f(l4.w));
    }
    __syncthreads();

#pragma unroll
    for (int g = 0; g < 4; ++g) {
        int h = g * 16 + rr;
        *(float4*)&pad[3 + h][4 + w0] = res[g];
    }
    __syncthreads();
    if (t < 64)       pad[67][4 + t] = pad[65][4 + t];
    else if (t < 128) { int y = t - 64; pad[3 + y][68] = pad[3 + y][66]; }
    else if (t == 128) pad[67][68] = pad[65][66];
    __syncthreads();

    const float* wdp = Wd + c * 64;
    float gc  = g3[c] * INVBN;
    float bcv = b3[c];
#pragma unroll
    for (int g = 0; g < 4; ++g) {
        int h = g * 16 + rr;
        float a0 = 0.f, a1 = 0.f, a2 = 0.f, a3 = 0.f;
#pragma unroll
        for (int i = 0; i < 8; ++i) {
            float win[12];
            *(float4*)&win[0] = *(const float4*)&pad[h + i][w0];
            *(float4*)&win[4] = *(const float4*)&pad[h + i][w0 + 4];
            *(float4*)&win[8] = *(const float4*)&pad[h + i][w0 + 8];
#pragma unroll
            for (int j = 0; j < 8; ++j) {
                float wv = wdp[i * 8 + j];
                a0 = fmaf(wv, win[1 + j], a0);
                a1 = fmaf(wv, win[2 + j], a1);
                a2 = fmaf(wv, win[3 + j], a2);
                a3 = fmaf(wv, win[4 + j], a3);
            }
        }
        ushort4 o;
        o.x = f2bf(gc * a0 + bcv);
        o.y = f2bf(gc * a1 + bcv);
        o.z = f2bf(gc * a2 + bcv);
        o.w = f2bf(gc * a3 + bcv);
        *(ushort4*)&U[(size_t)bc * 4096 + h * 64 + w0] = o;
    }
}

// ---------------------------------------------------------------------------
// U (B,512,4096) bf16 -> Ut (B,4096,512) bf16.  64p x 64c LDS tiles.
// ---------------------------------------------------------------------------
__global__ __launch_bounds__(256)
void transpose_cp_kernel(const unsigned short* __restrict__ U, unsigned short* __restrict__ Ut)
{
    int pt = blockIdx.x;               // p-tile 0..63
    int b  = blockIdx.y;
    const unsigned short* Ub = U + (size_t)b * 512 * 4096;
    unsigned short* Utb = Ut + (size_t)b * 4096 * 512;
    __shared__ unsigned short tile[64][72];
    int t = threadIdx.x;
    int p0 = pt * 64;

    for (int cc = 0; cc < 8; ++cc) {
        int c0 = cc * 64;
        __syncthreads();
        {
            int cl = t >> 2, px = (t & 3) * 16;
            const unsigned short* src = &Ub[(size_t)(c0 + cl) * 4096 + p0 + px];
            *(us8v*)&tile[cl][px]     = *(const us8v*)src;
            *(us8v*)&tile[cl][px + 8] = *(const us8v*)(src + 8);
        }
        __syncthreads();
        {
            int pl = t >> 2, cx = (t & 3) * 16;
            us8v o0, o1;
#pragma unroll
            for (int e = 0; e < 8; ++e) {
                o0[e] = tile[cx + e][pl];
                o1[e] = tile[cx + 8 + e][pl];
            }
            unsigned short* dst = &Utb[(size_t)(p0 + pl) * 512 + c0 + cx];
            *(us8v*)dst       = o0;
            *(us8v*)(dst + 8) = o1;
        }
    }
}

// ---------------------------------------------------------------------------
extern "C" void kernel_launch(void* const* d_in, const int* in_sizes, int n_in,
                              void* d_out, int out_size, void* d_ws, size_t ws_size,
                              hipStream_t stream)
{
    (void)in_sizes; (void)n_in; (void)out_size;
    const float* x     = (const float*)d_in[0];
    const float* w_lc1 = (const float*)d_in[1];
    const float* g1    = (const float*)d_in[2];
    const float* b1    = (const float*)d_in[3];
    const float* w_lc2 = (const float*)d_in[4];
    const float* g2    = (const float*)d_in[5];
    const float* b2    = (const float*)d_in[6];
    const float* w_qkv = (const float*)d_in[7];
    const float* rt    = (const float*)d_in[8];
    const float* w_dw  = (const float*)d_in[9];
    const float* g3    = (const float*)d_in[10];
    const float* b3    = (const float*)d_in[11];
    const float* w_pw  = (const float*)d_in[12];
    float* out = (float*)d_out;

    // workspace layout (bf16 short offsets):
    //   local : 16,777,216            [0 .. 16,777,216)
    //   xt    : 8*4356*512 = 17,842,176  [16,777,216 .. 34,619,392)   (aliased by U)
    //   wt3   : 2,359,296             [34,619,392 .. 36,978,688)
    //   wq    :   786,432             [36,978,688 .. 37,765,120)
    //   wpw   :   262,144             [37,765,120 .. 38,027,264)
    //   bsum  : 512 f32 = 1,024       [38,027,264 .. 38,028,288)
    //   biasM : 262,144 f32 = 524,288 [38,028,288 .. 38,552,576)
    //   qkv   : 6,291,456 (per-batch) or 50,331,648 (full)  [38,552,576 ..)
    unsigned short* S        = (unsigned short*)d_ws;
    unsigned short* local_us = S;
    unsigned short* xt_us    = S + 16777216;
    unsigned short* u_us     = xt_us;                   // alias: U after X_tp dead
    unsigned short* wt3_us   = S + 34619392;
    unsigned short* wq_us    = S + 36978688;
    unsigned short* wpw_us   = S + 37765120;
    float*          bsum     = (float*)(S + 38027264);
    float*          biasM    = (float*)(S + 38028288);
    unsigned short* qkv_us   = S + 38552576;
    unsigned short* ut_us    = local_us;                // alias: Ut after local dead

    const bool full = ws_size >= (size_t)(38552576 + 50331648) * 2;  // 177.77 MB

    repack_kernel<<<dim3(9216), 256, 0, stream>>>(w_lc2, w_lc1, w_qkv, w_pw,
                                                  g1, g2, b1, b2,
                                                  wt3_us, wq_us, wpw_us, bsum);
    bias_precompute_kernel<<<dim3(64), 256, 0, stream>>>(rt, biasM);
    pad_transpose_kernel<<<dim3(66, 8), 256, 0, stream>>>(x, xt_us);
    mfma_gemm<9, true, unsigned short><<<dim3(32, 4, 8), 256, 0, stream>>>(
        xt_us, wt3_us, bsum, local_us, 512);

    if (full) {
        mfma_gemm<1, true, unsigned short><<<dim3(32, 12, 8), 256, 0, stream>>>(
            xt_us, wq_us, nullptr, qkv_us, 1536);
        attn_mfma_kernel<<<dim3(256, 8), 256, 0, stream>>>(qkv_us, biasM, out);
    } else {
        for (int b = 0; b < 8; ++b) {
            mfma_gemm<1, true, unsigned short><<<dim3(32, 12, 1), 256, 0, stream>>>(
                xt_us + (size_t)b * 4356 * 512, wq_us, nullptr, qkv_us, 1536);
            attn_mfma_kernel<<<dim3(256, 1), 256, 0, stream>>>(
                qkv_us, biasM, out + (size_t)b * 2097152);
        }
    }

    pooldw_kernel<<<dim3(4096), 256, 0, stream>>>(out, local_us, w_dw, g3, b3, u_us);
    transpose_cp_kernel<<<dim3(64, 8), 256, 0, stream>>>(u_us, ut_us);
    mfma_gemm<1, false, float><<<dim3(32, 4, 8), 256, 0, stream>>>(
        ut_us, wpw_us, nullptr, out, 512);
}

// Round 8
// 475.892 us; speedup vs baseline: 9.3526x; 1.0797x over previous
//
#include <hip/hip_runtime.h>

#define INVBN 0.9999950000374997f       // 1/sqrt(1 + 1e-5)
#define ATT_SCALE 0.17677669529663687f  // 32^-0.5

typedef short bf16x8 __attribute__((ext_vector_type(8)));
typedef float f32x4  __attribute__((ext_vector_type(4)));
typedef unsigned short us8v __attribute__((ext_vector_type(8)));

#define AS1C(p) ((const __attribute__((address_space(1))) void*)(p))
#define AS3(p)  ((__attribute__((address_space(3))) void*)(p))

#define VMCNT_BARRIER(Nstr) do {                                   \
    asm volatile("s_waitcnt vmcnt(" Nstr ")" ::: "memory");        \
    __builtin_amdgcn_s_barrier(); } while (0)

__device__ __forceinline__ float bf2f(unsigned short u) {
    return __uint_as_float(((unsigned)u) << 16);
}
__device__ __forceinline__ unsigned short f2bf(float f) {
    unsigned u = __float_as_uint(f);
    u += 0x7FFFu + ((u >> 16) & 1u);        // RNE
    return (unsigned short)(u >> 16);
}

// ---------------------------------------------------------------------------
// Repack: Wt3[tap][m][k] bf16 (BN-folded conv3x3 + lc1 into center tap),
// Wq, Wpw bf16, bsum[m] = b1+b2.
// ---------------------------------------------------------------------------
__global__ __launch_bounds__(256)
void repack_kernel(const float* __restrict__ W2, const float* __restrict__ W1,
                   const float* __restrict__ Wq, const float* __restrict__ Wp,
                   const float* __restrict__ g1, const float* __restrict__ g2,
                   const float* __restrict__ b1, const float* __restrict__ b2,
                   unsigned short* __restrict__ Wt, unsigned short* __restrict__ WqO,
                   unsigned short* __restrict__ WpO, float* __restrict__ bsum)
{
    int i = blockIdx.x * 256 + threadIdx.x;
    if (i < 512) bsum[i] = b1[i] + b2[i];
    if (i < 786432) WqO[i] = f2bf(Wq[i]);
    if (i < 262144) WpO[i] = f2bf(Wp[i]);
    if (i >= 2359296) return;
    int tap = i / 262144;
    int rem = i - tap * 262144;          // m*512 + k
    int m   = rem >> 9;
    float v = g2[m] * INVBN * W2[(size_t)rem * 9 + tap];
    if (tap == 4) v = fmaf(g1[m] * INVBN, W1[rem], v);
    Wt[i] = f2bf(v);
}

// ---------------------------------------------------------------------------
// Precompute Swin relative-position bias in the MFMA C-layout.
// ---------------------------------------------------------------------------
__global__ __launch_bounds__(256)
void bias_precompute_kernel(const float* __restrict__ RT, float* __restrict__ biasM)
{
    int idx = blockIdx.x * 256 + threadIdx.x;      // 0..16383
    int h = idx >> 10, rem = idx & 1023;
    int frag = rem >> 6, lane = rem & 63;
    int fi = frag >> 2, fj = frag & 3;
    int q  = 16 * fj + (lane & 15);
    int kb = 16 * fi + ((lane >> 4) << 2);
    int yi = q >> 3, xi = q & 7;
    float4 o;
    float* op = (float*)&o;
#pragma unroll
    for (int r = 0; r < 4; ++r) {
        int j = kb + r;
        int ridx = (yi - (j >> 3) + 7) * 15 + (xi - (j & 7) + 7);
        op[r] = RT[ridx * 16 + h];
    }
    *(float4*)&biasM[(size_t)idx * 4] = o;
}

// ---------------------------------------------------------------------------
// x (B,512,64,64) f32 NCHW  ->  X_tp (B, 66*66, 512) bf16, zero borders.
// ---------------------------------------------------------------------------
__global__ __launch_bounds__(256)
void pad_transpose_kernel(const float* __restrict__ X, unsigned short* __restrict__ XT)
{
    int ph = blockIdx.x;      // 0..65
    int b  = blockIdx.y;
    int t  = threadIdx.x;
    unsigned short* rowbase = XT + ((size_t)b * 4356 + (size_t)ph * 66) * 512;
    uint4 z = make_uint4(0, 0, 0, 0);
    if (ph == 0 || ph == 65) {
        uint4* p4 = (uint4*)rowbase;                 // 66*512 elems = 4224 uint4
        for (int i = t; i < 4224; i += 256) p4[i] = z;
        return;
    }
    if (t < 64)       ((uint4*)rowbase)[t] = z;                  // pw = 0
    else if (t < 128) ((uint4*)(rowbase + 65 * 512))[t - 64] = z; // pw = 65

    int h = ph - 1;
    __shared__ float tile[64][65];
    const float* xb = X + (size_t)b * 512 * 4096 + h * 64;
    for (int cc = 0; cc < 8; ++cc) {
        int c0 = cc * 64;
        __syncthreads();
#pragma unroll
        for (int i = 0; i < 4; ++i) {
            int cl = i * 16 + (t >> 4);
            int w0 = (t & 15) * 4;
            *(float4*)&tile[cl][w0] =
                *(const float4*)&xb[(size_t)(c0 + cl) * 4096 + w0];
        }
        __syncthreads();
#pragma unroll
        for (int it = 0; it < 2; ++it) {
            int wl = it * 32 + (t >> 3);     // w = 0..63  -> pw = wl+1
            int cs = (t & 7) * 8;
            us8v v;
#pragma unroll
            for (int e = 0; e < 8; ++e) v[e] = f2bf(tile[cs + e][wl]);
            *(us8v*)&rowbase[(size_t)(1 + wl) * 512 + c0 + cs] = v;
        }
    }
}

// ---------------------------------------------------------------------------
// Deep-pipelined 256x256 MFMA GEMM (T3+T4+T5).  A bf16 padded-transposed
// (B,66*66,512); Bw bf16 [NTAPS][M][512]; out bf16.
// 8 waves (512 thr), BK=32, 4 LDS buffers (128 KiB), 1 block/CU.
// Per K-tile: 1 stage (4x16B gload_lds/thread) + vmcnt(8) + barrier.
// BK=32 -> 64B LDS rows: 16 consecutive rows tile all 32 banks -> fragment
// ds_read_b128 naturally conflict-free, linear gload_lds dest (no swizzle).
// ---------------------------------------------------------------------------
template<int NTAPS>
__global__ __launch_bounds__(512, 2)
void mfma_gemm256(const unsigned short* __restrict__ A,
                  const unsigned short* __restrict__ Bw,
                  const float* __restrict__ bias,
                  unsigned short* __restrict__ Out, int M)
{
    __shared__ __align__(16) unsigned short ldsbuf[65536];   // 128 KiB

    const int t    = threadIdx.x;
    const int wid  = t >> 6, lane = t & 63;
    const int wr   = wid >> 2, wc = wid & 3;          // wave n-half / m-quarter
    const int lrow = lane & 15, lk = lane >> 4;
    const int n0 = blockIdx.x * 256;
    const int m0 = blockIdx.y * 256;
    const int b  = blockIdx.z;
    const unsigned short* Ab = A + (size_t)b * (4356 * 512);
    unsigned short* Ob = Out + (size_t)b * ((size_t)M * 4096);

    // --- staging source pointers: waves 0-3 stage A (256 spatial rows),
    //     waves 4-7 stage B (256 weight rows); thread covers (row, chunk) ---
    const unsigned short* src[4];
    {
        int rsub = lane >> 2, ch = lane & 3;
#pragma unroll
        for (int i = 0; i < 4; ++i) {
            if (wid < 4) {
                int p = n0 + (wid * 4 + i) * 16 + rsub;
                int h = p >> 6, w = p & 63;
                src[i] = Ab + (size_t)((h + 1) * 66 + (w + 1)) * 512 + ch * 8;
            } else {
                int m = m0 + ((wid - 4) * 4 + i) * 16 + rsub;
                src[i] = Bw + (size_t)m * 512 + ch * 8;
            }
        }
    }

    f32x4 acc[8][4] = {};

    auto aScal = [&](int tt) -> int {
        if (NTAPS == 1) return tt * 32;
        int tap = tt >> 4;
        return (tap / 3 - 1) * (66 * 512) + (tap % 3 - 1) * 512 + (tt & 15) * 32;
    };
    auto bScal = [&](int tt) -> int {
        if (NTAPS == 1) return tt * 32;
        return (tt >> 4) * (M * 512) + (tt & 15) * 32;
    };
    auto STAGE = [&](int bufk, int aoff, int boff) {
        int off = (wid < 4) ? aoff : boff;
#pragma unroll
        for (int i = 0; i < 4; ++i)
            __builtin_amdgcn_global_load_lds(
                AS1C(src[i] + off),
                AS3(&ldsbuf[bufk * 16384 + (wid * 4 + i) * 512]), 16, 0, 0);
    };
    auto COMPUTE = [&](int bufk) {
        const unsigned short* Ak = &ldsbuf[bufk * 16384];
        const unsigned short* Bk = &ldsbuf[bufk * 16384 + 8192];
        bf16x8 af[8], bfr[4];
#pragma unroll
        for (int f = 0; f < 8; ++f)
            af[f] = *(const bf16x8*)&Ak[(wr * 128 + f * 16 + lrow) * 32 + lk * 8];
#pragma unroll
        for (int g = 0; g < 4; ++g)
            bfr[g] = *(const bf16x8*)&Bk[(wc * 64 + g * 16 + lrow) * 32 + lk * 8];
        __builtin_amdgcn_s_setprio(1);
#pragma unroll
        for (int f = 0; f < 8; ++f)
#pragma unroll
            for (int g = 0; g < 4; ++g)
                acc[f][g] = __builtin_amdgcn_mfma_f32_16x16x32_bf16(
                    af[f], bfr[g], acc[f][g], 0, 0, 0);
        __builtin_amdgcn_s_setprio(0);
    };

    constexpr int NT = NTAPS * 16;               // K-tiles of 32

    // prologue: stage tiles 0,1,2; wait tile0 (outstanding: tiles 1,2 = 8)
    STAGE(0, aScal(0), bScal(0));
    STAGE(1, aScal(1), bScal(1));
    STAGE(2, aScal(2), bScal(2));
    VMCNT_BARRIER("8");

    // steady state: compute tile t (buf t%4), stage tile t+3 (buf (t+3)%4,
    // freed by the barrier ending tile t-1); end wait = tiles t+2,t+3 in
    // flight (8 loads) -> tile t+1 ready.
#pragma unroll 1
    for (int tb = 0; tb < NT - 4; tb += 4) {
        STAGE(3, aScal(tb + 3), bScal(tb + 3)); COMPUTE(0); VMCNT_BARRIER("8");
        STAGE(0, aScal(tb + 4), bScal(tb + 4)); COMPUTE(1); VMCNT_BARRIER("8");
        STAGE(1, aScal(tb + 5), bScal(tb + 5)); COMPUTE(2); VMCNT_BARRIER("8");
        STAGE(2, aScal(tb + 6), bScal(tb + 6)); COMPUTE(3); VMCNT_BARRIER("8");
    }
    // tail: tiles NT-4..NT-1 (NT ≡ 0 mod 4), drain 8 -> 4 -> 0
    STAGE(3, aScal(NT - 1), bScal(NT - 1)); COMPUTE(0); VMCNT_BARRIER("8");
    COMPUTE(1); VMCNT_BARRIER("4");
    COMPUTE(2); VMCNT_BARRIER("0");
    COMPUTE(3);

    // --- epilogue: bias + bf16 store (D: col m uses lrow, rows n use lk*4+r)
#pragma unroll
    for (int g = 0; g < 4; ++g) {
        int m = m0 + wc * 64 + g * 16 + lrow;
        float bv = bias ? bias[m] : 0.f;
        size_t mrow = (size_t)m * 4096;
#pragma unroll
        for (int f = 0; f < 8; ++f) {
            int nb = n0 + wr * 128 + f * 16 + lk * 4;
            f32x4 a4 = acc[f][g];
            ushort4 o;
            o.x = f2bf(a4[0] + bv);
            o.y = f2bf(a4[1] + bv);
            o.z = f2bf(a4[2] + bv);
            o.w = f2bf(a4[3] + bv);
            *(ushort4*)&Ob[mrow + nb] = o;
        }
    }
}

// ---------------------------------------------------------------------------
// 128x128 MFMA GEMM (proven m97-style) — kept for the final 1x1 (f32 out).
// A bf16 (B,4096,512) linear.
// ---------------------------------------------------------------------------
__global__ __launch_bounds__(256)
void mfma_gemm_f32out(const unsigned short* __restrict__ A,
                      const unsigned short* __restrict__ Bw,
                      float* __restrict__ Out, int M)
{
    __shared__ short As[128 * 64];
    __shared__ short Bs[128 * 64];

    const int t  = threadIdx.x;
    const int n0 = blockIdx.x * 128;
    const int m0 = blockIdx.y * 128;
    const int b  = blockIdx.z;
    const unsigned short* Ab = A + (size_t)b * (4096 * 512);
    float* Ob = Out + (size_t)b * ((size_t)M * 4096);

    const int trow = t >> 3;
    const int csrc = (t & 7) ^ (trow & 7);
    const unsigned short* aSrc[4];
    const unsigned short* bSrc[4];
#pragma unroll
    for (int i = 0; i < 4; ++i) {
        int r = i * 32 + trow;
        aSrc[i] = Ab + ((size_t)(n0 + r) * 512 + csrc * 8);
        bSrc[i] = Bw + ((size_t)(m0 + r) * 512 + csrc * 8);
    }
    short* aDst = As + (t & 192) * 8;
    short* bDst = Bs + (t & 192) * 8;

    const int lane = t & 63;
    const int wv = t >> 6, wr = wv >> 1, wc = wv & 1;
    const int lrow = lane & 15, lk = lane >> 4;
    int aOff[4][2], bOff[4][2];
#pragma unroll
    for (int f = 0; f < 4; ++f)
#pragma unroll
        for (int kk = 0; kk < 2; ++kk) {
            int ra = wr * 64 + f * 16 + lrow;
            aOff[f][kk] = ra * 64 + ((kk * 4 + lk) ^ (ra & 7)) * 8;
            int rb = wc * 64 + f * 16 + lrow;
            bOff[f][kk] = rb * 64 + ((kk * 4 + lk) ^ (rb & 7)) * 8;
        }

    f32x4 acc[4][4] = {};

#pragma unroll 1
    for (int ks = 0; ks < 8; ++ks) {
        const int k0 = ks * 64;
        __syncthreads();
#pragma unroll
        for (int i = 0; i < 4; ++i) {
            __builtin_amdgcn_global_load_lds(
                AS1C(aSrc[i] + k0), AS3(aDst + i * 2048), 16, 0, 0);
            __builtin_amdgcn_global_load_lds(
                AS1C(bSrc[i] + k0), AS3(bDst + i * 2048), 16, 0, 0);
        }
        __syncthreads();
        bf16x8 av[4][2], bv[4][2];
#pragma unroll
        for (int f = 0; f < 4; ++f) {
            av[f][0] = *(const bf16x8*)&As[aOff[f][0]];
            av[f][1] = *(const bf16x8*)&As[aOff[f][1]];
            bv[f][0] = *(const bf16x8*)&Bs[bOff[f][0]];
            bv[f][1] = *(const bf16x8*)&Bs[bOff[f][1]];
        }
#pragma unroll
        for (int kk = 0; kk < 2; ++kk)
#pragma unroll
            for (int fn = 0; fn < 4; ++fn)
#pragma unroll
                for (int fm = 0; fm < 4; ++fm)
                    acc[fn][fm] = __builtin_amdgcn_mfma_f32_16x16x32_bf16(
                        av[fn][kk], bv[fm][kk], acc[fn][fm], 0, 0, 0);
    }

#pragma unroll
    for (int fm = 0; fm < 4; ++fm) {
        int m = m0 + wc * 64 + fm * 16 + lrow;
        size_t mrow = (size_t)m * 4096;
#pragma unroll
        for (int fn = 0; fn < 4; ++fn) {
            int nb = n0 + wr * 64 + fn * 16 + lk * 4;
            f32x4 a4 = acc[fn][fm];
            *(float4*)&Ob[mrow + nb] = make_float4(a4[0], a4[1], a4[2], a4[3]);
        }
    }
}

// ---------------------------------------------------------------------------
// MFMA window attention: 1 wave per (window, head), 4 waves/block.
// ---------------------------------------------------------------------------
__global__ __launch_bounds__(256)
void attn_mfma_kernel(const unsigned short* __restrict__ QKV,
                      const float* __restrict__ biasM,
                      float* __restrict__ OutB)
{
    __shared__ short smem[4 * 9216];
    int t = threadIdx.x;
    int wv = t >> 6, lane = t & 63;
    int wing = blockIdx.x >> 2;
    int head = (blockIdx.x & 3) * 4 + wv;
    int b    = blockIdx.y;
    int hhi = wing >> 3, wwi = wing & 7;
    int sp0 = hhi * 512 + wwi * 8;
    int ch0 = head * 32;
    const unsigned short* Qg = QKV + (size_t)b * 1536 * 4096;

    short* Qtm = smem + wv * 9216;     // [64][36] token-major Q
    short* Ktm = Qtm + 2304;           // [64][36] token-major K
    short* Pq  = Qtm + 4608;           // [64][72] P (q-major)

    {
        int d  = lane & 31;
        int rb = lane >> 5;
#pragma unroll
        for (int i = 0; i < 4; ++i) {
            int r = rb + 2 * i;        // window row 0..7
            us8v q8 = *(const us8v*)&Qg[(size_t)(ch0 + d) * 4096 + sp0 + r * 64];
            us8v k8 = *(const us8v*)&Qg[(size_t)(512 + ch0 + d) * 4096 + sp0 + r * 64];
#pragma unroll
            for (int e = 0; e < 8; ++e) {
                Qtm[(r * 8 + e) * 36 + d] = (short)q8[e];
                Ktm[(r * 8 + e) * 36 + d] = (short)k8[e];
            }
        }
    }

    int lrow = lane & 15, lk = lane >> 4;

    bf16x8 kf[4], qf[4];
#pragma unroll
    for (int f = 0; f < 4; ++f) {
        kf[f] = *(const bf16x8*)&Ktm[(lrow + 16 * f) * 36 + lk * 8];
        qf[f] = *(const bf16x8*)&Qtm[(lrow + 16 * f) * 36 + lk * 8];
    }
    f32x4 s[4][4] = {};
#pragma unroll
    for (int fi = 0; fi < 4; ++fi)
#pragma unroll
        for (int fj = 0; fj < 4; ++fj)
            s[fi][fj] = __builtin_amdgcn_mfma_f32_16x16x32_bf16(
                kf[fi], qf[fj], s[fi][fj], 0, 0, 0);

    const float* bM = biasM + (size_t)head * 4096;
    float rs[4];
#pragma unroll
    for (int fj = 0; fj < 4; ++fj) {
        float v[4][4];
#pragma unroll
        for (int fi = 0; fi < 4; ++fi) {
            float4 bv = *(const float4*)&bM[((fi * 4 + fj) * 64 + lane) * 4];
            const float* bvp = (const float*)&bv;
#pragma unroll
            for (int r = 0; r < 4; ++r)
                v[fi][r] = fmaf(s[fi][fj][r], ATT_SCALE, bvp[r]);
        }
        float m = -1e30f;
#pragma unroll
        for (int fi = 0; fi < 4; ++fi)
#pragma unroll
            for (int r = 0; r < 4; ++r) m = fmaxf(m, v[fi][r]);
        m = fmaxf(m, __shfl_xor(m, 16));
        m = fmaxf(m, __shfl_xor(m, 32));
        float ev[4][4];
        float sum = 0.f;
#pragma unroll
        for (int fi = 0; fi < 4; ++fi)
#pragma unroll
            for (int r = 0; r < 4; ++r) {
                ev[fi][r] = __expf(v[fi][r] - m);
                sum += ev[fi][r];
            }
        sum += __shfl_xor(sum, 16);
        sum += __shfl_xor(sum, 32);
        rs[fj] = 1.f / sum;
#pragma unroll
        for (int fi = 0; fi < 4; ++fi) {
            unsigned p0 = (unsigned)f2bf(ev[fi][0]) | ((unsigned)f2bf(ev[fi][1]) << 16);
            unsigned p1 = (unsigned)f2bf(ev[fi][2]) | ((unsigned)f2bf(ev[fi][3]) << 16);
            *(uint2*)&Pq[(lrow + 16 * fj) * 72 + 16 * fi + lk * 4] = make_uint2(p0, p1);
        }
    }

    f32x4 o[2][4] = {};
#pragma unroll
    for (int ks = 0; ks < 2; ++ks) {
        bf16x8 vf[2], pf[4];
#pragma unroll
        for (int fid = 0; fid < 2; ++fid)
            vf[fid] = *(const bf16x8*)&Qg[(size_t)(1024 + ch0 + 16 * fid + lrow) * 4096
                                          + sp0 + (lk + 4 * ks) * 64];
#pragma unroll
        for (int fjq = 0; fjq < 4; ++fjq)
            pf[fjq] = *(const bf16x8*)&Pq[(lrow + 16 * fjq) * 72 + ks * 32 + lk * 8];
#pragma unroll
        for (int fid = 0; fid < 2; ++fid)
#pragma unroll
            for (int fjq = 0; fjq < 4; ++fjq)
                o[fid][fjq] = __builtin_amdgcn_mfma_f32_16x16x32_bf16(
                    vf[fid], pf[fjq], o[fid][fjq], 0, 0, 0);
    }

    float* Out = OutB + (size_t)b * 512 * 4096;
#pragma unroll
    for (int fjq = 0; fjq < 4; ++fjq) {
        int q  = lrow + 16 * fjq;
        int sp = sp0 + ((q >> 3) << 6) + (q & 7);
        float rr = rs[fjq];
#pragma unroll
        for (int fid = 0; fid < 2; ++fid)
#pragma unroll
            for (int r = 0; r < 4; ++r) {
                int dch = 16 * fid + lk * 4 + r;
                Out[(size_t)(ch0 + dch) * 4096 + sp] = o[fid][fjq][r] * rr;
            }
    }
}

// ---------------------------------------------------------------------------
// Fused pool(+local) + depthwise 8x8 + BN3: single 72x72 LDS tile,
// 4-wide pixel groups, b128 LDS traffic, dw weights via scalar loads.
// ---------------------------------------------------------------------------
__global__ __launch_bounds__(256)
void pooldw_kernel(const float* __restrict__ A, const unsigned short* __restrict__ L,
                   const float* __restrict__ Wd,
                   const float* __restrict__ g3, const float* __restrict__ b3,
                   unsigned short* __restrict__ U)
{
    int bc = blockIdx.x;               // b*512 + c
    int c  = bc & 511;
    __shared__ float pad[72][72];      // 20.25 KB
    int t = threadIdx.x;
    float* pf = &pad[0][0];
#pragma unroll
    for (int i = 0; i < 21; ++i) {
        int e = i * 256 + t;
        if (e < 5184) pf[e] = 0.f;
    }
    __syncthreads();

    const float* ap = A + (size_t)bc * 4096;
#pragma unroll
    for (int i = 0; i < 4; ++i) {
        int idx = i * 256 + t;             // 1024 float4
        int y = idx >> 4, x4 = (idx & 15) * 4;
        *(float4*)&pad[3 + y][4 + x4] = ((const float4*)ap)[idx];
    }
    if (t < 64)       pad[67][4 + t] = ap[62 * 64 + t];
    else if (t < 128) { int y = t - 64; pad[3 + y][68] = ap[y * 64 + 62]; }
    else if (t == 128) pad[67][68] = ap[62 * 64 + 62];
    __syncthreads();

    const unsigned short* lp = L + (size_t)bc * 4096;
    int u  = t & 15, rr = t >> 4;
    int w0 = u * 4;
    float4 res[4];
#pragma unroll
    for (int g = 0; g < 4; ++g) {
        int h = g * 16 + rr;
        float4 sx = make_float4(0.f, 0.f, 0.f, 0.f);
#pragma unroll
        for (int i = 0; i < 8; ++i) {
            float4 v = *(const float4*)&pad[h + i][4 + w0];
            sx.x += v.x; sx.y += v.y; sx.z += v.z; sx.w += v.w;
        }
        float win[12];
        *(float4*)&win[0] = *(const float4*)&pad[3 + h][w0];
        *(float4*)&win[4] = *(const float4*)&pad[3 + h][w0 + 4];
        *(float4*)&win[8] = *(const float4*)&pad[3 + h][w0 + 8];
        float4 sy = make_float4(0.f, 0.f, 0.f, 0.f);
#pragma unroll
        for (int i = 0; i < 8; ++i) {
            sy.x += win[1 + i];
            sy.y += win[2 + i];
            sy.z += win[3 + i];
            sy.w += win[4 + i];
        }
        ushort4 l4 = *(const ushort4*)&lp[h * 64 + w0];
        res[g].x = fmaf(0.125f, sx.x + sy.x, bf2f(l4.x));
        res[g].y = fmaf(0.125f, sx.y + sy.y, bf2f(l4.y));
        res[g].z = fmaf(0.125f, sx.z + sy.z, bf2f(l4.z));
        res[g].w = fmaf(0.125f, sx.w + sy.w, bf2f(l4.w));
    }
    __syncthreads();

#pragma unroll
    for (int g = 0; g < 4; ++g) {
        int h = g * 16 + rr;
        *(float4*)&pad[3 + h][4 + w0] = res[g];
    }
    __syncthreads();
    if (t < 64)       pad[67][4 + t] = pad[65][4 + t];
    else if (t < 128) { int y = t - 64; pad[3 + y][68] = pad[3 + y][66]; }
    else if (t == 128) pad[67][68] = pad[65][66];
    __syncthreads();

    const float* wdp = Wd + c * 64;
    float gc  = g3[c] * INVBN;
    float bcv = b3[c];
#pragma unroll
    for (int g = 0; g < 4; ++g) {
        int h = g * 16 + rr;
        float a0 = 0.f, a1 = 0.f, a2 = 0.f, a3 = 0.f;
#pragma unroll
        for (int i = 0; i < 8; ++i) {
            float win[12];
            *(float4*)&win[0] = *(const float4*)&pad[h + i][w0];
            *(float4*)&win[4] = *(const float4*)&pad[h + i][w0 + 4];
            *(float4*)&win[8] = *(const float4*)&pad[h + i][w0 + 8];
#pragma unroll
            for (int j = 0; j < 8; ++j) {
                float wv = wdp[i * 8 + j];
                a0 = fmaf(wv, win[1 + j], a0);
                a1 = fmaf(wv, win[2 + j], a1);
                a2 = fmaf(wv, win[3 + j], a2);
                a3 = fmaf(wv, win[4 + j], a3);
            }
        }
        ushort4 o;
        o.x = f2bf(gc * a0 + bcv);
        o.y = f2bf(gc * a1 + bcv);
        o.z = f2bf(gc * a2 + bcv);
        o.w = f2bf(gc * a3 + bcv);
        *(ushort4*)&U[(size_t)bc * 4096 + h * 64 + w0] = o;
    }
}

// ---------------------------------------------------------------------------
// U (B,512,4096) bf16 -> Ut (B,4096,512) bf16.  64p x 64c LDS tiles.
// ---------------------------------------------------------------------------
__global__ __launch_bounds__(256)
void transpose_cp_kernel(const unsigned short* __restrict__ U, unsigned short* __restrict__ Ut)
{
    int pt = blockIdx.x;               // p-tile 0..63
    int b  = blockIdx.y;
    const unsigned short* Ub = U + (size_t)b * 512 * 4096;
    unsigned short* Utb = Ut + (size_t)b * 4096 * 512;
    __shared__ unsigned short tile[64][72];
    int t = threadIdx.x;
    int p0 = pt * 64;

    for (int cc = 0; cc < 8; ++cc) {
        int c0 = cc * 64;
        __syncthreads();
        {
            int cl = t >> 2, px = (t & 3) * 16;
            const unsigned short* src = &Ub[(size_t)(c0 + cl) * 4096 + p0 + px];
            *(us8v*)&tile[cl][px]     = *(const us8v*)src;
            *(us8v*)&tile[cl][px + 8] = *(const us8v*)(src + 8);
        }
        __syncthreads();
        {
            int pl = t >> 2, cx = (t & 3) * 16;
            us8v o0, o1;
#pragma unroll
            for (int e = 0; e < 8; ++e) {
                o0[e] = tile[cx + e][pl];
                o1[e] = tile[cx + 8 + e][pl];
            }
            unsigned short* dst = &Utb[(size_t)(p0 + pl) * 512 + c0 + cx];
            *(us8v*)dst       = o0;
            *(us8v*)(dst + 8) = o1;
        }
    }
}

// ---------------------------------------------------------------------------
extern "C" void kernel_launch(void* const* d_in, const int* in_sizes, int n_in,
                              void* d_out, int out_size, void* d_ws, size_t ws_size,
                              hipStream_t stream)
{
    (void)in_sizes; (void)n_in; (void)out_size;
    const float* x     = (const float*)d_in[0];
    const float* w_lc1 = (const float*)d_in[1];
    const float* g1    = (const float*)d_in[2];
    const float* b1    = (const float*)d_in[3];
    const float* w_lc2 = (const float*)d_in[4];
    const float* g2    = (const float*)d_in[5];
    const float* b2    = (const float*)d_in[6];
    const float* w_qkv = (const float*)d_in[7];
    const float* rt    = (const float*)d_in[8];
    const float* w_dw  = (const float*)d_in[9];
    const float* g3    = (const float*)d_in[10];
    const float* b3    = (const float*)d_in[11];
    const float* w_pw  = (const float*)d_in[12];
    float* out = (float*)d_out;

    // workspace layout (bf16 short offsets):
    //   local : 16,777,216            [0 .. 16,777,216)
    //   xt    : 8*4356*512 = 17,842,176  [16,777,216 .. 34,619,392)   (aliased by U)
    //   wt3   : 2,359,296             [34,619,392 .. 36,978,688)
    //   wq    :   786,432             [36,978,688 .. 37,765,120)
    //   wpw   :   262,144             [37,765,120 .. 38,027,264)
    //   bsum  : 512 f32 = 1,024       [38,027,264 .. 38,028,288)
    //   biasM : 262,144 f32 = 524,288 [38,028,288 .. 38,552,576)
    //   qkv   : 6,291,456 (per-batch) or 50,331,648 (full)  [38,552,576 ..)
    unsigned short* S        = (unsigned short*)d_ws;
    unsigned short* local_us = S;
    unsigned short* xt_us    = S + 16777216;
    unsigned short* u_us     = xt_us;                   // alias: U after X_tp dead
    unsigned short* wt3_us   = S + 34619392;
    unsigned short* wq_us    = S + 36978688;
    unsigned short* wpw_us   = S + 37765120;
    float*          bsum     = (float*)(S + 38027264);
    float*          biasM    = (float*)(S + 38028288);
    unsigned short* qkv_us   = S + 38552576;
    unsigned short* ut_us    = local_us;                // alias: Ut after local dead

    const bool full = ws_size >= (size_t)(38552576 + 50331648) * 2;  // 177.77 MB

    repack_kernel<<<dim3(9216), 256, 0, stream>>>(w_lc2, w_lc1, w_qkv, w_pw,
                                                  g1, g2, b1, b2,
                                                  wt3_us, wq_us, wpw_us, bsum);
    bias_precompute_kernel<<<dim3(64), 256, 0, stream>>>(rt, biasM);
    pad_transpose_kernel<<<dim3(66, 8), 256, 0, stream>>>(x, xt_us);
    mfma_gemm256<9><<<dim3(16, 2, 8), 512, 0, stream>>>(
        xt_us, wt3_us, bsum, local_us, 512);

    if (full) {
        mfma_gemm256<1><<<dim3(16, 6, 8), 512, 0, stream>>>(
            xt_us, wq_us, nullptr, qkv_us, 1536);
        attn_mfma_kernel<<<dim3(256, 8), 256, 0, stream>>>(qkv_us, biasM, out);
    } else {
        for (int b = 0; b < 8; ++b) {
            mfma_gemm256<1><<<dim3(16, 6, 1), 512, 0, stream>>>(
                xt_us + (size_t)b * 4356 * 512, wq_us, nullptr, qkv_us, 1536);
            attn_mfma_kernel<<<dim3(256, 1), 256, 0, stream>>>(
                qkv_us, biasM, out + (size_t)b * 2097152);
        }
    }

    pooldw_kernel<<<dim3(4096), 256, 0, stream>>>(out, local_us, w_dw, g3, b3, u_us);
    transpose_cp_kernel<<<dim3(64, 8), 256, 0, stream>>>(u_us, ut_us);
    mfma_gemm_f32out<<<dim3(32, 4, 8), 256, 0, stream>>>(
        ut_us, wpw_us, out, 512);
}

// Round 9
// 473.898 us; speedup vs baseline: 9.3920x; 1.0042x over previous
//
#include <hip/hip_runtime.h>

#define INVBN 0.9999950000374997f       // 1/sqrt(1 + 1e-5)
#define ATT_SCALE 0.17677669529663687f  // 32^-0.5

typedef short bf16x8 __attribute__((ext_vector_type(8)));
typedef float f32x4  __attribute__((ext_vector_type(4)));
typedef unsigned short us8v __attribute__((ext_vector_type(8)));

#define AS1C(p) ((const __attribute__((address_space(1))) void*)(p))
#define AS3(p)  ((__attribute__((address_space(3))) void*)(p))

#define VMCNT_BARRIER(Nstr) do {                                   \
    asm volatile("s_waitcnt vmcnt(" Nstr ")" ::: "memory");        \
    __builtin_amdgcn_s_barrier(); } while (0)

__device__ __forceinline__ float bf2f(unsigned short u) {
    return __uint_as_float(((unsigned)u) << 16);
}
__device__ __forceinline__ unsigned short f2bf(float f) {
    unsigned u = __float_as_uint(f);
    u += 0x7FFFu + ((u >> 16) & 1u);        // RNE
    return (unsigned short)(u >> 16);
}

// ---------------------------------------------------------------------------
// Repack: Wt3[tap][m][k] bf16 (BN-folded conv3x3 + lc1 into center tap),
// Wq, Wpw bf16, bsum[m] = b1+b2.
// ---------------------------------------------------------------------------
__global__ __launch_bounds__(256)
void repack_kernel(const float* __restrict__ W2, const float* __restrict__ W1,
                   const float* __restrict__ Wq, const float* __restrict__ Wp,
                   const float* __restrict__ g1, const float* __restrict__ g2,
                   const float* __restrict__ b1, const float* __restrict__ b2,
                   unsigned short* __restrict__ Wt, unsigned short* __restrict__ WqO,
                   unsigned short* __restrict__ WpO, float* __restrict__ bsum)
{
    int i = blockIdx.x * 256 + threadIdx.x;
    if (i < 512) bsum[i] = b1[i] + b2[i];
    if (i < 786432) WqO[i] = f2bf(Wq[i]);
    if (i < 262144) WpO[i] = f2bf(Wp[i]);
    if (i >= 2359296) return;
    int tap = i / 262144;
    int rem = i - tap * 262144;          // m*512 + k
    int m   = rem >> 9;
    float v = g2[m] * INVBN * W2[(size_t)rem * 9 + tap];
    if (tap == 4) v = fmaf(g1[m] * INVBN, W1[rem], v);
    Wt[i] = f2bf(v);
}

// ---------------------------------------------------------------------------
// Precompute Swin relative-position bias in the MFMA C-layout.
// ---------------------------------------------------------------------------
__global__ __launch_bounds__(256)
void bias_precompute_kernel(const float* __restrict__ RT, float* __restrict__ biasM)
{
    int idx = blockIdx.x * 256 + threadIdx.x;      // 0..16383
    int h = idx >> 10, rem = idx & 1023;
    int frag = rem >> 6, lane = rem & 63;
    int fi = frag >> 2, fj = frag & 3;
    int q  = 16 * fj + (lane & 15);
    int kb = 16 * fi + ((lane >> 4) << 2);
    int yi = q >> 3, xi = q & 7;
    float4 o;
    float* op = (float*)&o;
#pragma unroll
    for (int r = 0; r < 4; ++r) {
        int j = kb + r;
        int ridx = (yi - (j >> 3) + 7) * 15 + (xi - (j & 7) + 7);
        op[r] = RT[ridx * 16 + h];
    }
    *(float4*)&biasM[(size_t)idx * 4] = o;
}

// ---------------------------------------------------------------------------
// x (B,512,64,64) f32 NCHW  ->  X_tp (B, 66*66, 512) bf16, zero borders.
// ---------------------------------------------------------------------------
__global__ __launch_bounds__(256)
void pad_transpose_kernel(const float* __restrict__ X, unsigned short* __restrict__ XT)
{
    int ph = blockIdx.x;      // 0..65
    int b  = blockIdx.y;
    int t  = threadIdx.x;
    unsigned short* rowbase = XT + ((size_t)b * 4356 + (size_t)ph * 66) * 512;
    uint4 z = make_uint4(0, 0, 0, 0);
    if (ph == 0 || ph == 65) {
        uint4* p4 = (uint4*)rowbase;                 // 66*512 elems = 4224 uint4
        for (int i = t; i < 4224; i += 256) p4[i] = z;
        return;
    }
    if (t < 64)       ((uint4*)rowbase)[t] = z;                  // pw = 0
    else if (t < 128) ((uint4*)(rowbase + 65 * 512))[t - 64] = z; // pw = 65

    int h = ph - 1;
    __shared__ float tile[64][65];
    const float* xb = X + (size_t)b * 512 * 4096 + h * 64;
    for (int cc = 0; cc < 8; ++cc) {
        int c0 = cc * 64;
        __syncthreads();
#pragma unroll
        for (int i = 0; i < 4; ++i) {
            int cl = i * 16 + (t >> 4);
            int w0 = (t & 15) * 4;
            *(float4*)&tile[cl][w0] =
                *(const float4*)&xb[(size_t)(c0 + cl) * 4096 + w0];
        }
        __syncthreads();
#pragma unroll
        for (int it = 0; it < 2; ++it) {
            int wl = it * 32 + (t >> 3);     // w = 0..63  -> pw = wl+1
            int cs = (t & 7) * 8;
            us8v v;
#pragma unroll
            for (int e = 0; e < 8; ++e) v[e] = f2bf(tile[cs + e][wl]);
            *(us8v*)&rowbase[(size_t)(1 + wl) * 512 + c0 + cs] = v;
        }
    }
}

// ---------------------------------------------------------------------------
// Deep-pipelined 256x256 MFMA GEMM (T3+T4+T5).  A bf16 padded-transposed
// (B,66*66,512); Bw bf16 [NTAPS][M][512]; out bf16.
// 8 waves (512 thr), BK=32, 4 LDS buffers (128 KiB), 1 block/CU.
// Chunk XOR-swizzle sigma(r) = (r>>1)&3 within each 16-row block (rule #21:
// pre-swizzled GLOBAL source + swizzled ds_read; LDS dest stays linear) ->
// fragment ds_read_b128 covers all 8 bank-groups (2-way = free).
// ---------------------------------------------------------------------------
template<int NTAPS>
__global__ __launch_bounds__(512, 2)
void mfma_gemm256(const unsigned short* __restrict__ A,
                  const unsigned short* __restrict__ Bw,
                  const float* __restrict__ bias,
                  unsigned short* __restrict__ Out, int M)
{
    __shared__ __align__(16) unsigned short ldsbuf[65536];   // 128 KiB

    const int t    = threadIdx.x;
    const int wid  = t >> 6, lane = t & 63;
    const int wr   = wid >> 2, wc = wid & 3;          // wave n-half / m-quarter
    const int lrow = lane & 15, lk = lane >> 4;
    const int n0 = blockIdx.x * 256;
    const int m0 = blockIdx.y * 256;
    const int b  = blockIdx.z;
    const unsigned short* Ab = A + (size_t)b * (4356 * 512);
    unsigned short* Ob = Out + (size_t)b * ((size_t)M * 4096);

    // --- staging source pointers: waves 0-3 stage A (256 spatial rows),
    //     waves 4-7 stage B (256 weight rows).  Source chunk pre-swizzled:
    //     LDS slot (rsub, ch) receives global chunk ch ^ sigma(rsub). ---
    const unsigned short* src[4];
    {
        int rsub = lane >> 2, ch = lane & 3;
        int chs  = ch ^ ((rsub >> 1) & 3);            // inverse swizzle on source
#pragma unroll
        for (int i = 0; i < 4; ++i) {
            if (wid < 4) {
                int p = n0 + (wid * 4 + i) * 16 + rsub;
                int h = p >> 6, w = p & 63;
                src[i] = Ab + (size_t)((h + 1) * 66 + (w + 1)) * 512 + chs * 8;
            } else {
                int m = m0 + ((wid - 4) * 4 + i) * 16 + rsub;
                src[i] = Bw + (size_t)m * 512 + chs * 8;
            }
        }
    }

    f32x4 acc[8][4] = {};

    // fragment chunk indices (swizzled reads)
    const int ck0 = (lk ^ ((lrow >> 1) & 3)) * 8;

    auto aScal = [&](int tt) -> int {
        if (NTAPS == 1) return tt * 32;
        int tap = tt >> 4;
        return (tap / 3 - 1) * (66 * 512) + (tap % 3 - 1) * 512 + (tt & 15) * 32;
    };
    auto bScal = [&](int tt) -> int {
        if (NTAPS == 1) return tt * 32;
        return (tt >> 4) * (M * 512) + (tt & 15) * 32;
    };
    auto STAGE = [&](int bufk, int aoff, int boff) {
        int off = (wid < 4) ? aoff : boff;
#pragma unroll
        for (int i = 0; i < 4; ++i)
            __builtin_amdgcn_global_load_lds(
                AS1C(src[i] + off),
                AS3(&ldsbuf[bufk * 16384 + (wid * 4 + i) * 512]), 16, 0, 0);
    };
    auto COMPUTE = [&](int bufk) {
        const unsigned short* Ak = &ldsbuf[bufk * 16384];
        const unsigned short* Bk = &ldsbuf[bufk * 16384 + 8192];
        bf16x8 af[8], bfr[4];
#pragma unroll
        for (int f = 0; f < 8; ++f)
            af[f] = *(const bf16x8*)&Ak[(wr * 128 + f * 16 + lrow) * 32 + ck0];
#pragma unroll
        for (int g = 0; g < 4; ++g)
            bfr[g] = *(const bf16x8*)&Bk[(wc * 64 + g * 16 + lrow) * 32 + ck0];
        __builtin_amdgcn_s_setprio(1);
#pragma unroll
        for (int f = 0; f < 8; ++f)
#pragma unroll
            for (int g = 0; g < 4; ++g)
                acc[f][g] = __builtin_amdgcn_mfma_f32_16x16x32_bf16(
                    af[f], bfr[g], acc[f][g], 0, 0, 0);
        __builtin_amdgcn_s_setprio(0);
    };

    constexpr int NT = NTAPS * 16;               // K-tiles of 32

    // prologue: stage tiles 0,1,2; wait tile0 (outstanding: tiles 1,2 = 8)
    STAGE(0, aScal(0), bScal(0));
    STAGE(1, aScal(1), bScal(1));
    STAGE(2, aScal(2), bScal(2));
    VMCNT_BARRIER("8");

    // steady state: compute tile t (buf t%4), stage tile t+3 (buf (t+3)%4,
    // freed by the barrier ending tile t-1); end wait = tiles t+2,t+3 in
    // flight (8 loads) -> tile t+1 ready.
#pragma unroll 1
    for (int tb = 0; tb < NT - 4; tb += 4) {
        STAGE(3, aScal(tb + 3), bScal(tb + 3)); COMPUTE(0); VMCNT_BARRIER("8");
        STAGE(0, aScal(tb + 4), bScal(tb + 4)); COMPUTE(1); VMCNT_BARRIER("8");
        STAGE(1, aScal(tb + 5), bScal(tb + 5)); COMPUTE(2); VMCNT_BARRIER("8");
        STAGE(2, aScal(tb + 6), bScal(tb + 6)); COMPUTE(3); VMCNT_BARRIER("8");
    }
    // tail: tiles NT-4..NT-1 (NT ≡ 0 mod 4), drain 8 -> 4 -> 0
    STAGE(3, aScal(NT - 1), bScal(NT - 1)); COMPUTE(0); VMCNT_BARRIER("8");
    COMPUTE(1); VMCNT_BARRIER("4");
    COMPUTE(2); VMCNT_BARRIER("0");
    COMPUTE(3);

    // --- epilogue: bias + bf16 store (D: col m uses lrow, rows n use lk*4+r)
#pragma unroll
    for (int g = 0; g < 4; ++g) {
        int m = m0 + wc * 64 + g * 16 + lrow;
        float bv = bias ? bias[m] : 0.f;
        size_t mrow = (size_t)m * 4096;
#pragma unroll
        for (int f = 0; f < 8; ++f) {
            int nb = n0 + wr * 128 + f * 16 + lk * 4;
            f32x4 a4 = acc[f][g];
            ushort4 o;
            o.x = f2bf(a4[0] + bv);
            o.y = f2bf(a4[1] + bv);
            o.z = f2bf(a4[2] + bv);
            o.w = f2bf(a4[3] + bv);
            *(ushort4*)&Ob[mrow + nb] = o;
        }
    }
}

// ---------------------------------------------------------------------------
// 128x128 MFMA GEMM (proven m97-style) — kept for the final 1x1 (f32 out).
// A bf16 (B,4096,512) linear.
// ---------------------------------------------------------------------------
__global__ __launch_bounds__(256)
void mfma_gemm_f32out(const unsigned short* __restrict__ A,
                      const unsigned short* __restrict__ Bw,
                      float* __restrict__ Out, int M)
{
    __shared__ short As[128 * 64];
    __shared__ short Bs[128 * 64];

    const int t  = threadIdx.x;
    const int n0 = blockIdx.x * 128;
    const int m0 = blockIdx.y * 128;
    const int b  = blockIdx.z;
    const unsigned short* Ab = A + (size_t)b * (4096 * 512);
    float* Ob = Out + (size_t)b * ((size_t)M * 4096);

    const int trow = t >> 3;
    const int csrc = (t & 7) ^ (trow & 7);
    const unsigned short* aSrc[4];
    const unsigned short* bSrc[4];
#pragma unroll
    for (int i = 0; i < 4; ++i) {
        int r = i * 32 + trow;
        aSrc[i] = Ab + ((size_t)(n0 + r) * 512 + csrc * 8);
        bSrc[i] = Bw + ((size_t)(m0 + r) * 512 + csrc * 8);
    }
    short* aDst = As + (t & 192) * 8;
    short* bDst = Bs + (t & 192) * 8;

    const int lane = t & 63;
    const int wv = t >> 6, wr = wv >> 1, wc = wv & 1;
    const int lrow = lane & 15, lk = lane >> 4;
    int aOff[4][2], bOff[4][2];
#pragma unroll
    for (int f = 0; f < 4; ++f)
#pragma unroll
        for (int kk = 0; kk < 2; ++kk) {
            int ra = wr * 64 + f * 16 + lrow;
            aOff[f][kk] = ra * 64 + ((kk * 4 + lk) ^ (ra & 7)) * 8;
            int rb = wc * 64 + f * 16 + lrow;
            bOff[f][kk] = rb * 64 + ((kk * 4 + lk) ^ (rb & 7)) * 8;
        }

    f32x4 acc[4][4] = {};

#pragma unroll 1
    for (int ks = 0; ks < 8; ++ks) {
        const int k0 = ks * 64;
        __syncthreads();
#pragma unroll
        for (int i = 0; i < 4; ++i) {
            __builtin_amdgcn_global_load_lds(
                AS1C(aSrc[i] + k0), AS3(aDst + i * 2048), 16, 0, 0);
            __builtin_amdgcn_global_load_lds(
                AS1C(bSrc[i] + k0), AS3(bDst + i * 2048), 16, 0, 0);
        }
        __syncthreads();
        bf16x8 av[4][2], bv[4][2];
#pragma unroll
        for (int f = 0; f < 4; ++f) {
            av[f][0] = *(const bf16x8*)&As[aOff[f][0]];
            av[f][1] = *(const bf16x8*)&As[aOff[f][1]];
            bv[f][0] = *(const bf16x8*)&Bs[bOff[f][0]];
            bv[f][1] = *(const bf16x8*)&Bs[bOff[f][1]];
        }
#pragma unroll
        for (int kk = 0; kk < 2; ++kk)
#pragma unroll
            for (int fn = 0; fn < 4; ++fn)
#pragma unroll
                for (int fm = 0; fm < 4; ++fm)
                    acc[fn][fm] = __builtin_amdgcn_mfma_f32_16x16x32_bf16(
                        av[fn][kk], bv[fm][kk], acc[fn][fm], 0, 0, 0);
    }

#pragma unroll
    for (int fm = 0; fm < 4; ++fm) {
        int m = m0 + wc * 64 + fm * 16 + lrow;
        size_t mrow = (size_t)m * 4096;
#pragma unroll
        for (int fn = 0; fn < 4; ++fn) {
            int nb = n0 + wr * 64 + fn * 16 + lk * 4;
            f32x4 a4 = acc[fn][fm];
            *(float4*)&Ob[mrow + nb] = make_float4(a4[0], a4[1], a4[2], a4[3]);
        }
    }
}

// ---------------------------------------------------------------------------
// MFMA window attention: 1 wave per (window, head), 4 waves/block.
// ---------------------------------------------------------------------------
__global__ __launch_bounds__(256)
void attn_mfma_kernel(const unsigned short* __restrict__ QKV,
                      const float* __restrict__ biasM,
                      float* __restrict__ OutB)
{
    __shared__ short smem[4 * 9216];
    int t = threadIdx.x;
    int wv = t >> 6, lane = t & 63;
    int wing = blockIdx.x >> 2;
    int head = (blockIdx.x & 3) * 4 + wv;
    int b    = blockIdx.y;
    int hhi = wing >> 3, wwi = wing & 7;
    int sp0 = hhi * 512 + wwi * 8;
    int ch0 = head * 32;
    const unsigned short* Qg = QKV + (size_t)b * 1536 * 4096;

    short* Qtm = smem + wv * 9216;     // [64][36] token-major Q
    short* Ktm = Qtm + 2304;           // [64][36] token-major K
    short* Pq  = Qtm + 4608;           // [64][72] P (q-major)

    {
        int d  = lane & 31;
        int rb = lane >> 5;
#pragma unroll
        for (int i = 0; i < 4; ++i) {
            int r = rb + 2 * i;        // window row 0..7
            us8v q8 = *(const us8v*)&Qg[(size_t)(ch0 + d) * 4096 + sp0 + r * 64];
            us8v k8 = *(const us8v*)&Qg[(size_t)(512 + ch0 + d) * 4096 + sp0 + r * 64];
#pragma unroll
            for (int e = 0; e < 8; ++e) {
                Qtm[(r * 8 + e) * 36 + d] = (short)q8[e];
                Ktm[(r * 8 + e) * 36 + d] = (short)k8[e];
            }
        }
    }

    int lrow = lane & 15, lk = lane >> 4;

    bf16x8 kf[4], qf[4];
#pragma unroll
    for (int f = 0; f < 4; ++f) {
        kf[f] = *(const bf16x8*)&Ktm[(lrow + 16 * f) * 36 + lk * 8];
        qf[f] = *(const bf16x8*)&Qtm[(lrow + 16 * f) * 36 + lk * 8];
    }
    f32x4 s[4][4] = {};
#pragma unroll
    for (int fi = 0; fi < 4; ++fi)
#pragma unroll
        for (int fj = 0; fj < 4; ++fj)
            s[fi][fj] = __builtin_amdgcn_mfma_f32_16x16x32_bf16(
                kf[fi], qf[fj], s[fi][fj], 0, 0, 0);

    const float* bM = biasM + (size_t)head * 4096;
    float rs[4];
#pragma unroll
    for (int fj = 0; fj < 4; ++fj) {
        float v[4][4];
#pragma unroll
        for (int fi = 0; fi < 4; ++fi) {
            float4 bv = *(const float4*)&bM[((fi * 4 + fj) * 64 + lane) * 4];
            const float* bvp = (const float*)&bv;
#pragma unroll
            for (int r = 0; r < 4; ++r)
                v[fi][r] = fmaf(s[fi][fj][r], ATT_SCALE, bvp[r]);
        }
        float m = -1e30f;
#pragma unroll
        for (int fi = 0; fi < 4; ++fi)
#pragma unroll
            for (int r = 0; r < 4; ++r) m = fmaxf(m, v[fi][r]);
        m = fmaxf(m, __shfl_xor(m, 16));
        m = fmaxf(m, __shfl_xor(m, 32));
        float ev[4][4];
        float sum = 0.f;
#pragma unroll
        for (int fi = 0; fi < 4; ++fi)
#pragma unroll
            for (int r = 0; r < 4; ++r) {
                ev[fi][r] = __expf(v[fi][r] - m);
                sum += ev[fi][r];
            }
        sum += __shfl_xor(sum, 16);
        sum += __shfl_xor(sum, 32);
        rs[fj] = 1.f / sum;
#pragma unroll
        for (int fi = 0; fi < 4; ++fi) {
            unsigned p0 = (unsigned)f2bf(ev[fi][0]) | ((unsigned)f2bf(ev[fi][1]) << 16);
            unsigned p1 = (unsigned)f2bf(ev[fi][2]) | ((unsigned)f2bf(ev[fi][3]) << 16);
            *(uint2*)&Pq[(lrow + 16 * fj) * 72 + 16 * fi + lk * 4] = make_uint2(p0, p1);
        }
    }

    f32x4 o[2][4] = {};
#pragma unroll
    for (int ks = 0; ks < 2; ++ks) {
        bf16x8 vf[2], pf[4];
#pragma unroll
        for (int fid = 0; fid < 2; ++fid)
            vf[fid] = *(const bf16x8*)&Qg[(size_t)(1024 + ch0 + 16 * fid + lrow) * 4096
                                          + sp0 + (lk + 4 * ks) * 64];
#pragma unroll
        for (int fjq = 0; fjq < 4; ++fjq)
            pf[fjq] = *(const bf16x8*)&Pq[(lrow + 16 * fjq) * 72 + ks * 32 + lk * 8];
#pragma unroll
        for (int fid = 0; fid < 2; ++fid)
#pragma unroll
            for (int fjq = 0; fjq < 4; ++fjq)
                o[fid][fjq] = __builtin_amdgcn_mfma_f32_16x16x32_bf16(
                    vf[fid], pf[fjq], o[fid][fjq], 0, 0, 0);
    }

    float* Out = OutB + (size_t)b * 512 * 4096;
#pragma unroll
    for (int fjq = 0; fjq < 4; ++fjq) {
        int q  = lrow + 16 * fjq;
        int sp = sp0 + ((q >> 3) << 6) + (q & 7);
        float rr = rs[fjq];
#pragma unroll
        for (int fid = 0; fid < 2; ++fid)
#pragma unroll
            for (int r = 0; r < 4; ++r) {
                int dch = 16 * fid + lk * 4 + r;
                Out[(size_t)(ch0 + dch) * 4096 + sp] = o[fid][fjq][r] * rr;
            }
    }
}

// ---------------------------------------------------------------------------
// Fused pool(+local) + depthwise 8x8 + BN3: single 72x72 LDS tile,
// 4-wide pixel groups, b128 LDS traffic, dw weights via scalar loads.
// ---------------------------------------------------------------------------
__global__ __launch_bounds__(256)
void pooldw_kernel(const float* __restrict__ A, const unsigned short* __restrict__ L,
                   const float* __restrict__ Wd,
                   const float* __restrict__ g3, const float* __restrict__ b3,
                   unsigned short* __restrict__ U)
{
    int bc = blockIdx.x;               // b*512 + c
    int c  = bc & 511;
    __shared__ float pad[72][72];      // 20.25 KB
    int t = threadIdx.x;
    float* pf = &pad[0][0];
#pragma unroll
    for (int i = 0; i < 21; ++i) {
        int e = i * 256 + t;
        if (e < 5184) pf[e] = 0.f;
    }
    __syncthreads();

    const float* ap = A + (size_t)bc * 4096;
#pragma unroll
    for (int i = 0; i < 4; ++i) {
        int idx = i * 256 + t;             // 1024 float4
        int y = idx >> 4, x4 = (idx & 15) * 4;
        *(float4*)&pad[3 + y][4 + x4] = ((const float4*)ap)[idx];
    }
    if (t < 64)       pad[67][4 + t] = ap[62 * 64 + t];
    else if (t < 128) { int y = t - 64; pad[3 + y][68] = ap[y * 64 + 62]; }
    else if (t == 128) pad[67][68] = ap[62 * 64 + 62];
    __syncthreads();

    const unsigned short* lp = L + (size_t)bc * 4096;
    int u  = t & 15, rr = t >> 4;
    int w0 = u * 4;
    float4 res[4];
#pragma unroll
    for (int g = 0; g < 4; ++g) {
        int h = g * 16 + rr;
        float4 sx = make_float4(0.f, 0.f, 0.f, 0.f);
#pragma unroll
        for (int i = 0; i < 8; ++i) {
            float4 v = *(const float4*)&pad[h + i][4 + w0];
            sx.x += v.x; sx.y += v.y; sx.z += v.z; sx.w += v.w;
        }
        float win[12];
        *(float4*)&win[0] = *(const float4*)&pad[3 + h][w0];
        *(float4*)&win[4] = *(const float4*)&pad[3 + h][w0 + 4];
        *(float4*)&win[8] = *(const float4*)&pad[3 + h][w0 + 8];
        float4 sy = make_float4(0.f, 0.f, 0.f, 0.f);
#pragma unroll
        for (int i = 0; i < 8; ++i) {
            sy.x += win[1 + i];
            sy.y += win[2 + i];
            sy.z += win[3 + i];
            sy.w += win[4 + i];
        }
        ushort4 l4 = *(const ushort4*)&lp[h * 64 + w0];
        res[g].x = fmaf(0.125f, sx.x + sy.x, bf2f(l4.x));
        res[g].y = fmaf(0.125f, sx.y + sy.y, bf2f(l4.y));
        res[g].z = fmaf(0.125f, sx.z + sy.z, bf2f(l4.z));
        res[g].w = fmaf(0.125f, sx.w + sy.w, bf2f(l4.w));
    }
    __syncthreads();

#pragma unroll
    for (int g = 0; g < 4; ++g) {
        int h = g * 16 + rr;
        *(float4*)&pad[3 + h][4 + w0] = res[g];
    }
    __syncthreads();
    if (t < 64)       pad[67][4 + t] = pad[65][4 + t];
    else if (t < 128) { int y = t - 64; pad[3 + y][68] = pad[3 + y][66]; }
    else if (t == 128) pad[67][68] = pad[65][66];
    __syncthreads();

    const float* wdp = Wd + c * 64;
    float gc  = g3[c] * INVBN;
    float bcv = b3[c];
#pragma unroll
    for (int g = 0; g < 4; ++g) {
        int h = g * 16 + rr;
        float a0 = 0.f, a1 = 0.f, a2 = 0.f, a3 = 0.f;
#pragma unroll
        for (int i = 0; i < 8; ++i) {
            float win[12];
            *(float4*)&win[0] = *(const float4*)&pad[h + i][w0];
            *(float4*)&win[4] = *(const float4*)&pad[h + i][w0 + 4];
            *(float4*)&win[8] = *(const float4*)&pad[h + i][w0 + 8];
#pragma unroll
            for (int j = 0; j < 8; ++j) {
                float wv = wdp[i * 8 + j];
                a0 = fmaf(wv, win[1 + j], a0);
                a1 = fmaf(wv, win[2 + j], a1);
                a2 = fmaf(wv, win[3 + j], a2);
                a3 = fmaf(wv, win[4 + j], a3);
            }
        }
        ushort4 o;
        o.x = f2bf(gc * a0 + bcv);
        o.y = f2bf(gc * a1 + bcv);
        o.z = f2bf(gc * a2 + bcv);
        o.w = f2bf(gc * a3 + bcv);
        *(ushort4*)&U[(size_t)bc * 4096 + h * 64 + w0] = o;
    }
}

// ---------------------------------------------------------------------------
// U (B,512,4096) bf16 -> Ut (B,4096,512) bf16.  64p x 64c LDS tiles.
// ---------------------------------------------------------------------------
__global__ __launch_bounds__(256)
void transpose_cp_kernel(const unsigned short* __restrict__ U, unsigned short* __restrict__ Ut)
{
    int pt = blockIdx.x;               // p-tile 0..63
    int b  = blockIdx.y;
    const unsigned short* Ub = U + (size_t)b * 512 * 4096;
    unsigned short* Utb = Ut + (size_t)b * 4096 * 512;
    __shared__ unsigned short tile[64][72];
    int t = threadIdx.x;
    int p0 = pt * 64;

    for (int cc = 0; cc < 8; ++cc) {
        int c0 = cc * 64;
        __syncthreads();
        {
            int cl = t >> 2, px = (t & 3) * 16;
            const unsigned short* src = &Ub[(size_t)(c0 + cl) * 4096 + p0 + px];
            *(us8v*)&tile[cl][px]     = *(const us8v*)src;
            *(us8v*)&tile[cl][px + 8] = *(const us8v*)(src + 8);
        }
        __syncthreads();
        {
            int pl = t >> 2, cx = (t & 3) * 16;
            us8v o0, o1;
#pragma unroll
            for (int e = 0; e < 8; ++e) {
                o0[e] = tile[cx + e][pl];
                o1[e] = tile[cx + 8 + e][pl];
            }
            unsigned short* dst = &Utb[(size_t)(p0 + pl) * 512 + c0 + cx];
            *(us8v*)dst       = o0;
            *(us8v*)(dst + 8) = o1;
        }
    }
}

// ---------------------------------------------------------------------------
extern "C" void kernel_launch(void* const* d_in, const int* in_sizes, int n_in,
                              void* d_out, int out_size, void* d_ws, size_t ws_size,
                              hipStream_t stream)
{
    (void)in_sizes; (void)n_in; (void)out_size;
    const float* x     = (const float*)d_in[0];
    const float* w_lc1 = (const float*)d_in[1];
    const float* g1    = (const float*)d_in[2];
    const float* b1    = (const float*)d_in[3];
    const float* w_lc2 = (const float*)d_in[4];
    const float* g2    = (const float*)d_in[5];
    const float* b2    = (const float*)d_in[6];
    const float* w_qkv = (const float*)d_in[7];
    const float* rt    = (const float*)d_in[8];
    const float* w_dw  = (const float*)d_in[9];
    const float* g3    = (const float*)d_in[10];
    const float* b3    = (const float*)d_in[11];
    const float* w_pw  = (const float*)d_in[12];
    float* out = (float*)d_out;

    // workspace layout (bf16 short offsets):
    //   local : 16,777,216            [0 .. 16,777,216)
    //   xt    : 8*4356*512 = 17,842,176  [16,777,216 .. 34,619,392)   (aliased by U)
    //   wt3   : 2,359,296             [34,619,392 .. 36,978,688)
    //   wq    :   786,432             [36,978,688 .. 37,765,120)
    //   wpw   :   262,144             [37,765,120 .. 38,027,264)
    //   bsum  : 512 f32 = 1,024       [38,027,264 .. 38,028,288)
    //   biasM : 262,144 f32 = 524,288 [38,028,288 .. 38,552,576)
    //   qkv   : 6,291,456 (per-batch) or 50,331,648 (full)  [38,552,576 ..)
    unsigned short* S        = (unsigned short*)d_ws;
    unsigned short* local_us = S;
    unsigned short* xt_us    = S + 16777216;
    unsigned short* u_us     = xt_us;                   // alias: U after X_tp dead
    unsigned short* wt3_us   = S + 34619392;
    unsigned short* wq_us    = S + 36978688;
    unsigned short* wpw_us   = S + 37765120;
    float*          bsum     = (float*)(S + 38027264);
    float*          biasM    = (float*)(S + 38028288);
    unsigned short* qkv_us   = S + 38552576;
    unsigned short* ut_us    = local_us;                // alias: Ut after local dead

    const bool full = ws_size >= (size_t)(38552576 + 50331648) * 2;  // 177.77 MB

    repack_kernel<<<dim3(9216), 256, 0, stream>>>(w_lc2, w_lc1, w_qkv, w_pw,
                                                  g1, g2, b1, b2,
                                                  wt3_us, wq_us, wpw_us, bsum);
    bias_precompute_kernel<<<dim3(64), 256, 0, stream>>>(rt, biasM);
    pad_transpose_kernel<<<dim3(66, 8), 256, 0, stream>>>(x, xt_us);
    mfma_gemm256<9><<<dim3(16, 2, 8), 512, 0, stream>>>(
        xt_us, wt3_us, bsum, local_us, 512);

    if (full) {
        mfma_gemm256<1><<<dim3(16, 6, 8), 512, 0, stream>>>(
            xt_us, wq_us, nullptr, qkv_us, 1536);
        attn_mfma_kernel<<<dim3(256, 8), 256, 0, stream>>>(qkv_us, biasM, out);
    } else {
        for (int b = 0; b < 8; ++b) {
            mfma_gemm256<1><<<dim3(16, 6, 1), 512, 0, stream>>>(
                xt_us + (size_t)b * 4356 * 512, wq_us, nullptr, qkv_us, 1536);
            attn_mfma_kernel<<<dim3(256, 1), 256, 0, stream>>>(
                qkv_us, biasM, out + (size_t)b * 2097152);
        }
    }

    pooldw_kernel<<<dim3(4096), 256, 0, stream>>>(out, local_us, w_dw, g3, b3, u_us);
    transpose_cp_kernel<<<dim3(64, 8), 256, 0, stream>>>(u_us, ut_us);
    mfma_gemm_f32out<<<dim3(32, 4, 8), 256, 0, stream>>>(
        ut_us, wpw_us, out, 512);
}

// Round 10
// 465.760 us; speedup vs baseline: 9.5561x; 1.0175x over previous
//
#include <hip/hip_runtime.h>

#define INVBN 0.9999950000374997f       // 1/sqrt(1 + 1e-5)
#define ATT_SCALE 0.17677669529663687f  // 32^-0.5

typedef short bf16x8 __attribute__((ext_vector_type(8)));
typedef float f32x4  __attribute__((ext_vector_type(4)));
typedef unsigned short us8v __attribute__((ext_vector_type(8)));

#define AS1C(p) ((const __attribute__((address_space(1))) void*)(p))
#define AS3(p)  ((__attribute__((address_space(3))) void*)(p))

__device__ __forceinline__ float bf2f(unsigned short u) {
    return __uint_as_float(((unsigned)u) << 16);
}
__device__ __forceinline__ unsigned short f2bf(float f) {
    unsigned u = __float_as_uint(f);
    u += 0x7FFFu + ((u >> 16) & 1u);        // RNE
    return (unsigned short)(u >> 16);
}

// ---------------------------------------------------------------------------
// Repack: Wt3[tap][m][k] bf16 (BN-folded conv3x3 + lc1 into center tap),
// Wq, Wpw bf16, bsum[m] = b1+b2.
// ---------------------------------------------------------------------------
__global__ __launch_bounds__(256)
void repack_kernel(const float* __restrict__ W2, const float* __restrict__ W1,
                   const float* __restrict__ Wq, const float* __restrict__ Wp,
                   const float* __restrict__ g1, const float* __restrict__ g2,
                   const float* __restrict__ b1, const float* __restrict__ b2,
                   unsigned short* __restrict__ Wt, unsigned short* __restrict__ WqO,
                   unsigned short* __restrict__ WpO, float* __restrict__ bsum)
{
    int i = blockIdx.x * 256 + threadIdx.x;
    if (i < 512) bsum[i] = b1[i] + b2[i];
    if (i < 786432) WqO[i] = f2bf(Wq[i]);
    if (i < 262144) WpO[i] = f2bf(Wp[i]);
    if (i >= 2359296) return;
    int tap = i / 262144;
    int rem = i - tap * 262144;          // m*512 + k
    int m   = rem >> 9;
    float v = g2[m] * INVBN * W2[(size_t)rem * 9 + tap];
    if (tap == 4) v = fmaf(g1[m] * INVBN, W1[rem], v);
    Wt[i] = f2bf(v);
}

// ---------------------------------------------------------------------------
// Precompute Swin relative-position bias in the MFMA C-layout.
// ---------------------------------------------------------------------------
__global__ __launch_bounds__(256)
void bias_precompute_kernel(const float* __restrict__ RT, float* __restrict__ biasM)
{
    int idx = blockIdx.x * 256 + threadIdx.x;      // 0..16383
    int h = idx >> 10, rem = idx & 1023;
    int frag = rem >> 6, lane = rem & 63;
    int fi = frag >> 2, fj = frag & 3;
    int q  = 16 * fj + (lane & 15);
    int kb = 16 * fi + ((lane >> 4) << 2);
    int yi = q >> 3, xi = q & 7;
    float4 o;
    float* op = (float*)&o;
#pragma unroll
    for (int r = 0; r < 4; ++r) {
        int j = kb + r;
        int ridx = (yi - (j >> 3) + 7) * 15 + (xi - (j & 7) + 7);
        op[r] = RT[ridx * 16 + h];
    }
    *(float4*)&biasM[(size_t)idx * 4] = o;
}

// ---------------------------------------------------------------------------
// x (B,512,64,64) f32 NCHW  ->  X_tp (B, 66*66, 512) bf16, zero borders.
// ---------------------------------------------------------------------------
__global__ __launch_bounds__(256)
void pad_transpose_kernel(const float* __restrict__ X, unsigned short* __restrict__ XT)
{
    int ph = blockIdx.x;      // 0..65
    int b  = blockIdx.y;
    int t  = threadIdx.x;
    unsigned short* rowbase = XT + ((size_t)b * 4356 + (size_t)ph * 66) * 512;
    uint4 z = make_uint4(0, 0, 0, 0);
    if (ph == 0 || ph == 65) {
        uint4* p4 = (uint4*)rowbase;                 // 66*512 elems = 4224 uint4
        for (int i = t; i < 4224; i += 256) p4[i] = z;
        return;
    }
    if (t < 64)       ((uint4*)rowbase)[t] = z;                  // pw = 0
    else if (t < 128) ((uint4*)(rowbase + 65 * 512))[t - 64] = z; // pw = 65

    int h = ph - 1;
    __shared__ float tile[64][65];
    const float* xb = X + (size_t)b * 512 * 4096 + h * 64;
    for (int cc = 0; cc < 8; ++cc) {
        int c0 = cc * 64;
        __syncthreads();
#pragma unroll
        for (int i = 0; i < 4; ++i) {
            int cl = i * 16 + (t >> 4);
            int w0 = (t & 15) * 4;
            *(float4*)&tile[cl][w0] =
                *(const float4*)&xb[(size_t)(c0 + cl) * 4096 + w0];
        }
        __syncthreads();
#pragma unroll
        for (int it = 0; it < 2; ++it) {
            int wl = it * 32 + (t >> 3);     // w = 0..63  -> pw = wl+1
            int cs = (t & 7) * 8;
            us8v v;
#pragma unroll
            for (int e = 0; e < 8; ++e) v[e] = f2bf(tile[cs + e][wl]);
            *(us8v*)&rowbase[(size_t)(1 + wl) * 512 + c0 + cs] = v;
        }
    }
}

// ---------------------------------------------------------------------------
// Deep-pipelined 256x256 MFMA GEMM, phase-split (T3+T4+T5).
// 8 waves, BK=32, 4 LDS buffers (128 KiB), chunk XOR-swizzle (round-9, 0 confl).
// Each K-tile = 2 phases of 16 MFMA: {ds_read subtile || stage half ->
// barrier -> setprio MFMA -> barrier}, counted vmcnt(8) once per K-tile
// (never 0 in steady state; drain 8->4->0 in tail).
// ---------------------------------------------------------------------------
#define MF(A,B,C) __builtin_amdgcn_mfma_f32_16x16x32_bf16((A),(B),(C),0,0,0)

#define TILE(BUF, SBUF, SAO, SBO, DOSTAGE, DOVM, VMSTR) do {                  \
    bf16x8 aa[4], bb[4];                                                      \
    _Pragma("unroll")                                                         \
    for (int f = 0; f < 4; ++f) {                                             \
        aa[f] = *(const bf16x8*)&ldsbuf[(BUF)*16384 + (wr*128 + f*16 + lrow)*32 + ck0]; \
        bb[f] = *(const bf16x8*)&ldsbuf[(BUF)*16384 + 8192 + (wc*64 + f*16 + lrow)*32 + ck0]; \
    }                                                                         \
    if (DOSTAGE) STAGEH((SBUF), (SAO), (SBO), 0);                             \
    __builtin_amdgcn_s_barrier();                                             \
    __builtin_amdgcn_s_setprio(1);                                            \
    _Pragma("unroll")                                                         \
    for (int f = 0; f < 4; ++f)                                               \
        _Pragma("unroll")                                                     \
        for (int g = 0; g < 4; ++g)                                           \
            acc[f][g] = MF(aa[f], bb[g], acc[f][g]);                          \
    __builtin_amdgcn_s_setprio(0);                                            \
    __builtin_amdgcn_s_barrier();                                             \
    _Pragma("unroll")                                                         \
    for (int f = 0; f < 4; ++f)                                               \
        aa[f] = *(const bf16x8*)&ldsbuf[(BUF)*16384 + (wr*128 + (f+4)*16 + lrow)*32 + ck0]; \
    if (DOSTAGE) STAGEH((SBUF), (SAO), (SBO), 1);                             \
    if (DOVM) { asm volatile("s_waitcnt vmcnt(" VMSTR ")" ::: "memory"); }    \
    __builtin_amdgcn_s_barrier();                                             \
    __builtin_amdgcn_s_setprio(1);                                            \
    _Pragma("unroll")                                                         \
    for (int f = 0; f < 4; ++f)                                               \
        _Pragma("unroll")                                                     \
        for (int g = 0; g < 4; ++g)                                           \
            acc[f+4][g] = MF(aa[f], bb[g], acc[f+4][g]);                      \
    __builtin_amdgcn_s_setprio(0);                                            \
    __builtin_amdgcn_s_barrier();                                             \
} while (0)

template<int NTAPS>
__global__ __launch_bounds__(512, 2)
void mfma_gemm256(const unsigned short* __restrict__ A,
                  const unsigned short* __restrict__ Bw,
                  const float* __restrict__ bias,
                  unsigned short* __restrict__ Out, int M)
{
    __shared__ __align__(16) unsigned short ldsbuf[65536];   // 128 KiB

    const int t    = threadIdx.x;
    const int wid  = t >> 6, lane = t & 63;
    const int wr   = wid >> 2, wc = wid & 3;          // wave n-half / m-quarter
    const int lrow = lane & 15, lk = lane >> 4;
    const int n0 = blockIdx.x * 256;
    const int m0 = blockIdx.y * 256;
    const int b  = blockIdx.z;
    const unsigned short* Ab = A + (size_t)b * (4356 * 512);
    unsigned short* Ob = Out + (size_t)b * ((size_t)M * 4096);

    // staging source pointers (chunk pre-swizzled, round-9)
    const unsigned short* src[4];
    {
        int rsub = lane >> 2, ch = lane & 3;
        int chs  = ch ^ ((rsub >> 1) & 3);
#pragma unroll
        for (int i = 0; i < 4; ++i) {
            if (wid < 4) {
                int p = n0 + (wid * 4 + i) * 16 + rsub;
                int h = p >> 6, w = p & 63;
                src[i] = Ab + (size_t)((h + 1) * 66 + (w + 1)) * 512 + chs * 8;
            } else {
                int m = m0 + ((wid - 4) * 4 + i) * 16 + rsub;
                src[i] = Bw + (size_t)m * 512 + chs * 8;
            }
        }
    }

    f32x4 acc[8][4] = {};
    const int ck0 = (lk ^ ((lrow >> 1) & 3)) * 8;     // swizzled fragment chunk

    auto aScal = [&](int tt) -> int {
        if (NTAPS == 1) return tt * 32;
        int tap = tt >> 4;
        return (tap / 3 - 1) * (66 * 512) + (tap % 3 - 1) * 512 + (tt & 15) * 32;
    };
    auto bScal = [&](int tt) -> int {
        if (NTAPS == 1) return tt * 32;
        return (tt >> 4) * (M * 512) + (tt & 15) * 32;
    };
    auto STAGEH = [&](int bufk, int aoff, int boff, int half) {
        int off = (wid < 4) ? aoff : boff;
#pragma unroll
        for (int i = 2 * half; i < 2 * half + 2; ++i)
            __builtin_amdgcn_global_load_lds(
                AS1C(src[i] + off),
                AS3(&ldsbuf[bufk * 16384 + (wid * 4 + i) * 512]), 16, 0, 0);
    };

    constexpr int NT = NTAPS * 16;               // K-tiles of 32

    // prologue: stage tiles 0,1,2; wait tile0 (outstanding tiles 1,2 = 8)
    STAGEH(0, aScal(0), bScal(0), 0); STAGEH(0, aScal(0), bScal(0), 1);
    STAGEH(1, aScal(1), bScal(1), 0); STAGEH(1, aScal(1), bScal(1), 1);
    STAGEH(2, aScal(2), bScal(2), 0); STAGEH(2, aScal(2), bScal(2), 1);
    asm volatile("s_waitcnt vmcnt(8)" ::: "memory");
    __builtin_amdgcn_s_barrier();

#pragma unroll 1
    for (int tb = 0; tb < NT - 4; tb += 4) {
        TILE(0, 3, aScal(tb + 3), bScal(tb + 3), 1, 1, "8");
        TILE(1, 0, aScal(tb + 4), bScal(tb + 4), 1, 1, "8");
        TILE(2, 1, aScal(tb + 5), bScal(tb + 5), 1, 1, "8");
        TILE(3, 2, aScal(tb + 6), bScal(tb + 6), 1, 1, "8");
    }
    // tail: tiles NT-4..NT-1, stage NT-1, drain 8 -> 4 -> 0
    TILE(0, 3, aScal(NT - 1), bScal(NT - 1), 1, 1, "8");
    TILE(1, 0, 0, 0, 0, 1, "4");
    TILE(2, 0, 0, 0, 0, 1, "0");
    TILE(3, 0, 0, 0, 0, 0, "0");

    // epilogue: bias + bf16 store (D: col m uses lrow, rows n use lk*4+r)
#pragma unroll
    for (int g = 0; g < 4; ++g) {
        int m = m0 + wc * 64 + g * 16 + lrow;
        float bv = bias ? bias[m] : 0.f;
        size_t mrow = (size_t)m * 4096;
#pragma unroll
        for (int f = 0; f < 8; ++f) {
            int nb = n0 + wr * 128 + f * 16 + lk * 4;
            f32x4 a4 = acc[f][g];
            ushort4 o;
            o.x = f2bf(a4[0] + bv);
            o.y = f2bf(a4[1] + bv);
            o.z = f2bf(a4[2] + bv);
            o.w = f2bf(a4[3] + bv);
            *(ushort4*)&Ob[mrow + nb] = o;
        }
    }
}

// ---------------------------------------------------------------------------
// 128x128 MFMA GEMM (proven m97-style) — kept for the final 1x1 (f32 out).
// ---------------------------------------------------------------------------
__global__ __launch_bounds__(256)
void mfma_gemm_f32out(const unsigned short* __restrict__ A,
                      const unsigned short* __restrict__ Bw,
                      float* __restrict__ Out, int M)
{
    __shared__ short As[128 * 64];
    __shared__ short Bs[128 * 64];

    const int t  = threadIdx.x;
    const int n0 = blockIdx.x * 128;
    const int m0 = blockIdx.y * 128;
    const int b  = blockIdx.z;
    const unsigned short* Ab = A + (size_t)b * (4096 * 512);
    float* Ob = Out + (size_t)b * ((size_t)M * 4096);

    const int trow = t >> 3;
    const int csrc = (t & 7) ^ (trow & 7);
    const unsigned short* aSrc[4];
    const unsigned short* bSrc[4];
#pragma unroll
    for (int i = 0; i < 4; ++i) {
        int r = i * 32 + trow;
        aSrc[i] = Ab + ((size_t)(n0 + r) * 512 + csrc * 8);
        bSrc[i] = Bw + ((size_t)(m0 + r) * 512 + csrc * 8);
    }
    short* aDst = As + (t & 192) * 8;
    short* bDst = Bs + (t & 192) * 8;

    const int lane = t & 63;
    const int wv = t >> 6, wr = wv >> 1, wc = wv & 1;
    const int lrow = lane & 15, lk = lane >> 4;
    int aOff[4][2], bOff[4][2];
#pragma unroll
    for (int f = 0; f < 4; ++f)
#pragma unroll
        for (int kk = 0; kk < 2; ++kk) {
            int ra = wr * 64 + f * 16 + lrow;
            aOff[f][kk] = ra * 64 + ((kk * 4 + lk) ^ (ra & 7)) * 8;
            int rb = wc * 64 + f * 16 + lrow;
            bOff[f][kk] = rb * 64 + ((kk * 4 + lk) ^ (rb & 7)) * 8;
        }

    f32x4 acc[4][4] = {};

#pragma unroll 1
    for (int ks = 0; ks < 8; ++ks) {
        const int k0 = ks * 64;
        __syncthreads();
#pragma unroll
        for (int i = 0; i < 4; ++i) {
            __builtin_amdgcn_global_load_lds(
                AS1C(aSrc[i] + k0), AS3(aDst + i * 2048), 16, 0, 0);
            __builtin_amdgcn_global_load_lds(
                AS1C(bSrc[i] + k0), AS3(bDst + i * 2048), 16, 0, 0);
        }
        __syncthreads();
        bf16x8 av[4][2], bv[4][2];
#pragma unroll
        for (int f = 0; f < 4; ++f) {
            av[f][0] = *(const bf16x8*)&As[aOff[f][0]];
            av[f][1] = *(const bf16x8*)&As[aOff[f][1]];
            bv[f][0] = *(const bf16x8*)&Bs[bOff[f][0]];
            bv[f][1] = *(const bf16x8*)&Bs[bOff[f][1]];
        }
#pragma unroll
        for (int kk = 0; kk < 2; ++kk)
#pragma unroll
            for (int fn = 0; fn < 4; ++fn)
#pragma unroll
                for (int fm = 0; fm < 4; ++fm)
                    acc[fn][fm] = __builtin_amdgcn_mfma_f32_16x16x32_bf16(
                        av[fn][kk], bv[fm][kk], acc[fn][fm], 0, 0, 0);
    }

#pragma unroll
    for (int fm = 0; fm < 4; ++fm) {
        int m = m0 + wc * 64 + fm * 16 + lrow;
        size_t mrow = (size_t)m * 4096;
#pragma unroll
        for (int fn = 0; fn < 4; ++fn) {
            int nb = n0 + wr * 64 + fn * 16 + lk * 4;
            f32x4 a4 = acc[fn][fm];
            *(float4*)&Ob[mrow + nb] = make_float4(a4[0], a4[1], a4[2], a4[3]);
        }
    }
}

// ---------------------------------------------------------------------------
// MFMA window attention: 1 wave per (window, head), 4 waves/block.
// Output bf16 (feeds pooldw), channel-scattered stores.
// ---------------------------------------------------------------------------
__global__ __launch_bounds__(256)
void attn_mfma_kernel(const unsigned short* __restrict__ QKV,
                      const float* __restrict__ biasM,
                      unsigned short* __restrict__ OutB)
{
    __shared__ short smem[4 * 9216];
    int t = threadIdx.x;
    int wv = t >> 6, lane = t & 63;
    int wing = blockIdx.x >> 2;
    int head = (blockIdx.x & 3) * 4 + wv;
    int b    = blockIdx.y;
    int hhi = wing >> 3, wwi = wing & 7;
    int sp0 = hhi * 512 + wwi * 8;
    int ch0 = head * 32;
    const unsigned short* Qg = QKV + (size_t)b * 1536 * 4096;

    short* Qtm = smem + wv * 9216;     // [64][36] token-major Q
    short* Ktm = Qtm + 2304;           // [64][36] token-major K
    short* Pq  = Qtm + 4608;           // [64][72] P (q-major)

    {
        int d  = lane & 31;
        int rb = lane >> 5;
#pragma unroll
        for (int i = 0; i < 4; ++i) {
            int r = rb + 2 * i;        // window row 0..7
            us8v q8 = *(const us8v*)&Qg[(size_t)(ch0 + d) * 4096 + sp0 + r * 64];
            us8v k8 = *(const us8v*)&Qg[(size_t)(512 + ch0 + d) * 4096 + sp0 + r * 64];
#pragma unroll
            for (int e = 0; e < 8; ++e) {
                Qtm[(r * 8 + e) * 36 + d] = (short)q8[e];
                Ktm[(r * 8 + e) * 36 + d] = (short)k8[e];
            }
        }
    }

    int lrow = lane & 15, lk = lane >> 4;

    bf16x8 kf[4], qf[4];
#pragma unroll
    for (int f = 0; f < 4; ++f) {
        kf[f] = *(const bf16x8*)&Ktm[(lrow + 16 * f) * 36 + lk * 8];
        qf[f] = *(const bf16x8*)&Qtm[(lrow + 16 * f) * 36 + lk * 8];
    }
    f32x4 s[4][4] = {};
#pragma unroll
    for (int fi = 0; fi < 4; ++fi)
#pragma unroll
        for (int fj = 0; fj < 4; ++fj)
            s[fi][fj] = __builtin_amdgcn_mfma_f32_16x16x32_bf16(
                kf[fi], qf[fj], s[fi][fj], 0, 0, 0);

    const float* bM = biasM + (size_t)head * 4096;
    float rs[4];
#pragma unroll
    for (int fj = 0; fj < 4; ++fj) {
        float v[4][4];
#pragma unroll
        for (int fi = 0; fi < 4; ++fi) {
            float4 bv = *(const float4*)&bM[((fi * 4 + fj) * 64 + lane) * 4];
            const float* bvp = (const float*)&bv;
#pragma unroll
            for (int r = 0; r < 4; ++r)
                v[fi][r] = fmaf(s[fi][fj][r], ATT_SCALE, bvp[r]);
        }
        float m = -1e30f;
#pragma unroll
        for (int fi = 0; fi < 4; ++fi)
#pragma unroll
            for (int r = 0; r < 4; ++r) m = fmaxf(m, v[fi][r]);
        m = fmaxf(m, __shfl_xor(m, 16));
        m = fmaxf(m, __shfl_xor(m, 32));
        float ev[4][4];
        float sum = 0.f;
#pragma unroll
        for (int fi = 0; fi < 4; ++fi)
#pragma unroll
            for (int r = 0; r < 4; ++r) {
                ev[fi][r] = __expf(v[fi][r] - m);
                sum += ev[fi][r];
            }
        sum += __shfl_xor(sum, 16);
        sum += __shfl_xor(sum, 32);
        rs[fj] = 1.f / sum;
#pragma unroll
        for (int fi = 0; fi < 4; ++fi) {
            unsigned p0 = (unsigned)f2bf(ev[fi][0]) | ((unsigned)f2bf(ev[fi][1]) << 16);
            unsigned p1 = (unsigned)f2bf(ev[fi][2]) | ((unsigned)f2bf(ev[fi][3]) << 16);
            *(uint2*)&Pq[(lrow + 16 * fj) * 72 + 16 * fi + lk * 4] = make_uint2(p0, p1);
        }
    }

    f32x4 o[2][4] = {};
#pragma unroll
    for (int ks = 0; ks < 2; ++ks) {
        bf16x8 vf[2], pf[4];
#pragma unroll
        for (int fid = 0; fid < 2; ++fid)
            vf[fid] = *(const bf16x8*)&Qg[(size_t)(1024 + ch0 + 16 * fid + lrow) * 4096
                                          + sp0 + (lk + 4 * ks) * 64];
#pragma unroll
        for (int fjq = 0; fjq < 4; ++fjq)
            pf[fjq] = *(const bf16x8*)&Pq[(lrow + 16 * fjq) * 72 + ks * 32 + lk * 8];
#pragma unroll
        for (int fid = 0; fid < 2; ++fid)
#pragma unroll
            for (int fjq = 0; fjq < 4; ++fjq)
                o[fid][fjq] = __builtin_amdgcn_mfma_f32_16x16x32_bf16(
                    vf[fid], pf[fjq], o[fid][fjq], 0, 0, 0);
    }

    unsigned short* Out = OutB + (size_t)b * 512 * 4096;
#pragma unroll
    for (int fjq = 0; fjq < 4; ++fjq) {
        int q  = lrow + 16 * fjq;
        int sp = sp0 + ((q >> 3) << 6) + (q & 7);
        float rr = rs[fjq];
#pragma unroll
        for (int fid = 0; fid < 2; ++fid)
#pragma unroll
            for (int r = 0; r < 4; ++r) {
                int dch = 16 * fid + lk * 4 + r;
                Out[(size_t)(ch0 + dch) * 4096 + sp] = f2bf(o[fid][fjq][r] * rr);
            }
    }
}

// ---------------------------------------------------------------------------
// Fused pool(+local) + depthwise 8x8 + BN3: single 72x72 LDS tile,
// 4-wide pixel groups, b128 LDS traffic, dw weights via scalar loads.
// A (attn output) is bf16; U may alias A (per-plane read-before-write).
// ---------------------------------------------------------------------------
__global__ __launch_bounds__(256)
void pooldw_kernel(const unsigned short* __restrict__ A, const unsigned short* __restrict__ L,
                   const float* __restrict__ Wd,
                   const float* __restrict__ g3, const float* __restrict__ b3,
                   unsigned short* __restrict__ U)
{
    int bc = blockIdx.x;               // b*512 + c
    int c  = bc & 511;
    __shared__ float pad[72][72];      // 20.25 KB
    int t = threadIdx.x;
    float* pf = &pad[0][0];
#pragma unroll
    for (int i = 0; i < 21; ++i) {
        int e = i * 256 + t;
        if (e < 5184) pf[e] = 0.f;
    }
    __syncthreads();

    const unsigned short* ap = A + (size_t)bc * 4096;
#pragma unroll
    for (int i = 0; i < 4; ++i) {
        int idx = i * 256 + t;             // 1024 ushort4
        int y = idx >> 4, x4 = (idx & 15) * 4;
        ushort4 a4 = ((const ushort4*)ap)[idx];
        *(float4*)&pad[3 + y][4 + x4] =
            make_float4(bf2f(a4.x), bf2f(a4.y), bf2f(a4.z), bf2f(a4.w));
    }
    if (t < 64)       pad[67][4 + t] = bf2f(ap[62 * 64 + t]);
    else if (t < 128) { int y = t - 64; pad[3 + y][68] = bf2f(ap[y * 64 + 62]); }
    else if (t == 128) pad[67][68] = bf2f(ap[62 * 64 + 62]);
    __syncthreads();

    const unsigned short* lp = L + (size_t)bc * 4096;
    int u  = t & 15, rr = t >> 4;
    int w0 = u * 4;
    float4 res[4];
#pragma unroll
    for (int g = 0; g < 4; ++g) {
        int h = g * 16 + rr;
        float4 sx = make_float4(0.f, 0.f, 0.f, 0.f);
#pragma unroll
        for (int i = 0; i < 8; ++i) {
            float4 v = *(const float4*)&pad[h + i][4 + w0];
            sx.x += v.x; sx.y += v.y; sx.z += v.z; sx.w += v.w;
        }
        float win[12];
        *(float4*)&win[0] = *(const float4*)&pad[3 + h][w0];
        *(float4*)&win[4] = *(const float4*)&pad[3 + h][w0 + 4];
        *(float4*)&win[8] = *(const float4*)&pad[3 + h][w0 + 8];
        float4 sy = make_float4(0.f, 0.f, 0.f, 0.f);
#pragma unroll
        for (int i = 0; i < 8; ++i) {
            sy.x += win[1 + i];
            sy.y += win[2 + i];
            sy.z += win[3 + i];
            sy.w += win[4 + i];
        }
        ushort4 l4 = *(const ushort4*)&lp[h * 64 + w0];
        res[g].x = fmaf(0.125f, sx.x + sy.x, bf2f(l4.x));
        res[g].y = fmaf(0.125f, sx.y + sy.y, bf2f(l4.y));
        res[g].z = fmaf(0.125f, sx.z + sy.z, bf2f(l4.z));
        res[g].w = fmaf(0.125f, sx.w + sy.w, bf2f(l4.w));
    }
    __syncthreads();

#pragma unroll
    for (int g = 0; g < 4; ++g) {
        int h = g * 16 + rr;
        *(float4*)&pad[3 + h][4 + w0] = res[g];
    }
    __syncthreads();
    if (t < 64)       pad[67][4 + t] = pad[65][4 + t];
    else if (t < 128) { int y = t - 64; pad[3 + y][68] = pad[3 + y][66]; }
    else if (t == 128) pad[67][68] = pad[65][66];
    __syncthreads();

    const float* wdp = Wd + c * 64;
    float gc  = g3[c] * INVBN;
    float bcv = b3[c];
#pragma unroll
    for (int g = 0; g < 4; ++g) {
        int h = g * 16 + rr;
        float a0 = 0.f, a1 = 0.f, a2 = 0.f, a3 = 0.f;
#pragma unroll
        for (int i = 0; i < 8; ++i) {
            float win[12];
            *(float4*)&win[0] = *(const float4*)&pad[h + i][w0];
            *(float4*)&win[4] = *(const float4*)&pad[h + i][w0 + 4];
            *(float4*)&win[8] = *(const float4*)&pad[h + i][w0 + 8];
#pragma unroll
            for (int j = 0; j < 8; ++j) {
                float wv = wdp[i * 8 + j];
                a0 = fmaf(wv, win[1 + j], a0);
                a1 = fmaf(wv, win[2 + j], a1);
                a2 = fmaf(wv, win[3 + j], a2);
                a3 = fmaf(wv, win[4 + j], a3);
            }
        }
        ushort4 o;
        o.x = f2bf(gc * a0 + bcv);
        o.y = f2bf(gc * a1 + bcv);
        o.z = f2bf(gc * a2 + bcv);
        o.w = f2bf(gc * a3 + bcv);
        *(ushort4*)&U[(size_t)bc * 4096 + h * 64 + w0] = o;
    }
}

// ---------------------------------------------------------------------------
// U (B,512,4096) bf16 -> Ut (B,4096,512) bf16.  64p x 64c LDS tiles.
// ---------------------------------------------------------------------------
__global__ __launch_bounds__(256)
void transpose_cp_kernel(const unsigned short* __restrict__ U, unsigned short* __restrict__ Ut)
{
    int pt = blockIdx.x;               // p-tile 0..63
    int b  = blockIdx.y;
    const unsigned short* Ub = U + (size_t)b * 512 * 4096;
    unsigned short* Utb = Ut + (size_t)b * 4096 * 512;
    __shared__ unsigned short tile[64][72];
    int t = threadIdx.x;
    int p0 = pt * 64;

    for (int cc = 0; cc < 8; ++cc) {
        int c0 = cc * 64;
        __syncthreads();
        {
            int cl = t >> 2, px = (t & 3) * 16;
            const unsigned short* src = &Ub[(size_t)(c0 + cl) * 4096 + p0 + px];
            *(us8v*)&tile[cl][px]     = *(const us8v*)src;
            *(us8v*)&tile[cl][px + 8] = *(const us8v*)(src + 8);
        }
        __syncthreads();
        {
            int pl = t >> 2, cx = (t & 3) * 16;
            us8v o0, o1;
#pragma unroll
            for (int e = 0; e < 8; ++e) {
                o0[e] = tile[cx + e][pl];
                o1[e] = tile[cx + 8 + e][pl];
            }
            unsigned short* dst = &Utb[(size_t)(p0 + pl) * 512 + c0 + cx];
            *(us8v*)dst       = o0;
            *(us8v*)(dst + 8) = o1;
        }
    }
}

// ---------------------------------------------------------------------------
extern "C" void kernel_launch(void* const* d_in, const int* in_sizes, int n_in,
                              void* d_out, int out_size, void* d_ws, size_t ws_size,
                              hipStream_t stream)
{
    (void)in_sizes; (void)n_in; (void)out_size;
    const float* x     = (const float*)d_in[0];
    const float* w_lc1 = (const float*)d_in[1];
    const float* g1    = (const float*)d_in[2];
    const float* b1    = (const float*)d_in[3];
    const float* w_lc2 = (const float*)d_in[4];
    const float* g2    = (const float*)d_in[5];
    const float* b2    = (const float*)d_in[6];
    const float* w_qkv = (const float*)d_in[7];
    const float* rt    = (const float*)d_in[8];
    const float* w_dw  = (const float*)d_in[9];
    const float* g3    = (const float*)d_in[10];
    const float* b3    = (const float*)d_in[11];
    const float* w_pw  = (const float*)d_in[12];
    float* out = (float*)d_out;

    // workspace layout (bf16 short offsets):
    //   local : 16,777,216            [0 .. 16,777,216)
    //   xt    : 8*4356*512 = 17,842,176  [16,777,216 .. 34,619,392)
    //           (aliased by attnO and then U: attn(b) writes < xt[b+1] start)
    //   wt3   : 2,359,296             [34,619,392 .. 36,978,688)
    //   wq    :   786,432             [36,978,688 .. 37,765,120)
    //   wpw   :   262,144             [37,765,120 .. 38,027,264)
    //   bsum  : 512 f32 = 1,024       [38,027,264 .. 38,028,288)
    //   biasM : 262,144 f32 = 524,288 [38,028,288 .. 38,552,576)
    //   qkv   : 6,291,456 (per-batch) or 50,331,648 (full)  [38,552,576 ..)
    unsigned short* S        = (unsigned short*)d_ws;
    unsigned short* local_us = S;
    unsigned short* xt_us    = S + 16777216;
    unsigned short* attnO    = xt_us;                   // alias: attn out (bf16)
    unsigned short* u_us     = xt_us;                   // alias: U in-place over attnO
    unsigned short* wt3_us   = S + 34619392;
    unsigned short* wq_us    = S + 36978688;
    unsigned short* wpw_us   = S + 37765120;
    float*          bsum     = (float*)(S + 38027264);
    float*          biasM    = (float*)(S + 38028288);
    unsigned short* qkv_us   = S + 38552576;
    unsigned short* ut_us    = local_us;                // alias: Ut after local dead

    const bool full = ws_size >= (size_t)(38552576 + 50331648) * 2;  // 177.77 MB

    repack_kernel<<<dim3(9216), 256, 0, stream>>>(w_lc2, w_lc1, w_qkv, w_pw,
                                                  g1, g2, b1, b2,
                                                  wt3_us, wq_us, wpw_us, bsum);
    bias_precompute_kernel<<<dim3(64), 256, 0, stream>>>(rt, biasM);
    pad_transpose_kernel<<<dim3(66, 8), 256, 0, stream>>>(x, xt_us);
    mfma_gemm256<9><<<dim3(16, 2, 8), 512, 0, stream>>>(
        xt_us, wt3_us, bsum, local_us, 512);

    if (full) {
        mfma_gemm256<1><<<dim3(16, 6, 8), 512, 0, stream>>>(
            xt_us, wq_us, nullptr, qkv_us, 1536);
        attn_mfma_kernel<<<dim3(256, 8), 256, 0, stream>>>(qkv_us, biasM, attnO);
    } else {
        for (int b = 0; b < 8; ++b) {
            mfma_gemm256<1><<<dim3(16, 6, 1), 512, 0, stream>>>(
                xt_us + (size_t)b * 4356 * 512, wq_us, nullptr, qkv_us, 1536);
            attn_mfma_kernel<<<dim3(256, 1), 256, 0, stream>>>(
                qkv_us, biasM, attnO + (size_t)b * 2097152);
        }
    }

    pooldw_kernel<<<dim3(4096), 256, 0, stream>>>(attnO, local_us, w_dw, g3, b3, u_us);
    transpose_cp_kernel<<<dim3(64, 8), 256, 0, stream>>>(u_us, ut_us);
    mfma_gemm_f32out<<<dim3(32, 4, 8), 256, 0, stream>>>(
        ut_us, wpw_us, out, 512);
}